// Round 8
// baseline (339.409 us; speedup 1.0000x reference)
//
#include <hip/hip_runtime.h>
#include <math.h>

#define LEAKY 0.2f
#define SB 256

typedef _Float16 half2v __attribute__((ext_vector_type(2)));
typedef _Float16 half4 __attribute__((ext_vector_type(4)));
typedef _Float16 half8 __attribute__((ext_vector_type(8)));
typedef float f32x4 __attribute__((ext_vector_type(4)));

static inline int ceil_div(int a, int b) { return (a + b - 1) / b; }

// storage index p -> original column, for 64-col groups
__device__ __forceinline__ int PERM(int p) {
  int q = p & 63;
  return (p & ~63) | (((q & 3) << 4) | (q >> 2));
}

// ---------------- CSR build ----------------
__global__ __launch_bounds__(256) void k_count(const int* __restrict__ ei,
                                               int* __restrict__ deg, int NE, int N) {
  int e = blockIdx.x * 256 + threadIdx.x;
  int ET = NE + N;
  if (e >= ET) return;
  int d = (e < NE) ? ei[NE + e] : (e - NE);
  atomicAdd(&deg[d], 1);
}

__global__ __launch_bounds__(256) void k_bsum(const int* __restrict__ deg,
                                              int* __restrict__ bsum, int N) {
  int b = blockIdx.x;
  int chunk = (N + SB - 1) / SB;
  int s0 = b * chunk, s1 = min(s0 + chunk, N);
  int t = threadIdx.x;
  int sum = 0;
  for (int i = s0 + t; i < s1; i += 256) sum += deg[i];
#pragma unroll
  for (int o = 32; o; o >>= 1) sum += __shfl_xor(sum, o, 64);
  __shared__ int red[4];
  if ((t & 63) == 0) red[t >> 6] = sum;
  __syncthreads();
  if (t == 0) bsum[b] = red[0] + red[1] + red[2] + red[3];
}

__global__ __launch_bounds__(256) void k_bscan(const int* __restrict__ bsum,
                                               int* __restrict__ bpre,
                                               int* __restrict__ off, int N) {
  __shared__ int s[256];
  int t = threadIdx.x;
  int v = bsum[t];
  s[t] = v;
  __syncthreads();
  for (int o = 1; o < 256; o <<= 1) {
    int u = (t >= o) ? s[t - o] : 0;
    __syncthreads();
    s[t] += u;
    __syncthreads();
  }
  bpre[t] = s[t] - v;
  if (t == 255) off[N] = s[255];
}

__global__ __launch_bounds__(256) void k_cscan(const int* __restrict__ deg,
                                               const int* __restrict__ bpre,
                                               int* __restrict__ off,
                                               int* __restrict__ cursor, int N) {
  int b = blockIdx.x;
  int chunk = (N + SB - 1) / SB;
  int i = b * chunk + threadIdx.x;
  int t = threadIdx.x;
  int valid = (t < chunk && i < N);
  int v = valid ? deg[i] : 0;
  __shared__ int s[256];
  s[t] = v;
  __syncthreads();
  for (int o = 1; o < 256; o <<= 1) {
    int u = (t >= o) ? s[t - o] : 0;
    __syncthreads();
    s[t] += u;
    __syncthreads();
  }
  if (valid) {
    int ex = s[t] - v + bpre[b];
    off[i] = ex;
    cursor[i] = ex;
  }
}

__global__ __launch_bounds__(256) void k_fill(const int* __restrict__ ei,
                                              int* __restrict__ cursor,
                                              int* __restrict__ csr, int NE, int N) {
  int e = blockIdx.x * 256 + threadIdx.x;
  int ET = NE + N;
  if (e >= ET) return;
  int s = (e < NE) ? ei[e] : (e - NE);
  int d = (e < NE) ? ei[NE + e] : (e - NE);
  int pos = atomicAdd(&cursor[d], 1);
  csr[pos] = s;
}

// ---------------- prep: weight fragments + folded attention vectors ---------
__global__ __launch_bounds__(256) void k_prep(const float* __restrict__ W1,
                                              const float* __restrict__ W2,
                                              const float* __restrict__ a_src1,
                                              const float* __restrict__ a_dst1,
                                              const float* __restrict__ a_src2,
                                              const float* __restrict__ a_dst2,
                                              const float* __restrict__ b1,
                                              _Float16* __restrict__ w1hf,
                                              _Float16* __restrict__ w2f,
                                              float* __restrict__ wt1s,
                                              float* __restrict__ wt1d,
                                              float* __restrict__ b1p) {
  int idx = blockIdx.x * 256 + threadIdx.x;
  if (idx < 32768) {  // w1hf[h][ks][ct][l][i]
    int i = idx & 7, l = (idx >> 3) & 63, ct = (idx >> 9) & 3, ks = (idx >> 11) & 3,
        h = idx >> 13;
    int k = 32 * ks + 8 * (l >> 4) + i;
    int col = h * 64 + 16 * ct + (l & 15);
    w1hf[idx] = (_Float16)W1[k * 256 + col];
    return;
  }
  int i2 = idx - 32768;
  if (i2 < 16384) {  // w2f[ks][ct][l][i], A-side k' is layer-1 permuted index
    int i = i2 & 7, l = (i2 >> 3) & 63, ct = (i2 >> 9) & 3, ks = i2 >> 11;
    int kp = 32 * ks + 8 * (l >> 4) + i;
    int col = 16 * ct + (l & 15);
    w2f[i2] = (_Float16)W2[PERM(kp) * 64 + col];
    return;
  }
  int i3 = i2 - 16384;
  if (i3 < 512) {  // wt1s/wt1d[k*4+h]
    int h = i3 & 3, k = i3 >> 2;
    float ss = 0.f, sd = 0.f;
    for (int d = 0; d < 64; ++d) {
      float wv = W1[k * 256 + h * 64 + d];
      ss = fmaf(wv, a_src1[h * 64 + d], ss);
      sd = fmaf(wv, a_dst1[h * 64 + d], sd);
    }
    wt1s[i3] = ss;
    wt1d[i3] = sd;
    return;
  }
  int i4 = i3 - 512;
  if (i4 < 256) b1p[i4] = b1[PERM(i4)];
}

// ---------------- logits1: as1/ad1 = x @ wt1, also emit x16 -----------------
__global__ __launch_bounds__(256) void k_logits1(const float* __restrict__ x,
                                                 const float* __restrict__ wt1s,
                                                 const float* __restrict__ wt1d,
                                                 _Float16* __restrict__ x16,
                                                 float* __restrict__ as1,
                                                 float* __restrict__ ad1, int N) {
  int w = threadIdx.x >> 6, l = threadIdx.x & 63;
  int n = blockIdx.x * 4 + w;
  if (n >= N) return;
  float2 xv = *reinterpret_cast<const float2*>(x + (size_t)n * 128 + 2 * l);
  half2v xh;
  xh[0] = (_Float16)xv.x;
  xh[1] = (_Float16)xv.y;
  *reinterpret_cast<half2v*>(x16 + (size_t)n * 128 + 2 * l) = xh;
  float4 w0s = reinterpret_cast<const float4*>(wt1s)[2 * l];
  float4 w1s = reinterpret_cast<const float4*>(wt1s)[2 * l + 1];
  float4 w0d = reinterpret_cast<const float4*>(wt1d)[2 * l];
  float4 w1d = reinterpret_cast<const float4*>(wt1d)[2 * l + 1];
  float sa[4], sd[4];
  sa[0] = xv.x * w0s.x + xv.y * w1s.x;
  sa[1] = xv.x * w0s.y + xv.y * w1s.y;
  sa[2] = xv.x * w0s.z + xv.y * w1s.z;
  sa[3] = xv.x * w0s.w + xv.y * w1s.w;
  sd[0] = xv.x * w0d.x + xv.y * w1d.x;
  sd[1] = xv.x * w0d.y + xv.y * w1d.y;
  sd[2] = xv.x * w0d.z + xv.y * w1d.z;
  sd[3] = xv.x * w0d.w + xv.y * w1d.w;
#pragma unroll
  for (int o = 1; o <= 32; o <<= 1) {
#pragma unroll
    for (int h = 0; h < 4; ++h) {
      sa[h] += __shfl_xor(sa[h], o, 64);
      sd[h] += __shfl_xor(sd[h], o, 64);
    }
  }
  if (l == 0) {
#pragma unroll
    for (int h = 0; h < 4; ++h) {
      as1[n * 4 + h] = sa[h];
      ad1[n * 4 + h] = sd[h];
    }
  }
}

// ---------------- alpha precompute, layer 1 (H=4) ----------------
__global__ __launch_bounds__(256) void k_alpha1(const float* __restrict__ as1,
                                                const float* __restrict__ ad1,
                                                const int* __restrict__ off,
                                                const int* __restrict__ csr,
                                                float* __restrict__ alpha, int N) {
  int w = threadIdx.x >> 6, lane = threadIdx.x & 63;
  int n = blockIdx.x * 4 + w;
  if (n >= N) return;
  int eidx = lane >> 2, h = lane & 3;
  float adv = ad1[n * 4 + h];
  int e0 = off[n], e1 = off[n + 1];
  float m = -INFINITY;
  for (int base = e0; base < e1; base += 16) {
    int idx = base + eidx;
    if (idx < e1) {
      int s = csr[idx];
      float t = as1[s * 4 + h] + adv;
      t = t > 0.f ? t : LEAKY * t;
      m = fmaxf(m, t);
    }
  }
#pragma unroll
  for (int o = 4; o <= 32; o <<= 1) m = fmaxf(m, __shfl_xor(m, o, 64));
  float lp = 0.f;
  for (int base = e0; base < e1; base += 16) {
    int idx = base + eidx;
    if (idx < e1) {
      int s = csr[idx];
      float t = as1[s * 4 + h] + adv;
      t = t > 0.f ? t : LEAKY * t;
      float p = __expf(t - m);
      alpha[(size_t)idx * 4 + h] = p;
      lp += p;
    }
  }
#pragma unroll
  for (int o = 4; o <= 32; o <<= 1) lp += __shfl_xor(lp, o, 64);
  float rinv = 1.f / lp;
  for (int base = e0; base < e1; base += 16) {
    int idx = base + eidx;
    if (idx < e1) alpha[(size_t)idx * 4 + h] *= rinv;
  }
}

// ---------------- fused layer-1: aggregate x16 per head + block-diag MFMA ----
// 512 thr (8 waves), 32 nodes/block, LDS 32 KiB -> 4 blocks/CU.
// phase 1: wave aggregates 4 nodes, 8-deep gather MLP, lane = k/2.
// phase 2: wave (mt=w&1, h=w>>1): 16x64 output tile via 16 MFMA.
__global__ __launch_bounds__(512) void k_fagg1(const _Float16* __restrict__ x16,
                                               const float* __restrict__ alpha,
                                               const _Float16* __restrict__ w1hf,
                                               const float* __restrict__ b1p,
                                               const int* __restrict__ off,
                                               const int* __restrict__ csr,
                                               _Float16* __restrict__ hout1p, int N) {
  __shared__ _Float16 xs[32 * 512];  // 32 KiB
  int w = threadIdx.x >> 6, l = threadIdx.x & 63;
  int node0 = blockIdx.x * 32;
  // ---- phase 1 ----
  for (int s = 0; s < 4; ++s) {
    int nn = w * 4 + s;
    int n = node0 + nn;
    float a00 = 0.f, a01 = 0.f, a10 = 0.f, a11 = 0.f;
    float a20 = 0.f, a21 = 0.f, a30 = 0.f, a31 = 0.f;
    if (n < N) {
      int e0 = off[n], e1 = off[n + 1];
      for (int base = e0; base < e1; base += 8) {
#pragma unroll
        for (int u = 0; u < 8; ++u) {
          int e = base + u;
          int ec = min(e, e1 - 1);
          int src = csr[ec];
          float4 al = *reinterpret_cast<const float4*>(alpha + (size_t)ec * 4);
          if (e >= e1) al = make_float4(0.f, 0.f, 0.f, 0.f);
          half2v hv = *reinterpret_cast<const half2v*>(x16 + (size_t)src * 128 + 2 * l);
          float h0 = (float)hv[0], h1 = (float)hv[1];
          a00 = fmaf(al.x, h0, a00);
          a01 = fmaf(al.x, h1, a01);
          a10 = fmaf(al.y, h0, a10);
          a11 = fmaf(al.y, h1, a11);
          a20 = fmaf(al.z, h0, a20);
          a21 = fmaf(al.z, h1, a21);
          a30 = fmaf(al.w, h0, a30);
          a31 = fmaf(al.w, h1, a31);
        }
      }
    }
    int swz = (nn & 7) << 3;
    float acch[4][2] = {{a00, a01}, {a10, a11}, {a20, a21}, {a30, a31}};
#pragma unroll
    for (int h = 0; h < 4; ++h) {
      half2v o;
      o[0] = (_Float16)acch[h][0];
      o[1] = (_Float16)acch[h][1];
      *reinterpret_cast<half2v*>(&xs[nn * 512 + ((h * 128 + 2 * l) ^ swz)]) = o;
    }
  }
  __syncthreads();
  // ---- phase 2 ----
  int mt = w & 1, h = w >> 1;
  int lrow = l & 15, lgrp = l >> 4;
  int nodeA = 16 * mt + lrow;
  int swzA = (nodeA & 7) << 3;
  f32x4 acc[4];
#pragma unroll
  for (int ct = 0; ct < 4; ++ct) acc[ct] = (f32x4){0.f, 0.f, 0.f, 0.f};
#pragma unroll
  for (int ks = 0; ks < 4; ++ks) {
    half8 af = *reinterpret_cast<const half8*>(
        &xs[nodeA * 512 + ((h * 128 + 32 * ks + 8 * lgrp) ^ swzA)]);
    const half8* bp =
        reinterpret_cast<const half8*>(w1hf) + (size_t)((h * 4 + ks) * 4) * 64 + l;
#pragma unroll
    for (int ct = 0; ct < 4; ++ct) {
      half8 bf = bp[ct * 64];
      acc[ct] = __builtin_amdgcn_mfma_f32_16x16x32_f16(af, bf, acc[ct], 0, 0, 0);
    }
  }
  float4 bv = *reinterpret_cast<const float4*>(b1p + h * 64 + lrow * 4);
  int rbase = node0 + 16 * mt + 4 * lgrp;
#pragma unroll
  for (int r = 0; r < 4; ++r) {
    int n = rbase + r;
    if (n < N) {
      half4 o;
      o[0] = (_Float16)fmaxf(acc[0][r] + bv.x, 0.f);
      o[1] = (_Float16)fmaxf(acc[1][r] + bv.y, 0.f);
      o[2] = (_Float16)fmaxf(acc[2][r] + bv.z, 0.f);
      o[3] = (_Float16)fmaxf(acc[3][r] + bv.w, 0.f);
      *reinterpret_cast<half4*>(hout1p + (size_t)n * 256 + h * 64 + lrow * 4) = o;
    }
  }
}

// ---------------- alpha precompute, layer 2 (H=1) ----------------
__global__ __launch_bounds__(256) void k_alpha2(const float* __restrict__ as2,
                                                const float* __restrict__ ad2,
                                                const int* __restrict__ off,
                                                const int* __restrict__ csr,
                                                float* __restrict__ alpha, int N) {
  int w = threadIdx.x >> 6, lane = threadIdx.x & 63;
  int n = blockIdx.x * 4 + w;
  if (n >= N) return;
  float adv = ad2[n];
  int e0 = off[n], e1 = off[n + 1];
  float m = -INFINITY;
  for (int base = e0; base < e1; base += 64) {
    int idx = base + lane;
    if (idx < e1) {
      float t = as2[csr[idx]] + adv;
      t = t > 0.f ? t : LEAKY * t;
      m = fmaxf(m, t);
    }
  }
#pragma unroll
  for (int o = 1; o <= 32; o <<= 1) m = fmaxf(m, __shfl_xor(m, o, 64));
  float lp = 0.f;
  for (int base = e0; base < e1; base += 64) {
    int idx = base + lane;
    if (idx < e1) {
      float t = as2[csr[idx]] + adv;
      t = t > 0.f ? t : LEAKY * t;
      float p = __expf(t - m);
      alpha[idx] = p;
      lp += p;
    }
  }
#pragma unroll
  for (int o = 1; o <= 32; o <<= 1) lp += __shfl_xor(lp, o, 64);
  float rinv = 1.f / lp;
  for (int base = e0; base < e1; base += 64) {
    int idx = base + lane;
    if (idx < e1) alpha[idx] *= rinv;
  }
}

// ---------------- Layer 2 GEMM (MFMA) + fused as2/ad2 epilogue ---------------
__global__ __launch_bounds__(256) void k_gemm2(const _Float16* __restrict__ hin,
                                               const _Float16* __restrict__ w2f,
                                               const float* __restrict__ a_src2,
                                               const float* __restrict__ a_dst2,
                                               _Float16* __restrict__ h2p,
                                               float* __restrict__ as2,
                                               float* __restrict__ ad2, int N) {
  int w = threadIdx.x >> 6, l = threadIdx.x & 63;
  int n0 = blockIdx.x * 64 + 16 * w;
  int lrow = l & 15, lgrp = l >> 4;
  int arow = min(n0 + lrow, N - 1);
  f32x4 acc[4];
#pragma unroll
  for (int ct = 0; ct < 4; ++ct) acc[ct] = (f32x4){0.f, 0.f, 0.f, 0.f};
#pragma unroll
  for (int ks = 0; ks < 8; ++ks) {
    half8 af =
        *reinterpret_cast<const half8*>(hin + (size_t)arow * 256 + 32 * ks + 8 * lgrp);
    const half8* bp = reinterpret_cast<const half8*>(w2f) + (size_t)(ks * 4) * 64 + l;
#pragma unroll
    for (int ct = 0; ct < 4; ++ct) {
      half8 bf = bp[ct * 64];
      acc[ct] = __builtin_amdgcn_mfma_f32_16x16x32_f16(af, bf, acc[ct], 0, 0, 0);
    }
  }
  float ascol[4], adcol[4];
#pragma unroll
  for (int ct = 0; ct < 4; ++ct) {
    ascol[ct] = a_src2[16 * ct + lrow];
    adcol[ct] = a_dst2[16 * ct + lrow];
  }
  int rbase = n0 + 4 * lgrp;
#pragma unroll
  for (int r = 0; r < 4; ++r) {
    int row = rbase + r;
    bool ok = row < N;
    float sa = 0.f, sd = 0.f;
    half4 o;
#pragma unroll
    for (int ct = 0; ct < 4; ++ct) {
      float v = acc[ct][r];
      o[ct] = (_Float16)v;
      sa = fmaf(v, ascol[ct], sa);
      sd = fmaf(v, adcol[ct], sd);
    }
    if (ok) *reinterpret_cast<half4*>(h2p + (size_t)row * 64 + lrow * 4) = o;
#pragma unroll
    for (int oo = 1; oo <= 8; oo <<= 1) {
      sa += __shfl_xor(sa, oo, 64);
      sd += __shfl_xor(sd, oo, 64);
    }
    if (ok && lrow == 0) {
      as2[row] = sa;
      ad2[row] = sd;
    }
  }
}

// ---------------- Layer 2 aggregation (reads permuted h2p) ----------------
__global__ __launch_bounds__(256) void k_agg2(const _Float16* __restrict__ h2p,
                                              const float* __restrict__ alpha,
                                              const float* __restrict__ b2,
                                              const int* __restrict__ off,
                                              const int* __restrict__ csr,
                                              float* __restrict__ out, int N) {
  int w = threadIdx.x >> 6, lane = threadIdx.x & 63;
  int n = blockIdx.x * 4 + w;
  if (n >= N) return;
  int sub = lane >> 4, q = lane & 15;
  int e0 = off[n], e1 = off[n + 1];
  float4 acc = make_float4(0.f, 0.f, 0.f, 0.f);
  for (int base = e0; base < e1; base += 8) {
#pragma unroll
    for (int u = 0; u < 2; ++u) {
      int e = base + u * 4 + sub;
      int ec = min(e, e1 - 1);
      int s = csr[ec];
      float a = alpha[ec];
      if (e >= e1) a = 0.f;
      half4 hv = *reinterpret_cast<const half4*>(h2p + (size_t)s * 64 + 4 * q);
      acc.x = fmaf(a, (float)hv[0], acc.x);
      acc.y = fmaf(a, (float)hv[1], acc.y);
      acc.z = fmaf(a, (float)hv[2], acc.z);
      acc.w = fmaf(a, (float)hv[3], acc.w);
    }
  }
#pragma unroll
  for (int o = 16; o <= 32; o <<= 1) {
    acc.x += __shfl_xor(acc.x, o, 64);
    acc.y += __shfl_xor(acc.y, o, 64);
    acc.z += __shfl_xor(acc.z, o, 64);
    acc.w += __shfl_xor(acc.w, o, 64);
  }
  if (lane < 16) {
    out[(size_t)n * 64 + q] = acc.x + b2[q];
    out[(size_t)n * 64 + 16 + q] = acc.y + b2[16 + q];
    out[(size_t)n * 64 + 32 + q] = acc.z + b2[32 + q];
    out[(size_t)n * 64 + 48 + q] = acc.w + b2[48 + q];
  }
}

extern "C" void kernel_launch(void* const* d_in, const int* in_sizes, int n_in,
                              void* d_out, int out_size, void* d_ws, size_t ws_size,
                              hipStream_t stream) {
  const float* x = (const float*)d_in[0];
  const int* ei = (const int*)d_in[1];
  const float* W1 = (const float*)d_in[2];
  const float* a_src1 = (const float*)d_in[3];
  const float* a_dst1 = (const float*)d_in[4];
  const float* b1 = (const float*)d_in[5];
  const float* W2 = (const float*)d_in[6];
  const float* a_src2 = (const float*)d_in[7];
  const float* a_dst2 = (const float*)d_in[8];
  const float* b2 = (const float*)d_in[9];
  float* out = (float*)d_out;

  const int N = in_sizes[0] / 128;
  const int NE = in_sizes[1] / 2;
  const int ET = NE + N;

  char* p = (char*)d_ws;
  auto alloc = [&](size_t bytes) {
    char* r = p;
    p += (bytes + 255) & ~(size_t)255;
    return r;
  };
  int* deg = (int*)alloc((size_t)N * 4);
  int* cursor = (int*)alloc((size_t)N * 4);
  int* off = (int*)alloc((size_t)(N + 1) * 4);
  int* csr = (int*)alloc((size_t)ET * 4);
  int* bsum = (int*)alloc((size_t)SB * 4);
  int* bpre = (int*)alloc((size_t)SB * 4);
  _Float16* w1hf = (_Float16*)alloc((size_t)32768 * 2);
  _Float16* w2f = (_Float16*)alloc((size_t)16384 * 2);
  float* wt1s = (float*)alloc((size_t)512 * 4);
  float* wt1d = (float*)alloc((size_t)512 * 4);
  float* b1p = (float*)alloc((size_t)256 * 4);
  _Float16* x16 = (_Float16*)alloc((size_t)N * 128 * 2);
  _Float16* hout1p = (_Float16*)alloc((size_t)N * 256 * 2);
  float* as1 = (float*)alloc((size_t)N * 4 * 4);
  float* ad1 = (float*)alloc((size_t)N * 4 * 4);
  float* alpha1 = (float*)alloc((size_t)ET * 4 * 4);
  _Float16* h2p = x16;     // reuse: x16 dead after k_fagg1
  float* alpha2 = alpha1;  // reuse: alpha1 dead after k_fagg1
  float* as2 = (float*)alloc((size_t)N * 4);
  float* ad2 = (float*)alloc((size_t)N * 4);

  hipMemsetAsync(deg, 0, (size_t)N * 4, stream);
  k_count<<<ceil_div(ET, 256), 256, 0, stream>>>(ei, deg, NE, N);
  k_bsum<<<SB, 256, 0, stream>>>(deg, bsum, N);
  k_bscan<<<1, 256, 0, stream>>>(bsum, bpre, off, N);
  k_cscan<<<SB, 256, 0, stream>>>(deg, bpre, off, cursor, N);
  k_fill<<<ceil_div(ET, 256), 256, 0, stream>>>(ei, cursor, csr, NE, N);
  k_prep<<<198, 256, 0, stream>>>(W1, W2, a_src1, a_dst1, a_src2, a_dst2, b1,
                                  w1hf, w2f, wt1s, wt1d, b1p);

  k_logits1<<<ceil_div(N, 4), 256, 0, stream>>>(x, wt1s, wt1d, x16, as1, ad1, N);
  k_alpha1<<<ceil_div(N, 4), 256, 0, stream>>>(as1, ad1, off, csr, alpha1, N);
  k_fagg1<<<ceil_div(N, 32), 512, 0, stream>>>(x16, alpha1, w1hf, b1p, off, csr,
                                               hout1p, N);
  k_gemm2<<<ceil_div(N, 64), 256, 0, stream>>>(hout1p, w2f, a_src2, a_dst2, h2p,
                                               as2, ad2, N);
  k_alpha2<<<ceil_div(N, 4), 256, 0, stream>>>(as2, ad2, off, csr, alpha2, N);
  k_agg2<<<ceil_div(N, 4), 256, 0, stream>>>(h2p, alpha2, b2, off, csr, out, N);
}

// Round 9
// 292.412 us; speedup vs baseline: 1.1607x; 1.1607x over previous
//
#include <hip/hip_runtime.h>
#include <math.h>

#define LEAKY 0.2f
#define SB 256

typedef _Float16 half2v __attribute__((ext_vector_type(2)));
typedef _Float16 half4 __attribute__((ext_vector_type(4)));
typedef _Float16 half8 __attribute__((ext_vector_type(8)));
typedef float f32x4 __attribute__((ext_vector_type(4)));

static inline int ceil_div(int a, int b) { return (a + b - 1) / b; }

// storage index p -> original column, for 64-col groups
__device__ __forceinline__ int PERM(int p) {
  int q = p & 63;
  return (p & ~63) | (((q & 3) << 4) | (q >> 2));
}

// ---------------- CSR build ----------------
__global__ __launch_bounds__(256) void k_count(const int* __restrict__ ei,
                                               int* __restrict__ deg, int NE, int N) {
  int e = blockIdx.x * 256 + threadIdx.x;
  int ET = NE + N;
  if (e >= ET) return;
  int d = (e < NE) ? ei[NE + e] : (e - NE);
  atomicAdd(&deg[d], 1);
}

__global__ __launch_bounds__(256) void k_bsum(const int* __restrict__ deg,
                                              int* __restrict__ bsum, int N) {
  int b = blockIdx.x;
  int chunk = (N + SB - 1) / SB;
  int s0 = b * chunk, s1 = min(s0 + chunk, N);
  int t = threadIdx.x;
  int sum = 0;
  for (int i = s0 + t; i < s1; i += 256) sum += deg[i];
#pragma unroll
  for (int o = 32; o; o >>= 1) sum += __shfl_xor(sum, o, 64);
  __shared__ int red[4];
  if ((t & 63) == 0) red[t >> 6] = sum;
  __syncthreads();
  if (t == 0) bsum[b] = red[0] + red[1] + red[2] + red[3];
}

__global__ __launch_bounds__(256) void k_bscan(const int* __restrict__ bsum,
                                               int* __restrict__ bpre,
                                               int* __restrict__ off, int N) {
  __shared__ int s[256];
  int t = threadIdx.x;
  int v = bsum[t];
  s[t] = v;
  __syncthreads();
  for (int o = 1; o < 256; o <<= 1) {
    int u = (t >= o) ? s[t - o] : 0;
    __syncthreads();
    s[t] += u;
    __syncthreads();
  }
  bpre[t] = s[t] - v;
  if (t == 255) off[N] = s[255];
}

__global__ __launch_bounds__(256) void k_cscan(const int* __restrict__ deg,
                                               const int* __restrict__ bpre,
                                               int* __restrict__ off,
                                               int* __restrict__ cursor, int N) {
  int b = blockIdx.x;
  int chunk = (N + SB - 1) / SB;
  int i = b * chunk + threadIdx.x;
  int t = threadIdx.x;
  int valid = (t < chunk && i < N);
  int v = valid ? deg[i] : 0;
  __shared__ int s[256];
  s[t] = v;
  __syncthreads();
  for (int o = 1; o < 256; o <<= 1) {
    int u = (t >= o) ? s[t - o] : 0;
    __syncthreads();
    s[t] += u;
    __syncthreads();
  }
  if (valid) {
    int ex = s[t] - v + bpre[b];
    off[i] = ex;
    cursor[i] = ex;
  }
}

__global__ __launch_bounds__(256) void k_fill(const int* __restrict__ ei,
                                              int* __restrict__ cursor,
                                              int* __restrict__ csr, int NE, int N) {
  int e = blockIdx.x * 256 + threadIdx.x;
  int ET = NE + N;
  if (e >= ET) return;
  int s = (e < NE) ? ei[e] : (e - NE);
  int d = (e < NE) ? ei[NE + e] : (e - NE);
  int pos = atomicAdd(&cursor[d], 1);
  csr[pos] = s;
}

// ---------------- prep: weight fragments + folded attention vectors ---------
__global__ __launch_bounds__(256) void k_prep(const float* __restrict__ W1,
                                              const float* __restrict__ W2,
                                              const float* __restrict__ a_src1,
                                              const float* __restrict__ a_dst1,
                                              const float* __restrict__ a_src2,
                                              const float* __restrict__ a_dst2,
                                              const float* __restrict__ b1,
                                              _Float16* __restrict__ w1hf,
                                              _Float16* __restrict__ w2f,
                                              float* __restrict__ wt1s,
                                              float* __restrict__ wt1d,
                                              float* __restrict__ b1p) {
  int idx = blockIdx.x * 256 + threadIdx.x;
  if (idx < 32768) {  // w1hf[h][ks][ct][l][i]
    int i = idx & 7, l = (idx >> 3) & 63, ct = (idx >> 9) & 3, ks = (idx >> 11) & 3,
        h = idx >> 13;
    int k = 32 * ks + 8 * (l >> 4) + i;
    int col = h * 64 + 16 * ct + (l & 15);
    w1hf[idx] = (_Float16)W1[k * 256 + col];
    return;
  }
  int i2 = idx - 32768;
  if (i2 < 16384) {  // w2f[ks][ct][l][i], A-side k' is layer-1 permuted index
    int i = i2 & 7, l = (i2 >> 3) & 63, ct = (i2 >> 9) & 3, ks = i2 >> 11;
    int kp = 32 * ks + 8 * (l >> 4) + i;
    int col = 16 * ct + (l & 15);
    w2f[i2] = (_Float16)W2[PERM(kp) * 64 + col];
    return;
  }
  int i3 = i2 - 16384;
  if (i3 < 512) {  // wt1s/wt1d[k*4+h]
    int h = i3 & 3, k = i3 >> 2;
    float ss = 0.f, sd = 0.f;
    for (int d = 0; d < 64; ++d) {
      float wv = W1[k * 256 + h * 64 + d];
      ss = fmaf(wv, a_src1[h * 64 + d], ss);
      sd = fmaf(wv, a_dst1[h * 64 + d], sd);
    }
    wt1s[i3] = ss;
    wt1d[i3] = sd;
    return;
  }
  int i4 = i3 - 512;
  if (i4 < 256) b1p[i4] = b1[PERM(i4)];
}

// ---------------- logits1: as1/ad1 = x @ wt1, also emit x16 -----------------
__global__ __launch_bounds__(256) void k_logits1(const float* __restrict__ x,
                                                 const float* __restrict__ wt1s,
                                                 const float* __restrict__ wt1d,
                                                 _Float16* __restrict__ x16,
                                                 float* __restrict__ as1,
                                                 float* __restrict__ ad1, int N) {
  int w = threadIdx.x >> 6, l = threadIdx.x & 63;
  int n = blockIdx.x * 4 + w;
  if (n >= N) return;
  float2 xv = *reinterpret_cast<const float2*>(x + (size_t)n * 128 + 2 * l);
  half2v xh;
  xh[0] = (_Float16)xv.x;
  xh[1] = (_Float16)xv.y;
  *reinterpret_cast<half2v*>(x16 + (size_t)n * 128 + 2 * l) = xh;
  float4 w0s = reinterpret_cast<const float4*>(wt1s)[2 * l];
  float4 w1s = reinterpret_cast<const float4*>(wt1s)[2 * l + 1];
  float4 w0d = reinterpret_cast<const float4*>(wt1d)[2 * l];
  float4 w1d = reinterpret_cast<const float4*>(wt1d)[2 * l + 1];
  float sa[4], sd[4];
  sa[0] = xv.x * w0s.x + xv.y * w1s.x;
  sa[1] = xv.x * w0s.y + xv.y * w1s.y;
  sa[2] = xv.x * w0s.z + xv.y * w1s.z;
  sa[3] = xv.x * w0s.w + xv.y * w1s.w;
  sd[0] = xv.x * w0d.x + xv.y * w1d.x;
  sd[1] = xv.x * w0d.y + xv.y * w1d.y;
  sd[2] = xv.x * w0d.z + xv.y * w1d.z;
  sd[3] = xv.x * w0d.w + xv.y * w1d.w;
#pragma unroll
  for (int o = 1; o <= 32; o <<= 1) {
#pragma unroll
    for (int h = 0; h < 4; ++h) {
      sa[h] += __shfl_xor(sa[h], o, 64);
      sd[h] += __shfl_xor(sd[h], o, 64);
    }
  }
  if (l == 0) {
#pragma unroll
    for (int h = 0; h < 4; ++h) {
      as1[n * 4 + h] = sa[h];
      ad1[n * 4 + h] = sd[h];
    }
  }
}

// ---------------- alpha precompute, layer 1 (H=4) ----------------
__global__ __launch_bounds__(256) void k_alpha1(const float* __restrict__ as1,
                                                const float* __restrict__ ad1,
                                                const int* __restrict__ off,
                                                const int* __restrict__ csr,
                                                float* __restrict__ alpha, int N) {
  int w = threadIdx.x >> 6, lane = threadIdx.x & 63;
  int n = blockIdx.x * 4 + w;
  if (n >= N) return;
  int eidx = lane >> 2, h = lane & 3;
  float adv = ad1[n * 4 + h];
  int e0 = off[n], e1 = off[n + 1];
  float m = -INFINITY;
  for (int base = e0; base < e1; base += 16) {
    int idx = base + eidx;
    if (idx < e1) {
      int s = csr[idx];
      float t = as1[s * 4 + h] + adv;
      t = t > 0.f ? t : LEAKY * t;
      m = fmaxf(m, t);
    }
  }
#pragma unroll
  for (int o = 4; o <= 32; o <<= 1) m = fmaxf(m, __shfl_xor(m, o, 64));
  float lp = 0.f;
  for (int base = e0; base < e1; base += 16) {
    int idx = base + eidx;
    if (idx < e1) {
      int s = csr[idx];
      float t = as1[s * 4 + h] + adv;
      t = t > 0.f ? t : LEAKY * t;
      float p = __expf(t - m);
      alpha[(size_t)idx * 4 + h] = p;
      lp += p;
    }
  }
#pragma unroll
  for (int o = 4; o <= 32; o <<= 1) lp += __shfl_xor(lp, o, 64);
  float rinv = 1.f / lp;
  for (int base = e0; base < e1; base += 16) {
    int idx = base + eidx;
    if (idx < e1) alpha[(size_t)idx * 4 + h] *= rinv;
  }
}

// ---------------- x-space aggregation: wave per node, 8B/lane gathers --------
// lane = slot*32 + kq; slot covers edge e0+2u+slot, kq covers k = 4kq..4kq+3.
// out: xagg[n][h][k] fp16 (per-head aggregated input features)
__global__ __launch_bounds__(256) void k_xagg(const _Float16* __restrict__ x16,
                                              const float* __restrict__ alpha,
                                              const int* __restrict__ off,
                                              const int* __restrict__ csr,
                                              _Float16* __restrict__ xagg, int N) {
  int w = threadIdx.x >> 6, l = threadIdx.x & 63;
  int n = blockIdx.x * 4 + w;
  if (n >= N) return;
  int slot = l >> 5, kq = l & 31;
  int e0 = off[n], e1 = off[n + 1];
  float acc[4][4];
#pragma unroll
  for (int h = 0; h < 4; ++h)
#pragma unroll
    for (int k = 0; k < 4; ++k) acc[h][k] = 0.f;
  for (int base = e0; base < e1; base += 8) {
#pragma unroll
    for (int u = 0; u < 4; ++u) {
      int e = base + 2 * u + slot;
      int ec = min(e, e1 - 1);
      int src = csr[ec];
      float4 al = *reinterpret_cast<const float4*>(alpha + (size_t)ec * 4);
      if (e >= e1) al = make_float4(0.f, 0.f, 0.f, 0.f);
      half4 hv = *reinterpret_cast<const half4*>(x16 + (size_t)src * 128 + 4 * kq);
      float x0 = (float)hv[0], x1 = (float)hv[1], x2 = (float)hv[2], x3 = (float)hv[3];
      acc[0][0] = fmaf(al.x, x0, acc[0][0]);
      acc[0][1] = fmaf(al.x, x1, acc[0][1]);
      acc[0][2] = fmaf(al.x, x2, acc[0][2]);
      acc[0][3] = fmaf(al.x, x3, acc[0][3]);
      acc[1][0] = fmaf(al.y, x0, acc[1][0]);
      acc[1][1] = fmaf(al.y, x1, acc[1][1]);
      acc[1][2] = fmaf(al.y, x2, acc[1][2]);
      acc[1][3] = fmaf(al.y, x3, acc[1][3]);
      acc[2][0] = fmaf(al.z, x0, acc[2][0]);
      acc[2][1] = fmaf(al.z, x1, acc[2][1]);
      acc[2][2] = fmaf(al.z, x2, acc[2][2]);
      acc[2][3] = fmaf(al.z, x3, acc[2][3]);
      acc[3][0] = fmaf(al.w, x0, acc[3][0]);
      acc[3][1] = fmaf(al.w, x1, acc[3][1]);
      acc[3][2] = fmaf(al.w, x2, acc[3][2]);
      acc[3][3] = fmaf(al.w, x3, acc[3][3]);
    }
  }
#pragma unroll
  for (int h = 0; h < 4; ++h)
#pragma unroll
    for (int k = 0; k < 4; ++k) acc[h][k] += __shfl_xor(acc[h][k], 32, 64);
  if (slot == 0) {
#pragma unroll
    for (int h = 0; h < 4; ++h) {
      half4 o;
      o[0] = (_Float16)acc[h][0];
      o[1] = (_Float16)acc[h][1];
      o[2] = (_Float16)acc[h][2];
      o[3] = (_Float16)acc[h][3];
      *reinterpret_cast<half4*>(xagg + (size_t)n * 512 + h * 128 + 4 * kq) = o;
    }
  }
}

// ---------------- layer-1 GEMM over aggregated x: hout1p = ReLU(xagg@W1+b1) --
// block = 4 waves x 16 rows; per wave: 4 heads x 4 ct tiles, K=128 per head.
__global__ __launch_bounds__(256) void k_gemm1f(const _Float16* __restrict__ xagg,
                                                const _Float16* __restrict__ w1hf,
                                                const float* __restrict__ b1p,
                                                _Float16* __restrict__ hout1p, int N) {
  int w = threadIdx.x >> 6, l = threadIdx.x & 63;
  int n0 = blockIdx.x * 64 + 16 * w;
  int lrow = l & 15, lgrp = l >> 4;
  int arow = min(n0 + lrow, N - 1);
  f32x4 acc[4][4];
#pragma unroll
  for (int h = 0; h < 4; ++h)
#pragma unroll
    for (int ct = 0; ct < 4; ++ct) acc[h][ct] = (f32x4){0.f, 0.f, 0.f, 0.f};
#pragma unroll
  for (int h = 0; h < 4; ++h) {
#pragma unroll
    for (int ks = 0; ks < 4; ++ks) {
      half8 af = *reinterpret_cast<const half8*>(xagg + (size_t)arow * 512 + h * 128 +
                                                 32 * ks + 8 * lgrp);
      const half8* bp =
          reinterpret_cast<const half8*>(w1hf) + (size_t)((h * 4 + ks) * 4) * 64 + l;
#pragma unroll
      for (int ct = 0; ct < 4; ++ct) {
        half8 bf = bp[ct * 64];
        acc[h][ct] = __builtin_amdgcn_mfma_f32_16x16x32_f16(af, bf, acc[h][ct], 0, 0, 0);
      }
    }
  }
  int rbase = n0 + 4 * lgrp;
#pragma unroll
  for (int h = 0; h < 4; ++h) {
    float4 bv = *reinterpret_cast<const float4*>(b1p + h * 64 + lrow * 4);
#pragma unroll
    for (int r = 0; r < 4; ++r) {
      int n = rbase + r;
      if (n < N) {
        half4 o;
        o[0] = (_Float16)fmaxf(acc[h][0][r] + bv.x, 0.f);
        o[1] = (_Float16)fmaxf(acc[h][1][r] + bv.y, 0.f);
        o[2] = (_Float16)fmaxf(acc[h][2][r] + bv.z, 0.f);
        o[3] = (_Float16)fmaxf(acc[h][3][r] + bv.w, 0.f);
        *reinterpret_cast<half4*>(hout1p + (size_t)n * 256 + h * 64 + lrow * 4) = o;
      }
    }
  }
}

// ---------------- alpha precompute, layer 2 (H=1) ----------------
__global__ __launch_bounds__(256) void k_alpha2(const float* __restrict__ as2,
                                                const float* __restrict__ ad2,
                                                const int* __restrict__ off,
                                                const int* __restrict__ csr,
                                                float* __restrict__ alpha, int N) {
  int w = threadIdx.x >> 6, lane = threadIdx.x & 63;
  int n = blockIdx.x * 4 + w;
  if (n >= N) return;
  float adv = ad2[n];
  int e0 = off[n], e1 = off[n + 1];
  float m = -INFINITY;
  for (int base = e0; base < e1; base += 64) {
    int idx = base + lane;
    if (idx < e1) {
      float t = as2[csr[idx]] + adv;
      t = t > 0.f ? t : LEAKY * t;
      m = fmaxf(m, t);
    }
  }
#pragma unroll
  for (int o = 1; o <= 32; o <<= 1) m = fmaxf(m, __shfl_xor(m, o, 64));
  float lp = 0.f;
  for (int base = e0; base < e1; base += 64) {
    int idx = base + lane;
    if (idx < e1) {
      float t = as2[csr[idx]] + adv;
      t = t > 0.f ? t : LEAKY * t;
      float p = __expf(t - m);
      alpha[idx] = p;
      lp += p;
    }
  }
#pragma unroll
  for (int o = 1; o <= 32; o <<= 1) lp += __shfl_xor(lp, o, 64);
  float rinv = 1.f / lp;
  for (int base = e0; base < e1; base += 64) {
    int idx = base + lane;
    if (idx < e1) alpha[idx] *= rinv;
  }
}

// ---------------- Layer 2 GEMM (MFMA) + fused as2/ad2 epilogue ---------------
__global__ __launch_bounds__(256) void k_gemm2(const _Float16* __restrict__ hin,
                                               const _Float16* __restrict__ w2f,
                                               const float* __restrict__ a_src2,
                                               const float* __restrict__ a_dst2,
                                               _Float16* __restrict__ h2p,
                                               float* __restrict__ as2,
                                               float* __restrict__ ad2, int N) {
  int w = threadIdx.x >> 6, l = threadIdx.x & 63;
  int n0 = blockIdx.x * 64 + 16 * w;
  int lrow = l & 15, lgrp = l >> 4;
  int arow = min(n0 + lrow, N - 1);
  f32x4 acc[4];
#pragma unroll
  for (int ct = 0; ct < 4; ++ct) acc[ct] = (f32x4){0.f, 0.f, 0.f, 0.f};
#pragma unroll
  for (int ks = 0; ks < 8; ++ks) {
    half8 af =
        *reinterpret_cast<const half8*>(hin + (size_t)arow * 256 + 32 * ks + 8 * lgrp);
    const half8* bp = reinterpret_cast<const half8*>(w2f) + (size_t)(ks * 4) * 64 + l;
#pragma unroll
    for (int ct = 0; ct < 4; ++ct) {
      half8 bf = bp[ct * 64];
      acc[ct] = __builtin_amdgcn_mfma_f32_16x16x32_f16(af, bf, acc[ct], 0, 0, 0);
    }
  }
  float ascol[4], adcol[4];
#pragma unroll
  for (int ct = 0; ct < 4; ++ct) {
    ascol[ct] = a_src2[16 * ct + lrow];
    adcol[ct] = a_dst2[16 * ct + lrow];
  }
  int rbase = n0 + 4 * lgrp;
#pragma unroll
  for (int r = 0; r < 4; ++r) {
    int row = rbase + r;
    bool ok = row < N;
    float sa = 0.f, sd = 0.f;
    half4 o;
#pragma unroll
    for (int ct = 0; ct < 4; ++ct) {
      float v = acc[ct][r];
      o[ct] = (_Float16)v;
      sa = fmaf(v, ascol[ct], sa);
      sd = fmaf(v, adcol[ct], sd);
    }
    if (ok) *reinterpret_cast<half4*>(h2p + (size_t)row * 64 + lrow * 4) = o;
#pragma unroll
    for (int oo = 1; oo <= 8; oo <<= 1) {
      sa += __shfl_xor(sa, oo, 64);
      sd += __shfl_xor(sd, oo, 64);
    }
    if (ok && lrow == 0) {
      as2[row] = sa;
      ad2[row] = sd;
    }
  }
}

// ---------------- Layer 2 aggregation (reads permuted h2p) ----------------
__global__ __launch_bounds__(256) void k_agg2(const _Float16* __restrict__ h2p,
                                              const float* __restrict__ alpha,
                                              const float* __restrict__ b2,
                                              const int* __restrict__ off,
                                              const int* __restrict__ csr,
                                              float* __restrict__ out, int N) {
  int w = threadIdx.x >> 6, lane = threadIdx.x & 63;
  int n = blockIdx.x * 4 + w;
  if (n >= N) return;
  int sub = lane >> 4, q = lane & 15;
  int e0 = off[n], e1 = off[n + 1];
  float4 acc = make_float4(0.f, 0.f, 0.f, 0.f);
  for (int base = e0; base < e1; base += 8) {
#pragma unroll
    for (int u = 0; u < 2; ++u) {
      int e = base + u * 4 + sub;
      int ec = min(e, e1 - 1);
      int s = csr[ec];
      float a = alpha[ec];
      if (e >= e1) a = 0.f;
      half4 hv = *reinterpret_cast<const half4*>(h2p + (size_t)s * 64 + 4 * q);
      acc.x = fmaf(a, (float)hv[0], acc.x);
      acc.y = fmaf(a, (float)hv[1], acc.y);
      acc.z = fmaf(a, (float)hv[2], acc.z);
      acc.w = fmaf(a, (float)hv[3], acc.w);
    }
  }
#pragma unroll
  for (int o = 16; o <= 32; o <<= 1) {
    acc.x += __shfl_xor(acc.x, o, 64);
    acc.y += __shfl_xor(acc.y, o, 64);
    acc.z += __shfl_xor(acc.z, o, 64);
    acc.w += __shfl_xor(acc.w, o, 64);
  }
  if (lane < 16) {
    out[(size_t)n * 64 + q] = acc.x + b2[q];
    out[(size_t)n * 64 + 16 + q] = acc.y + b2[16 + q];
    out[(size_t)n * 64 + 32 + q] = acc.z + b2[32 + q];
    out[(size_t)n * 64 + 48 + q] = acc.w + b2[48 + q];
  }
}

extern "C" void kernel_launch(void* const* d_in, const int* in_sizes, int n_in,
                              void* d_out, int out_size, void* d_ws, size_t ws_size,
                              hipStream_t stream) {
  const float* x = (const float*)d_in[0];
  const int* ei = (const int*)d_in[1];
  const float* W1 = (const float*)d_in[2];
  const float* a_src1 = (const float*)d_in[3];
  const float* a_dst1 = (const float*)d_in[4];
  const float* b1 = (const float*)d_in[5];
  const float* W2 = (const float*)d_in[6];
  const float* a_src2 = (const float*)d_in[7];
  const float* a_dst2 = (const float*)d_in[8];
  const float* b2 = (const float*)d_in[9];
  float* out = (float*)d_out;

  const int N = in_sizes[0] / 128;
  const int NE = in_sizes[1] / 2;
  const int ET = NE + N;

  char* p = (char*)d_ws;
  auto alloc = [&](size_t bytes) {
    char* r = p;
    p += (bytes + 255) & ~(size_t)255;
    return r;
  };
  int* deg = (int*)alloc((size_t)N * 4);
  int* cursor = (int*)alloc((size_t)N * 4);
  int* off = (int*)alloc((size_t)(N + 1) * 4);
  int* csr = (int*)alloc((size_t)ET * 4);
  int* bsum = (int*)alloc((size_t)SB * 4);
  int* bpre = (int*)alloc((size_t)SB * 4);
  _Float16* w1hf = (_Float16*)alloc((size_t)32768 * 2);
  _Float16* w2f = (_Float16*)alloc((size_t)16384 * 2);
  float* wt1s = (float*)alloc((size_t)512 * 4);
  float* wt1d = (float*)alloc((size_t)512 * 4);
  float* b1p = (float*)alloc((size_t)256 * 4);
  _Float16* x16 = (_Float16*)alloc((size_t)N * 128 * 2);
  _Float16* xagg = (_Float16*)alloc((size_t)N * 512 * 2);
  _Float16* hout1p = (_Float16*)alloc((size_t)N * 256 * 2);
  float* as1 = (float*)alloc((size_t)N * 4 * 4);
  float* ad1 = (float*)alloc((size_t)N * 4 * 4);
  float* alpha1 = (float*)alloc((size_t)ET * 4 * 4);
  _Float16* h2p = x16;     // reuse: x16 dead after k_xagg
  float* alpha2 = alpha1;  // reuse: alpha1 dead after k_xagg
  float* as2 = (float*)alloc((size_t)N * 4);
  float* ad2 = (float*)alloc((size_t)N * 4);

  hipMemsetAsync(deg, 0, (size_t)N * 4, stream);
  k_count<<<ceil_div(ET, 256), 256, 0, stream>>>(ei, deg, NE, N);
  k_bsum<<<SB, 256, 0, stream>>>(deg, bsum, N);
  k_bscan<<<1, 256, 0, stream>>>(bsum, bpre, off, N);
  k_cscan<<<SB, 256, 0, stream>>>(deg, bpre, off, cursor, N);
  k_fill<<<ceil_div(ET, 256), 256, 0, stream>>>(ei, cursor, csr, NE, N);
  k_prep<<<198, 256, 0, stream>>>(W1, W2, a_src1, a_dst1, a_src2, a_dst2, b1,
                                  w1hf, w2f, wt1s, wt1d, b1p);

  k_logits1<<<ceil_div(N, 4), 256, 0, stream>>>(x, wt1s, wt1d, x16, as1, ad1, N);
  k_alpha1<<<ceil_div(N, 4), 256, 0, stream>>>(as1, ad1, off, csr, alpha1, N);
  k_xagg<<<ceil_div(N, 4), 256, 0, stream>>>(x16, alpha1, off, csr, xagg, N);
  k_gemm1f<<<ceil_div(N, 64), 256, 0, stream>>>(xagg, w1hf, b1p, hout1p, N);
  k_gemm2<<<ceil_div(N, 64), 256, 0, stream>>>(hout1p, w2f, a_src2, a_dst2, h2p,
                                               as2, ad2, N);
  k_alpha2<<<ceil_div(N, 4), 256, 0, stream>>>(as2, ad2, off, csr, alpha2, N);
  k_agg2<<<ceil_div(N, 4), 256, 0, stream>>>(h2p, alpha2, b2, off, csr, out, N);
}

// Round 10
// 254.318 us; speedup vs baseline: 1.3346x; 1.1498x over previous
//
#include <hip/hip_runtime.h>
#include <math.h>

#define LEAKY 0.2f
#define SB 256
#define FTILE 4096

typedef _Float16 half2v __attribute__((ext_vector_type(2)));
typedef _Float16 half4 __attribute__((ext_vector_type(4)));
typedef _Float16 half8 __attribute__((ext_vector_type(8)));
typedef float f32x4 __attribute__((ext_vector_type(4)));

static inline int ceil_div(int a, int b) { return (a + b - 1) / b; }

// storage index p -> original column, for 64-col groups
__device__ __forceinline__ int PERM(int p) {
  int q = p & 63;
  return (p & ~63) | (((q & 3) << 4) | (q >> 2));
}

// ---------------- CSR build ----------------
__global__ __launch_bounds__(256) void k_count(const int* __restrict__ ei,
                                               int* __restrict__ deg, int NE, int N) {
  int e = blockIdx.x * 256 + threadIdx.x;
  int ET = NE + N;
  if (e >= ET) return;
  int d = (e < NE) ? ei[NE + e] : (e - NE);
  atomicAdd(&deg[d], 1);
}

__global__ __launch_bounds__(256) void k_bsum(const int* __restrict__ deg,
                                              int* __restrict__ bsum, int N) {
  int b = blockIdx.x;
  int chunk = (N + SB - 1) / SB;
  int s0 = b * chunk, s1 = min(s0 + chunk, N);
  int t = threadIdx.x;
  int sum = 0;
  for (int i = s0 + t; i < s1; i += 256) sum += deg[i];
#pragma unroll
  for (int o = 32; o; o >>= 1) sum += __shfl_xor(sum, o, 64);
  __shared__ int red[4];
  if ((t & 63) == 0) red[t >> 6] = sum;
  __syncthreads();
  if (t == 0) bsum[b] = red[0] + red[1] + red[2] + red[3];
}

// scan 256 bucket sums; bpre has 257 entries; bcur is a working copy for fillA
__global__ __launch_bounds__(256) void k_bscan(const int* __restrict__ bsum,
                                               int* __restrict__ bpre,
                                               int* __restrict__ bcur,
                                               int* __restrict__ off, int N) {
  __shared__ int s[256];
  int t = threadIdx.x;
  int v = bsum[t];
  s[t] = v;
  __syncthreads();
  for (int o = 1; o < 256; o <<= 1) {
    int u = (t >= o) ? s[t - o] : 0;
    __syncthreads();
    s[t] += u;
    __syncthreads();
  }
  bpre[t] = s[t] - v;
  bcur[t] = s[t] - v;
  if (t == 255) {
    off[N] = s[255];
    bpre[256] = s[255];
  }
}

__global__ __launch_bounds__(256) void k_cscan(const int* __restrict__ deg,
                                               const int* __restrict__ bpre,
                                               int* __restrict__ off, int N) {
  int b = blockIdx.x;
  int chunk = (N + SB - 1) / SB;
  int i = b * chunk + threadIdx.x;
  int t = threadIdx.x;
  int valid = (t < chunk && i < N);
  int v = valid ? deg[i] : 0;
  __shared__ int s[256];
  s[t] = v;
  __syncthreads();
  for (int o = 1; o < 256; o <<= 1) {
    int u = (t >= o) ? s[t - o] : 0;
    __syncthreads();
    s[t] += u;
    __syncthreads();
  }
  if (valid) off[i] = s[t] - v + bpre[b];
}

// ---- fillA: radix-partition edges into bucket-contiguous (dst,src) pairs ----
__global__ __launch_bounds__(256) void k_fillA(const int* __restrict__ ei,
                                               int* __restrict__ bcur,
                                               int2* __restrict__ pairs,
                                               int NE, int N, int chunk) {
  __shared__ int hist[256], base[256], cnt2[256];
  int t = threadIdx.x;
  hist[t] = 0;
  cnt2[t] = 0;
  __syncthreads();
  int ET = NE + N;
  int e0 = blockIdx.x * FTILE;
  int sv[16], dv[16];
#pragma unroll
  for (int j = 0; j < 16; ++j) {
    int e = e0 + t + 256 * j;
    if (e < ET) {
      sv[j] = (e < NE) ? ei[e] : (e - NE);
      dv[j] = (e < NE) ? ei[NE + e] : (e - NE);
      atomicAdd(&hist[dv[j] / chunk], 1);
    } else {
      dv[j] = -1;
    }
  }
  __syncthreads();
  if (hist[t] > 0) base[t] = atomicAdd(&bcur[t], hist[t]);
  __syncthreads();
#pragma unroll
  for (int j = 0; j < 16; ++j) {
    if (dv[j] >= 0) {
      int b = dv[j] / chunk;
      int r = atomicAdd(&cnt2[b], 1);
      pairs[base[b] + r] = make_int2(dv[j], sv[j]);
    }
  }
}

// ---- fillB: one block per bucket; LDS per-dst cursors; local scatter --------
__global__ __launch_bounds__(256) void k_fillB(const int2* __restrict__ pairs,
                                               const int* __restrict__ bpre,
                                               const int* __restrict__ off,
                                               int* __restrict__ csr, int N, int chunk) {
  __shared__ int cur[256];
  int b = blockIdx.x, t = threadIdx.x;
  int node0 = b * chunk;
  for (int i = t; i < chunk; i += 256)
    if (node0 + i < N) cur[i] = off[node0 + i];
  __syncthreads();
  int i0 = bpre[b], i1 = bpre[b + 1];
  for (int i = i0 + t; i < i1; i += 256) {
    int2 pr = pairs[i];
    int pos = atomicAdd(&cur[pr.x - node0], 1);
    csr[pos] = pr.y;
  }
}

// ---------------- prep: weight fragments + folded attention vectors ---------
__global__ __launch_bounds__(256) void k_prep(const float* __restrict__ W1,
                                              const float* __restrict__ W2,
                                              const float* __restrict__ a_src1,
                                              const float* __restrict__ a_dst1,
                                              const float* __restrict__ a_src2,
                                              const float* __restrict__ a_dst2,
                                              const float* __restrict__ b1,
                                              _Float16* __restrict__ w1hf,
                                              _Float16* __restrict__ w2f,
                                              float* __restrict__ wt1s,
                                              float* __restrict__ wt1d,
                                              float* __restrict__ b1p) {
  int idx = blockIdx.x * 256 + threadIdx.x;
  if (idx < 32768) {  // w1hf[h][ks][ct][l][i]
    int i = idx & 7, l = (idx >> 3) & 63, ct = (idx >> 9) & 3, ks = (idx >> 11) & 3,
        h = idx >> 13;
    int k = 32 * ks + 8 * (l >> 4) + i;
    int col = h * 64 + 16 * ct + (l & 15);
    w1hf[idx] = (_Float16)W1[k * 256 + col];
    return;
  }
  int i2 = idx - 32768;
  if (i2 < 16384) {  // w2f[ks][ct][l][i], A-side k' is layer-1 permuted index
    int i = i2 & 7, l = (i2 >> 3) & 63, ct = (i2 >> 9) & 3, ks = i2 >> 11;
    int kp = 32 * ks + 8 * (l >> 4) + i;
    int col = 16 * ct + (l & 15);
    w2f[i2] = (_Float16)W2[PERM(kp) * 64 + col];
    return;
  }
  int i3 = i2 - 16384;
  if (i3 < 512) {  // wt1s/wt1d[k*4+h]
    int h = i3 & 3, k = i3 >> 2;
    float ss = 0.f, sd = 0.f;
    for (int d = 0; d < 64; ++d) {
      float wv = W1[k * 256 + h * 64 + d];
      ss = fmaf(wv, a_src1[h * 64 + d], ss);
      sd = fmaf(wv, a_dst1[h * 64 + d], sd);
    }
    wt1s[i3] = ss;
    wt1d[i3] = sd;
    return;
  }
  int i4 = i3 - 512;
  if (i4 < 256) b1p[i4] = b1[PERM(i4)];
}

// ---------------- logits1: as1/ad1 = x @ wt1, also emit x16 -----------------
__global__ __launch_bounds__(256) void k_logits1(const float* __restrict__ x,
                                                 const float* __restrict__ wt1s,
                                                 const float* __restrict__ wt1d,
                                                 _Float16* __restrict__ x16,
                                                 float* __restrict__ as1,
                                                 float* __restrict__ ad1, int N) {
  int w = threadIdx.x >> 6, l = threadIdx.x & 63;
  int n = blockIdx.x * 4 + w;
  if (n >= N) return;
  float2 xv = *reinterpret_cast<const float2*>(x + (size_t)n * 128 + 2 * l);
  half2v xh;
  xh[0] = (_Float16)xv.x;
  xh[1] = (_Float16)xv.y;
  *reinterpret_cast<half2v*>(x16 + (size_t)n * 128 + 2 * l) = xh;
  float4 w0s = reinterpret_cast<const float4*>(wt1s)[2 * l];
  float4 w1s = reinterpret_cast<const float4*>(wt1s)[2 * l + 1];
  float4 w0d = reinterpret_cast<const float4*>(wt1d)[2 * l];
  float4 w1d = reinterpret_cast<const float4*>(wt1d)[2 * l + 1];
  float sa[4], sd[4];
  sa[0] = xv.x * w0s.x + xv.y * w1s.x;
  sa[1] = xv.x * w0s.y + xv.y * w1s.y;
  sa[2] = xv.x * w0s.z + xv.y * w1s.z;
  sa[3] = xv.x * w0s.w + xv.y * w1s.w;
  sd[0] = xv.x * w0d.x + xv.y * w1d.x;
  sd[1] = xv.x * w0d.y + xv.y * w1d.y;
  sd[2] = xv.x * w0d.z + xv.y * w1d.z;
  sd[3] = xv.x * w0d.w + xv.y * w1d.w;
#pragma unroll
  for (int o = 1; o <= 32; o <<= 1) {
#pragma unroll
    for (int h = 0; h < 4; ++h) {
      sa[h] += __shfl_xor(sa[h], o, 64);
      sd[h] += __shfl_xor(sd[h], o, 64);
    }
  }
  if (l == 0) {
#pragma unroll
    for (int h = 0; h < 4; ++h) {
      as1[n * 4 + h] = sa[h];
      ad1[n * 4 + h] = sd[h];
    }
  }
}

// ---------------- alpha precompute, layer 1 (H=4) ----------------
__global__ __launch_bounds__(256) void k_alpha1(const float* __restrict__ as1,
                                                const float* __restrict__ ad1,
                                                const int* __restrict__ off,
                                                const int* __restrict__ csr,
                                                float* __restrict__ alpha, int N) {
  int w = threadIdx.x >> 6, lane = threadIdx.x & 63;
  int n = blockIdx.x * 4 + w;
  if (n >= N) return;
  int eidx = lane >> 2, h = lane & 3;
  float adv = ad1[n * 4 + h];
  int e0 = off[n], e1 = off[n + 1];
  float m = -INFINITY;
  for (int base = e0; base < e1; base += 16) {
    int idx = base + eidx;
    if (idx < e1) {
      int s = csr[idx];
      float t = as1[s * 4 + h] + adv;
      t = t > 0.f ? t : LEAKY * t;
      m = fmaxf(m, t);
    }
  }
#pragma unroll
  for (int o = 4; o <= 32; o <<= 1) m = fmaxf(m, __shfl_xor(m, o, 64));
  float lp = 0.f;
  for (int base = e0; base < e1; base += 16) {
    int idx = base + eidx;
    if (idx < e1) {
      int s = csr[idx];
      float t = as1[s * 4 + h] + adv;
      t = t > 0.f ? t : LEAKY * t;
      float p = __expf(t - m);
      alpha[(size_t)idx * 4 + h] = p;
      lp += p;
    }
  }
#pragma unroll
  for (int o = 4; o <= 32; o <<= 1) lp += __shfl_xor(lp, o, 64);
  float rinv = 1.f / lp;
  for (int base = e0; base < e1; base += 16) {
    int idx = base + eidx;
    if (idx < e1) alpha[(size_t)idx * 4 + h] *= rinv;
  }
}

// ---------------- x-space aggregation: wave per node, 16B/lane gathers -------
// lane = slot*16 + kq; slot covers edge e0+4u+slot, kq covers k = 8kq..8kq+7
__global__ __launch_bounds__(256) void k_xagg(const _Float16* __restrict__ x16,
                                              const float* __restrict__ alpha,
                                              const int* __restrict__ off,
                                              const int* __restrict__ csr,
                                              _Float16* __restrict__ xagg, int N) {
  int w = threadIdx.x >> 6, l = threadIdx.x & 63;
  int n = blockIdx.x * 4 + w;
  if (n >= N) return;
  int slot = l >> 4, kq = l & 15;
  int e0 = off[n], e1 = off[n + 1];
  float acc[4][8];
#pragma unroll
  for (int h = 0; h < 4; ++h)
#pragma unroll
    for (int k = 0; k < 8; ++k) acc[h][k] = 0.f;
  for (int base = e0; base < e1; base += 8) {
#pragma unroll
    for (int u = 0; u < 2; ++u) {
      int e = base + 4 * u + slot;
      int ec = min(e, e1 - 1);
      int src = csr[ec];
      float4 al = *reinterpret_cast<const float4*>(alpha + (size_t)ec * 4);
      if (e >= e1) al = make_float4(0.f, 0.f, 0.f, 0.f);
      half8 hv = *reinterpret_cast<const half8*>(x16 + (size_t)src * 128 + 8 * kq);
      float xf[8];
#pragma unroll
      for (int k = 0; k < 8; ++k) xf[k] = (float)hv[k];
#pragma unroll
      for (int k = 0; k < 8; ++k) {
        acc[0][k] = fmaf(al.x, xf[k], acc[0][k]);
        acc[1][k] = fmaf(al.y, xf[k], acc[1][k]);
        acc[2][k] = fmaf(al.z, xf[k], acc[2][k]);
        acc[3][k] = fmaf(al.w, xf[k], acc[3][k]);
      }
    }
  }
#pragma unroll
  for (int h = 0; h < 4; ++h)
#pragma unroll
    for (int k = 0; k < 8; ++k) {
      acc[h][k] += __shfl_xor(acc[h][k], 16, 64);
      acc[h][k] += __shfl_xor(acc[h][k], 32, 64);
    }
  if (slot == 0) {
#pragma unroll
    for (int h = 0; h < 4; ++h) {
      half8 o;
#pragma unroll
      for (int k = 0; k < 8; ++k) o[k] = (_Float16)acc[h][k];
      *reinterpret_cast<half8*>(xagg + (size_t)n * 512 + h * 128 + 8 * kq) = o;
    }
  }
}

// ---------------- layer-1 GEMM over aggregated x: hout1p = ReLU(xagg@W1+b1) --
__global__ __launch_bounds__(256) void k_gemm1f(const _Float16* __restrict__ xagg,
                                                const _Float16* __restrict__ w1hf,
                                                const float* __restrict__ b1p,
                                                _Float16* __restrict__ hout1p, int N) {
  int w = threadIdx.x >> 6, l = threadIdx.x & 63;
  int n0 = blockIdx.x * 64 + 16 * w;
  int lrow = l & 15, lgrp = l >> 4;
  int arow = min(n0 + lrow, N - 1);
  f32x4 acc[4][4];
#pragma unroll
  for (int h = 0; h < 4; ++h)
#pragma unroll
    for (int ct = 0; ct < 4; ++ct) acc[h][ct] = (f32x4){0.f, 0.f, 0.f, 0.f};
#pragma unroll
  for (int h = 0; h < 4; ++h) {
#pragma unroll
    for (int ks = 0; ks < 4; ++ks) {
      half8 af = *reinterpret_cast<const half8*>(xagg + (size_t)arow * 512 + h * 128 +
                                                 32 * ks + 8 * lgrp);
      const half8* bp =
          reinterpret_cast<const half8*>(w1hf) + (size_t)((h * 4 + ks) * 4) * 64 + l;
#pragma unroll
      for (int ct = 0; ct < 4; ++ct) {
        half8 bf = bp[ct * 64];
        acc[h][ct] = __builtin_amdgcn_mfma_f32_16x16x32_f16(af, bf, acc[h][ct], 0, 0, 0);
      }
    }
  }
  int rbase = n0 + 4 * lgrp;
#pragma unroll
  for (int h = 0; h < 4; ++h) {
    float4 bv = *reinterpret_cast<const float4*>(b1p + h * 64 + lrow * 4);
#pragma unroll
    for (int r = 0; r < 4; ++r) {
      int n = rbase + r;
      if (n < N) {
        half4 o;
        o[0] = (_Float16)fmaxf(acc[h][0][r] + bv.x, 0.f);
        o[1] = (_Float16)fmaxf(acc[h][1][r] + bv.y, 0.f);
        o[2] = (_Float16)fmaxf(acc[h][2][r] + bv.z, 0.f);
        o[3] = (_Float16)fmaxf(acc[h][3][r] + bv.w, 0.f);
        *reinterpret_cast<half4*>(hout1p + (size_t)n * 256 + h * 64 + lrow * 4) = o;
      }
    }
  }
}

// ---------------- alpha precompute, layer 2 (H=1) ----------------
__global__ __launch_bounds__(256) void k_alpha2(const float* __restrict__ as2,
                                                const float* __restrict__ ad2,
                                                const int* __restrict__ off,
                                                const int* __restrict__ csr,
                                                float* __restrict__ alpha, int N) {
  int w = threadIdx.x >> 6, lane = threadIdx.x & 63;
  int n = blockIdx.x * 4 + w;
  if (n >= N) return;
  float adv = ad2[n];
  int e0 = off[n], e1 = off[n + 1];
  float m = -INFINITY;
  for (int base = e0; base < e1; base += 64) {
    int idx = base + lane;
    if (idx < e1) {
      float t = as2[csr[idx]] + adv;
      t = t > 0.f ? t : LEAKY * t;
      m = fmaxf(m, t);
    }
  }
#pragma unroll
  for (int o = 1; o <= 32; o <<= 1) m = fmaxf(m, __shfl_xor(m, o, 64));
  float lp = 0.f;
  for (int base = e0; base < e1; base += 64) {
    int idx = base + lane;
    if (idx < e1) {
      float t = as2[csr[idx]] + adv;
      t = t > 0.f ? t : LEAKY * t;
      float p = __expf(t - m);
      alpha[idx] = p;
      lp += p;
    }
  }
#pragma unroll
  for (int o = 1; o <= 32; o <<= 1) lp += __shfl_xor(lp, o, 64);
  float rinv = 1.f / lp;
  for (int base = e0; base < e1; base += 64) {
    int idx = base + lane;
    if (idx < e1) alpha[idx] *= rinv;
  }
}

// ---------------- Layer 2 GEMM (MFMA) + fused as2/ad2 epilogue ---------------
__global__ __launch_bounds__(256) void k_gemm2(const _Float16* __restrict__ hin,
                                               const _Float16* __restrict__ w2f,
                                               const float* __restrict__ a_src2,
                                               const float* __restrict__ a_dst2,
                                               _Float16* __restrict__ h2p,
                                               float* __restrict__ as2,
                                               float* __restrict__ ad2, int N) {
  int w = threadIdx.x >> 6, l = threadIdx.x & 63;
  int n0 = blockIdx.x * 64 + 16 * w;
  int lrow = l & 15, lgrp = l >> 4;
  int arow = min(n0 + lrow, N - 1);
  f32x4 acc[4];
#pragma unroll
  for (int ct = 0; ct < 4; ++ct) acc[ct] = (f32x4){0.f, 0.f, 0.f, 0.f};
#pragma unroll
  for (int ks = 0; ks < 8; ++ks) {
    half8 af =
        *reinterpret_cast<const half8*>(hin + (size_t)arow * 256 + 32 * ks + 8 * lgrp);
    const half8* bp = reinterpret_cast<const half8*>(w2f) + (size_t)(ks * 4) * 64 + l;
#pragma unroll
    for (int ct = 0; ct < 4; ++ct) {
      half8 bf = bp[ct * 64];
      acc[ct] = __builtin_amdgcn_mfma_f32_16x16x32_f16(af, bf, acc[ct], 0, 0, 0);
    }
  }
  float ascol[4], adcol[4];
#pragma unroll
  for (int ct = 0; ct < 4; ++ct) {
    ascol[ct] = a_src2[16 * ct + lrow];
    adcol[ct] = a_dst2[16 * ct + lrow];
  }
  int rbase = n0 + 4 * lgrp;
#pragma unroll
  for (int r = 0; r < 4; ++r) {
    int row = rbase + r;
    bool ok = row < N;
    float sa = 0.f, sd = 0.f;
    half4 o;
#pragma unroll
    for (int ct = 0; ct < 4; ++ct) {
      float v = acc[ct][r];
      o[ct] = (_Float16)v;
      sa = fmaf(v, ascol[ct], sa);
      sd = fmaf(v, adcol[ct], sd);
    }
    if (ok) *reinterpret_cast<half4*>(h2p + (size_t)row * 64 + lrow * 4) = o;
#pragma unroll
    for (int oo = 1; oo <= 8; oo <<= 1) {
      sa += __shfl_xor(sa, oo, 64);
      sd += __shfl_xor(sd, oo, 64);
    }
    if (ok && lrow == 0) {
      as2[row] = sa;
      ad2[row] = sd;
    }
  }
}

// ---------------- Layer 2 aggregation (reads permuted h2p) ----------------
__global__ __launch_bounds__(256) void k_agg2(const _Float16* __restrict__ h2p,
                                              const float* __restrict__ alpha,
                                              const float* __restrict__ b2,
                                              const int* __restrict__ off,
                                              const int* __restrict__ csr,
                                              float* __restrict__ out, int N) {
  int w = threadIdx.x >> 6, lane = threadIdx.x & 63;
  int n = blockIdx.x * 4 + w;
  if (n >= N) return;
  int sub = lane >> 4, q = lane & 15;
  int e0 = off[n], e1 = off[n + 1];
  float4 acc = make_float4(0.f, 0.f, 0.f, 0.f);
  for (int base = e0; base < e1; base += 8) {
#pragma unroll
    for (int u = 0; u < 2; ++u) {
      int e = base + u * 4 + sub;
      int ec = min(e, e1 - 1);
      int s = csr[ec];
      float a = alpha[ec];
      if (e >= e1) a = 0.f;
      half4 hv = *reinterpret_cast<const half4*>(h2p + (size_t)s * 64 + 4 * q);
      acc.x = fmaf(a, (float)hv[0], acc.x);
      acc.y = fmaf(a, (float)hv[1], acc.y);
      acc.z = fmaf(a, (float)hv[2], acc.z);
      acc.w = fmaf(a, (float)hv[3], acc.w);
    }
  }
#pragma unroll
  for (int o = 16; o <= 32; o <<= 1) {
    acc.x += __shfl_xor(acc.x, o, 64);
    acc.y += __shfl_xor(acc.y, o, 64);
    acc.z += __shfl_xor(acc.z, o, 64);
    acc.w += __shfl_xor(acc.w, o, 64);
  }
  if (lane < 16) {
    out[(size_t)n * 64 + q] = acc.x + b2[q];
    out[(size_t)n * 64 + 16 + q] = acc.y + b2[16 + q];
    out[(size_t)n * 64 + 32 + q] = acc.z + b2[32 + q];
    out[(size_t)n * 64 + 48 + q] = acc.w + b2[48 + q];
  }
}

extern "C" void kernel_launch(void* const* d_in, const int* in_sizes, int n_in,
                              void* d_out, int out_size, void* d_ws, size_t ws_size,
                              hipStream_t stream) {
  const float* x = (const float*)d_in[0];
  const int* ei = (const int*)d_in[1];
  const float* W1 = (const float*)d_in[2];
  const float* a_src1 = (const float*)d_in[3];
  const float* a_dst1 = (const float*)d_in[4];
  const float* b1 = (const float*)d_in[5];
  const float* W2 = (const float*)d_in[6];
  const float* a_src2 = (const float*)d_in[7];
  const float* a_dst2 = (const float*)d_in[8];
  const float* b2 = (const float*)d_in[9];
  float* out = (float*)d_out;

  const int N = in_sizes[0] / 128;
  const int NE = in_sizes[1] / 2;
  const int ET = NE + N;
  const int chunk = ceil_div(N, SB);

  char* p = (char*)d_ws;
  auto alloc = [&](size_t bytes) {
    char* r = p;
    p += (bytes + 255) & ~(size_t)255;
    return r;
  };
  int* deg = (int*)alloc((size_t)N * 4);
  int* off = (int*)alloc((size_t)(N + 1) * 4);
  int* csr = (int*)alloc((size_t)ET * 4);
  int* bsum = (int*)alloc((size_t)SB * 4);
  int* bpre = (int*)alloc((size_t)(SB + 1) * 4);
  int* bcur = (int*)alloc((size_t)SB * 4);
  int2* pairs = (int2*)alloc((size_t)ET * 8);
  _Float16* w1hf = (_Float16*)alloc((size_t)32768 * 2);
  _Float16* w2f = (_Float16*)alloc((size_t)16384 * 2);
  float* wt1s = (float*)alloc((size_t)512 * 4);
  float* wt1d = (float*)alloc((size_t)512 * 4);
  float* b1p = (float*)alloc((size_t)256 * 4);
  _Float16* x16 = (_Float16*)alloc((size_t)N * 128 * 2);
  _Float16* xagg = (_Float16*)alloc((size_t)N * 512 * 2);
  _Float16* hout1p = (_Float16*)alloc((size_t)N * 256 * 2);
  float* as1 = (float*)alloc((size_t)N * 4 * 4);
  float* ad1 = (float*)alloc((size_t)N * 4 * 4);
  float* alpha1 = (float*)alloc((size_t)ET * 4 * 4);
  _Float16* h2p = x16;     // reuse: x16 dead after k_xagg
  float* alpha2 = alpha1;  // reuse: alpha1 dead after k_xagg
  float* as2 = (float*)alloc((size_t)N * 4);
  float* ad2 = (float*)alloc((size_t)N * 4);

  hipMemsetAsync(deg, 0, (size_t)N * 4, stream);
  k_count<<<ceil_div(ET, 256), 256, 0, stream>>>(ei, deg, NE, N);
  k_bsum<<<SB, 256, 0, stream>>>(deg, bsum, N);
  k_bscan<<<1, 256, 0, stream>>>(bsum, bpre, bcur, off, N);
  k_cscan<<<SB, 256, 0, stream>>>(deg, bpre, off, N);
  k_fillA<<<ceil_div(ET, FTILE), 256, 0, stream>>>(ei, bcur, pairs, NE, N, chunk);
  k_fillB<<<SB, 256, 0, stream>>>(pairs, bpre, off, csr, N, chunk);
  k_prep<<<198, 256, 0, stream>>>(W1, W2, a_src1, a_dst1, a_src2, a_dst2, b1,
                                  w1hf, w2f, wt1s, wt1d, b1p);

  k_logits1<<<ceil_div(N, 4), 256, 0, stream>>>(x, wt1s, wt1d, x16, as1, ad1, N);
  k_alpha1<<<ceil_div(N, 4), 256, 0, stream>>>(as1, ad1, off, csr, alpha1, N);
  k_xagg<<<ceil_div(N, 4), 256, 0, stream>>>(x16, alpha1, off, csr, xagg, N);
  k_gemm1f<<<ceil_div(N, 64), 256, 0, stream>>>(xagg, w1hf, b1p, hout1p, N);
  k_gemm2<<<ceil_div(N, 64), 256, 0, stream>>>(hout1p, w2f, a_src2, a_dst2, h2p,
                                               as2, ad2, N);
  k_alpha2<<<ceil_div(N, 4), 256, 0, stream>>>(as2, ad2, off, csr, alpha2, N);
  k_agg2<<<ceil_div(N, 4), 256, 0, stream>>>(h2p, alpha2, b2, off, csr, out, N);
}

// Round 11
// 240.895 us; speedup vs baseline: 1.4090x; 1.0557x over previous
//
#include <hip/hip_runtime.h>
#include <math.h>

#define LEAKY 0.2f
#define SB 256
#define FTILE 4096

typedef _Float16 half2v __attribute__((ext_vector_type(2)));
typedef _Float16 half4 __attribute__((ext_vector_type(4)));
typedef _Float16 half8 __attribute__((ext_vector_type(8)));
typedef float f32x4 __attribute__((ext_vector_type(4)));

static inline int ceil_div(int a, int b) { return (a + b - 1) / b; }

// storage index p -> original column, for 64-col groups
__device__ __forceinline__ int PERM(int p) {
  int q = p & 63;
  return (p & ~63) | (((q & 3) << 4) | (q >> 2));
}

// ---------------- CSR build ----------------
__global__ __launch_bounds__(256) void k_count(const int* __restrict__ ei,
                                               int* __restrict__ deg, int NE, int N) {
  int e = blockIdx.x * 256 + threadIdx.x;
  int ET = NE + N;
  if (e >= ET) return;
  int d = (e < NE) ? ei[NE + e] : (e - NE);
  atomicAdd(&deg[d], 1);
}

__global__ __launch_bounds__(256) void k_bsum(const int* __restrict__ deg,
                                              int* __restrict__ bsum, int N) {
  int b = blockIdx.x;
  int chunk = (N + SB - 1) / SB;
  int s0 = b * chunk, s1 = min(s0 + chunk, N);
  int t = threadIdx.x;
  int sum = 0;
  for (int i = s0 + t; i < s1; i += 256) sum += deg[i];
#pragma unroll
  for (int o = 32; o; o >>= 1) sum += __shfl_xor(sum, o, 64);
  __shared__ int red[4];
  if ((t & 63) == 0) red[t >> 6] = sum;
  __syncthreads();
  if (t == 0) bsum[b] = red[0] + red[1] + red[2] + red[3];
}

// scan 256 bucket sums; bpre has 257 entries; bcur is a working copy for fillA
__global__ __launch_bounds__(256) void k_bscan(const int* __restrict__ bsum,
                                               int* __restrict__ bpre,
                                               int* __restrict__ bcur,
                                               int* __restrict__ off, int N) {
  __shared__ int s[256];
  int t = threadIdx.x;
  int v = bsum[t];
  s[t] = v;
  __syncthreads();
  for (int o = 1; o < 256; o <<= 1) {
    int u = (t >= o) ? s[t - o] : 0;
    __syncthreads();
    s[t] += u;
    __syncthreads();
  }
  bpre[t] = s[t] - v;
  bcur[t] = s[t] - v;
  if (t == 255) {
    off[N] = s[255];
    bpre[256] = s[255];
  }
}

__global__ __launch_bounds__(256) void k_cscan(const int* __restrict__ deg,
                                               const int* __restrict__ bpre,
                                               int* __restrict__ off, int N) {
  int b = blockIdx.x;
  int chunk = (N + SB - 1) / SB;
  int i = b * chunk + threadIdx.x;
  int t = threadIdx.x;
  int valid = (t < chunk && i < N);
  int v = valid ? deg[i] : 0;
  __shared__ int s[256];
  s[t] = v;
  __syncthreads();
  for (int o = 1; o < 256; o <<= 1) {
    int u = (t >= o) ? s[t - o] : 0;
    __syncthreads();
    s[t] += u;
    __syncthreads();
  }
  if (valid) off[i] = s[t] - v + bpre[b];
}

// ---- fillA: radix-partition edges into bucket-contiguous (dst,src) pairs ----
__global__ __launch_bounds__(256) void k_fillA(const int* __restrict__ ei,
                                               int* __restrict__ bcur,
                                               int2* __restrict__ pairs,
                                               int NE, int N, int chunk) {
  __shared__ int hist[256], base[256], cnt2[256];
  int t = threadIdx.x;
  hist[t] = 0;
  cnt2[t] = 0;
  __syncthreads();
  int ET = NE + N;
  int e0 = blockIdx.x * FTILE;
  int sv[16], dv[16];
#pragma unroll
  for (int j = 0; j < 16; ++j) {
    int e = e0 + t + 256 * j;
    if (e < ET) {
      sv[j] = (e < NE) ? ei[e] : (e - NE);
      dv[j] = (e < NE) ? ei[NE + e] : (e - NE);
      atomicAdd(&hist[dv[j] / chunk], 1);
    } else {
      dv[j] = -1;
    }
  }
  __syncthreads();
  if (hist[t] > 0) base[t] = atomicAdd(&bcur[t], hist[t]);
  __syncthreads();
#pragma unroll
  for (int j = 0; j < 16; ++j) {
    if (dv[j] >= 0) {
      int b = dv[j] / chunk;
      int r = atomicAdd(&cnt2[b], 1);
      pairs[base[b] + r] = make_int2(dv[j], sv[j]);
    }
  }
}

// ---- fillB: one block per bucket; LDS per-dst cursors; local scatter --------
__global__ __launch_bounds__(256) void k_fillB(const int2* __restrict__ pairs,
                                               const int* __restrict__ bpre,
                                               const int* __restrict__ off,
                                               int* __restrict__ csr, int N, int chunk) {
  __shared__ int cur[256];
  int b = blockIdx.x, t = threadIdx.x;
  int node0 = b * chunk;
  for (int i = t; i < chunk; i += 256)
    if (node0 + i < N) cur[i] = off[node0 + i];
  __syncthreads();
  int i0 = bpre[b], i1 = bpre[b + 1];
  for (int i = i0 + t; i < i1; i += 256) {
    int2 pr = pairs[i];
    int pos = atomicAdd(&cur[pr.x - node0], 1);
    csr[pos] = pr.y;
  }
}

// ---------------- prep: weight fragments + folded attention vectors ---------
__global__ __launch_bounds__(256) void k_prep(const float* __restrict__ W1,
                                              const float* __restrict__ W2,
                                              const float* __restrict__ a_src1,
                                              const float* __restrict__ a_dst1,
                                              const float* __restrict__ a_src2,
                                              const float* __restrict__ a_dst2,
                                              const float* __restrict__ b1,
                                              _Float16* __restrict__ w1hf,
                                              _Float16* __restrict__ w2f,
                                              float* __restrict__ wt1s,
                                              float* __restrict__ wt1d,
                                              float* __restrict__ b1p) {
  int idx = blockIdx.x * 256 + threadIdx.x;
  if (idx < 32768) {  // w1hf[h][ks][ct][l][i]
    int i = idx & 7, l = (idx >> 3) & 63, ct = (idx >> 9) & 3, ks = (idx >> 11) & 3,
        h = idx >> 13;
    int k = 32 * ks + 8 * (l >> 4) + i;
    int col = h * 64 + 16 * ct + (l & 15);
    w1hf[idx] = (_Float16)W1[k * 256 + col];
    return;
  }
  int i2 = idx - 32768;
  if (i2 < 16384) {  // w2f[ks][ct][l][i], A-side k' is layer-1 permuted index
    int i = i2 & 7, l = (i2 >> 3) & 63, ct = (i2 >> 9) & 3, ks = i2 >> 11;
    int kp = 32 * ks + 8 * (l >> 4) + i;
    int col = 16 * ct + (l & 15);
    w2f[i2] = (_Float16)W2[PERM(kp) * 64 + col];
    return;
  }
  int i3 = i2 - 16384;
  if (i3 < 512) {  // wt1s/wt1d[k*4+h]
    int h = i3 & 3, k = i3 >> 2;
    float ss = 0.f, sd = 0.f;
    for (int d = 0; d < 64; ++d) {
      float wv = W1[k * 256 + h * 64 + d];
      ss = fmaf(wv, a_src1[h * 64 + d], ss);
      sd = fmaf(wv, a_dst1[h * 64 + d], sd);
    }
    wt1s[i3] = ss;
    wt1d[i3] = sd;
    return;
  }
  int i4 = i3 - 512;
  if (i4 < 256) b1p[i4] = b1[PERM(i4)];
}

// ---------------- logits1: as1/ad1 = x @ wt1, also emit x16 -----------------
__global__ __launch_bounds__(256) void k_logits1(const float* __restrict__ x,
                                                 const float* __restrict__ wt1s,
                                                 const float* __restrict__ wt1d,
                                                 _Float16* __restrict__ x16,
                                                 float* __restrict__ as1,
                                                 float* __restrict__ ad1, int N) {
  int w = threadIdx.x >> 6, l = threadIdx.x & 63;
  int n = blockIdx.x * 4 + w;
  if (n >= N) return;
  float2 xv = *reinterpret_cast<const float2*>(x + (size_t)n * 128 + 2 * l);
  half2v xh;
  xh[0] = (_Float16)xv.x;
  xh[1] = (_Float16)xv.y;
  *reinterpret_cast<half2v*>(x16 + (size_t)n * 128 + 2 * l) = xh;
  float4 w0s = reinterpret_cast<const float4*>(wt1s)[2 * l];
  float4 w1s = reinterpret_cast<const float4*>(wt1s)[2 * l + 1];
  float4 w0d = reinterpret_cast<const float4*>(wt1d)[2 * l];
  float4 w1d = reinterpret_cast<const float4*>(wt1d)[2 * l + 1];
  float sa[4], sd[4];
  sa[0] = xv.x * w0s.x + xv.y * w1s.x;
  sa[1] = xv.x * w0s.y + xv.y * w1s.y;
  sa[2] = xv.x * w0s.z + xv.y * w1s.z;
  sa[3] = xv.x * w0s.w + xv.y * w1s.w;
  sd[0] = xv.x * w0d.x + xv.y * w1d.x;
  sd[1] = xv.x * w0d.y + xv.y * w1d.y;
  sd[2] = xv.x * w0d.z + xv.y * w1d.z;
  sd[3] = xv.x * w0d.w + xv.y * w1d.w;
#pragma unroll
  for (int o = 1; o <= 32; o <<= 1) {
#pragma unroll
    for (int h = 0; h < 4; ++h) {
      sa[h] += __shfl_xor(sa[h], o, 64);
      sd[h] += __shfl_xor(sd[h], o, 64);
    }
  }
  if (l == 0) {
#pragma unroll
    for (int h = 0; h < 4; ++h) {
      as1[n * 4 + h] = sa[h];
      ad1[n * 4 + h] = sd[h];
    }
  }
}

// ---------------- alpha precompute, layer 1 (H=4, fp16 output) --------------
__global__ __launch_bounds__(256) void k_alpha1(const float* __restrict__ as1,
                                                const float* __restrict__ ad1,
                                                const int* __restrict__ off,
                                                const int* __restrict__ csr,
                                                _Float16* __restrict__ alpha, int N) {
  int w = threadIdx.x >> 6, lane = threadIdx.x & 63;
  int n = blockIdx.x * 4 + w;
  if (n >= N) return;
  int eidx = lane >> 2, h = lane & 3;
  float adv = ad1[n * 4 + h];
  int e0 = off[n], e1 = off[n + 1];
  float m = -INFINITY;
  for (int base = e0; base < e1; base += 16) {
    int idx = base + eidx;
    if (idx < e1) {
      int s = csr[idx];
      float t = as1[s * 4 + h] + adv;
      t = t > 0.f ? t : LEAKY * t;
      m = fmaxf(m, t);
    }
  }
#pragma unroll
  for (int o = 4; o <= 32; o <<= 1) m = fmaxf(m, __shfl_xor(m, o, 64));
  float lp = 0.f;
  for (int base = e0; base < e1; base += 16) {
    int idx = base + eidx;
    if (idx < e1) {
      int s = csr[idx];
      float t = as1[s * 4 + h] + adv;
      t = t > 0.f ? t : LEAKY * t;
      float p = __expf(t - m);
      alpha[(size_t)idx * 4 + h] = (_Float16)p;
      lp += p;
    }
  }
#pragma unroll
  for (int o = 4; o <= 32; o <<= 1) lp += __shfl_xor(lp, o, 64);
  float rinv = 1.f / lp;
  for (int base = e0; base < e1; base += 16) {
    int idx = base + eidx;
    if (idx < e1) {
      float p = (float)alpha[(size_t)idx * 4 + h];
      alpha[(size_t)idx * 4 + h] = (_Float16)(p * rinv);
    }
  }
}

// ---------------- x-space aggregation: packed-fp16 accumulate, 16 edges deep -
// lane = slot*16 + kq; slot covers edge base+4u+slot, kq covers k = 8kq..8kq+7
__global__ __launch_bounds__(256) void k_xagg(const _Float16* __restrict__ x16,
                                              const _Float16* __restrict__ alpha,
                                              const int* __restrict__ off,
                                              const int* __restrict__ csr,
                                              _Float16* __restrict__ xagg, int N) {
  int w = threadIdx.x >> 6, l = threadIdx.x & 63;
  int n = blockIdx.x * 4 + w;
  if (n >= N) return;
  int slot = l >> 4, kq = l & 15;
  int e0 = off[n], e1 = off[n + 1];
  half2v acc[4][4];
#pragma unroll
  for (int h = 0; h < 4; ++h)
#pragma unroll
    for (int j = 0; j < 4; ++j) acc[h][j] = (half2v){(_Float16)0.f, (_Float16)0.f};
  const _Float16 zero16 = (_Float16)0.f;
  for (int base = e0; base < e1; base += 16) {
#pragma unroll
    for (int u = 0; u < 4; ++u) {
      int e = base + 4 * u + slot;
      int ec = min(e, e1 - 1);
      int src = csr[ec];
      half4 al = *reinterpret_cast<const half4*>(alpha + (size_t)ec * 4);
      if (e >= e1) al = (half4){zero16, zero16, zero16, zero16};
      half8 hv = *reinterpret_cast<const half8*>(x16 + (size_t)src * 128 + 8 * kq);
      half2v xp[4];
      xp[0] = (half2v){hv[0], hv[1]};
      xp[1] = (half2v){hv[2], hv[3]};
      xp[2] = (half2v){hv[4], hv[5]};
      xp[3] = (half2v){hv[6], hv[7]};
#pragma unroll
      for (int h = 0; h < 4; ++h) {
        half2v ah = (half2v){al[h], al[h]};
#pragma unroll
        for (int j = 0; j < 4; ++j) acc[h][j] = ah * xp[j] + acc[h][j];
      }
    }
  }
  // cross-slot reduce (xor 16, 32) in packed fp16
#pragma unroll
  for (int h = 0; h < 4; ++h)
#pragma unroll
    for (int j = 0; j < 4; ++j) {
      int v0 = __shfl_xor(__builtin_bit_cast(int, acc[h][j]), 16, 64);
      acc[h][j] = acc[h][j] + __builtin_bit_cast(half2v, v0);
      int v1 = __shfl_xor(__builtin_bit_cast(int, acc[h][j]), 32, 64);
      acc[h][j] = acc[h][j] + __builtin_bit_cast(half2v, v1);
    }
  if (slot == 0) {
#pragma unroll
    for (int h = 0; h < 4; ++h) {
      half8 o;
      o[0] = acc[h][0][0];
      o[1] = acc[h][0][1];
      o[2] = acc[h][1][0];
      o[3] = acc[h][1][1];
      o[4] = acc[h][2][0];
      o[5] = acc[h][2][1];
      o[6] = acc[h][3][0];
      o[7] = acc[h][3][1];
      *reinterpret_cast<half8*>(xagg + (size_t)n * 512 + h * 128 + 8 * kq) = o;
    }
  }
}

// ---------------- layer-1 GEMM over aggregated x: hout1p = ReLU(xagg@W1+b1) --
__global__ __launch_bounds__(256) void k_gemm1f(const _Float16* __restrict__ xagg,
                                                const _Float16* __restrict__ w1hf,
                                                const float* __restrict__ b1p,
                                                _Float16* __restrict__ hout1p, int N) {
  int w = threadIdx.x >> 6, l = threadIdx.x & 63;
  int n0 = blockIdx.x * 64 + 16 * w;
  int lrow = l & 15, lgrp = l >> 4;
  int arow = min(n0 + lrow, N - 1);
  f32x4 acc[4][4];
#pragma unroll
  for (int h = 0; h < 4; ++h)
#pragma unroll
    for (int ct = 0; ct < 4; ++ct) acc[h][ct] = (f32x4){0.f, 0.f, 0.f, 0.f};
#pragma unroll
  for (int h = 0; h < 4; ++h) {
#pragma unroll
    for (int ks = 0; ks < 4; ++ks) {
      half8 af = *reinterpret_cast<const half8*>(xagg + (size_t)arow * 512 + h * 128 +
                                                 32 * ks + 8 * lgrp);
      const half8* bp =
          reinterpret_cast<const half8*>(w1hf) + (size_t)((h * 4 + ks) * 4) * 64 + l;
#pragma unroll
      for (int ct = 0; ct < 4; ++ct) {
        half8 bf = bp[ct * 64];
        acc[h][ct] = __builtin_amdgcn_mfma_f32_16x16x32_f16(af, bf, acc[h][ct], 0, 0, 0);
      }
    }
  }
  int rbase = n0 + 4 * lgrp;
#pragma unroll
  for (int h = 0; h < 4; ++h) {
    float4 bv = *reinterpret_cast<const float4*>(b1p + h * 64 + lrow * 4);
#pragma unroll
    for (int r = 0; r < 4; ++r) {
      int n = rbase + r;
      if (n < N) {
        half4 o;
        o[0] = (_Float16)fmaxf(acc[h][0][r] + bv.x, 0.f);
        o[1] = (_Float16)fmaxf(acc[h][1][r] + bv.y, 0.f);
        o[2] = (_Float16)fmaxf(acc[h][2][r] + bv.z, 0.f);
        o[3] = (_Float16)fmaxf(acc[h][3][r] + bv.w, 0.f);
        *reinterpret_cast<half4*>(hout1p + (size_t)n * 256 + h * 64 + lrow * 4) = o;
      }
    }
  }
}

// ---------------- Layer 2 GEMM (MFMA) + fused as2/ad2 epilogue ---------------
__global__ __launch_bounds__(256) void k_gemm2(const _Float16* __restrict__ hin,
                                               const _Float16* __restrict__ w2f,
                                               const float* __restrict__ a_src2,
                                               const float* __restrict__ a_dst2,
                                               _Float16* __restrict__ h2p,
                                               float* __restrict__ as2,
                                               float* __restrict__ ad2, int N) {
  int w = threadIdx.x >> 6, l = threadIdx.x & 63;
  int n0 = blockIdx.x * 64 + 16 * w;
  int lrow = l & 15, lgrp = l >> 4;
  int arow = min(n0 + lrow, N - 1);
  f32x4 acc[4];
#pragma unroll
  for (int ct = 0; ct < 4; ++ct) acc[ct] = (f32x4){0.f, 0.f, 0.f, 0.f};
#pragma unroll
  for (int ks = 0; ks < 8; ++ks) {
    half8 af =
        *reinterpret_cast<const half8*>(hin + (size_t)arow * 256 + 32 * ks + 8 * lgrp);
    const half8* bp = reinterpret_cast<const half8*>(w2f) + (size_t)(ks * 4) * 64 + l;
#pragma unroll
    for (int ct = 0; ct < 4; ++ct) {
      half8 bf = bp[ct * 64];
      acc[ct] = __builtin_amdgcn_mfma_f32_16x16x32_f16(af, bf, acc[ct], 0, 0, 0);
    }
  }
  float ascol[4], adcol[4];
#pragma unroll
  for (int ct = 0; ct < 4; ++ct) {
    ascol[ct] = a_src2[16 * ct + lrow];
    adcol[ct] = a_dst2[16 * ct + lrow];
  }
  int rbase = n0 + 4 * lgrp;
#pragma unroll
  for (int r = 0; r < 4; ++r) {
    int row = rbase + r;
    bool ok = row < N;
    float sa = 0.f, sd = 0.f;
    half4 o;
#pragma unroll
    for (int ct = 0; ct < 4; ++ct) {
      float v = acc[ct][r];
      o[ct] = (_Float16)v;
      sa = fmaf(v, ascol[ct], sa);
      sd = fmaf(v, adcol[ct], sd);
    }
    if (ok) *reinterpret_cast<half4*>(h2p + (size_t)row * 64 + lrow * 4) = o;
#pragma unroll
    for (int oo = 1; oo <= 8; oo <<= 1) {
      sa += __shfl_xor(sa, oo, 64);
      sd += __shfl_xor(sd, oo, 64);
    }
    if (ok && lrow == 0) {
      as2[row] = sa;
      ad2[row] = sd;
    }
  }
}

// ---------------- Layer 2: fused softmax + aggregation (wave per node) -------
// pass1/2: all 64 lanes over edges (max, sum-exp). pass3: 8 slots x 8 lanes,
// half8 (16B) gathers, p recomputed per edge (as2 is L2-resident).
__global__ __launch_bounds__(256) void k_agg2(const _Float16* __restrict__ h2p,
                                              const float* __restrict__ as2,
                                              const float* __restrict__ ad2,
                                              const float* __restrict__ b2,
                                              const int* __restrict__ off,
                                              const int* __restrict__ csr,
                                              float* __restrict__ out, int N) {
  int w = threadIdx.x >> 6, lane = threadIdx.x & 63;
  int n = blockIdx.x * 4 + w;
  if (n >= N) return;
  float adv = ad2[n];
  int e0 = off[n], e1 = off[n + 1];
  float m = -INFINITY;
  for (int idx = e0 + lane; idx < e1; idx += 64) {
    float t = as2[csr[idx]] + adv;
    t = t > 0.f ? t : LEAKY * t;
    m = fmaxf(m, t);
  }
#pragma unroll
  for (int o = 1; o <= 32; o <<= 1) m = fmaxf(m, __shfl_xor(m, o, 64));
  float lp = 0.f;
  for (int idx = e0 + lane; idx < e1; idx += 64) {
    float t = as2[csr[idx]] + adv;
    t = t > 0.f ? t : LEAKY * t;
    lp += __expf(t - m);
  }
#pragma unroll
  for (int o = 1; o <= 32; o <<= 1) lp += __shfl_xor(lp, o, 64);
  float rinv = 1.f / lp;
  // pass 3: gather-accumulate
  int slot = lane >> 3, q = lane & 7;
  float acc[8];
#pragma unroll
  for (int k = 0; k < 8; ++k) acc[k] = 0.f;
  for (int base = e0; base < e1; base += 16) {
#pragma unroll
    for (int u = 0; u < 2; ++u) {
      int e = base + 8 * u + slot;
      int ec = min(e, e1 - 1);
      int s = csr[ec];
      float t = as2[s] + adv;
      t = t > 0.f ? t : LEAKY * t;
      float p = (e < e1) ? __expf(t - m) * rinv : 0.f;
      half8 hv = *reinterpret_cast<const half8*>(h2p + (size_t)s * 64 + 8 * q);
#pragma unroll
      for (int k = 0; k < 8; ++k) acc[k] = fmaf(p, (float)hv[k], acc[k]);
    }
  }
#pragma unroll
  for (int k = 0; k < 8; ++k) {
    acc[k] += __shfl_xor(acc[k], 8, 64);
    acc[k] += __shfl_xor(acc[k], 16, 64);
    acc[k] += __shfl_xor(acc[k], 32, 64);
  }
  if (slot == 0) {
    // storage p = 8q + k  ->  orig col = ((k&3)<<4) | (2q + (k>>2))
#pragma unroll
    for (int k = 0; k < 8; ++k) {
      int col = ((k & 3) << 4) + 2 * q + (k >> 2);
      out[(size_t)n * 64 + col] = acc[k] + b2[col];
    }
  }
}

extern "C" void kernel_launch(void* const* d_in, const int* in_sizes, int n_in,
                              void* d_out, int out_size, void* d_ws, size_t ws_size,
                              hipStream_t stream) {
  const float* x = (const float*)d_in[0];
  const int* ei = (const int*)d_in[1];
  const float* W1 = (const float*)d_in[2];
  const float* a_src1 = (const float*)d_in[3];
  const float* a_dst1 = (const float*)d_in[4];
  const float* b1 = (const float*)d_in[5];
  const float* W2 = (const float*)d_in[6];
  const float* a_src2 = (const float*)d_in[7];
  const float* a_dst2 = (const float*)d_in[8];
  const float* b2 = (const float*)d_in[9];
  float* out = (float*)d_out;

  const int N = in_sizes[0] / 128;
  const int NE = in_sizes[1] / 2;
  const int ET = NE + N;
  const int chunk = ceil_div(N, SB);

  char* p = (char*)d_ws;
  auto alloc = [&](size_t bytes) {
    char* r = p;
    p += (bytes + 255) & ~(size_t)255;
    return r;
  };
  int* deg = (int*)alloc((size_t)N * 4);
  int* off = (int*)alloc((size_t)(N + 1) * 4);
  int* csr = (int*)alloc((size_t)ET * 4);
  int* bsum = (int*)alloc((size_t)SB * 4);
  int* bpre = (int*)alloc((size_t)(SB + 1) * 4);
  int* bcur = (int*)alloc((size_t)SB * 4);
  int2* pairs = (int2*)alloc((size_t)ET * 8);
  _Float16* w1hf = (_Float16*)alloc((size_t)32768 * 2);
  _Float16* w2f = (_Float16*)alloc((size_t)16384 * 2);
  float* wt1s = (float*)alloc((size_t)512 * 4);
  float* wt1d = (float*)alloc((size_t)512 * 4);
  float* b1p = (float*)alloc((size_t)256 * 4);
  _Float16* x16 = (_Float16*)alloc((size_t)N * 128 * 2);
  _Float16* xagg = (_Float16*)alloc((size_t)N * 512 * 2);
  _Float16* hout1p = (_Float16*)alloc((size_t)N * 256 * 2);
  float* as1 = (float*)alloc((size_t)N * 4 * 4);
  float* ad1 = (float*)alloc((size_t)N * 4 * 4);
  _Float16* alpha1 = (_Float16*)alloc((size_t)ET * 4 * 2);
  _Float16* h2p = x16;  // reuse: x16 dead after k_xagg
  float* as2 = (float*)alloc((size_t)N * 4);
  float* ad2 = (float*)alloc((size_t)N * 4);

  hipMemsetAsync(deg, 0, (size_t)N * 4, stream);
  k_count<<<ceil_div(ET, 256), 256, 0, stream>>>(ei, deg, NE, N);
  k_bsum<<<SB, 256, 0, stream>>>(deg, bsum, N);
  k_bscan<<<1, 256, 0, stream>>>(bsum, bpre, bcur, off, N);
  k_cscan<<<SB, 256, 0, stream>>>(deg, bpre, off, N);
  k_fillA<<<ceil_div(ET, FTILE), 256, 0, stream>>>(ei, bcur, pairs, NE, N, chunk);
  k_fillB<<<SB, 256, 0, stream>>>(pairs, bpre, off, csr, N, chunk);
  k_prep<<<198, 256, 0, stream>>>(W1, W2, a_src1, a_dst1, a_src2, a_dst2, b1,
                                  w1hf, w2f, wt1s, wt1d, b1p);

  k_logits1<<<ceil_div(N, 4), 256, 0, stream>>>(x, wt1s, wt1d, x16, as1, ad1, N);
  k_alpha1<<<ceil_div(N, 4), 256, 0, stream>>>(as1, ad1, off, csr, alpha1, N);
  k_xagg<<<ceil_div(N, 4), 256, 0, stream>>>(x16, alpha1, off, csr, xagg, N);
  k_gemm1f<<<ceil_div(N, 64), 256, 0, stream>>>(xagg, w1hf, b1p, hout1p, N);
  k_gemm2<<<ceil_div(N, 64), 256, 0, stream>>>(hout1p, w2f, a_src2, a_dst2, h2p,
                                               as2, ad2, N);
  k_agg2<<<ceil_div(N, 4), 256, 0, stream>>>(h2p, as2, ad2, b2, off, csr, out, N);
}

// Round 12
// 237.208 us; speedup vs baseline: 1.4308x; 1.0155x over previous
//
#include <hip/hip_runtime.h>
#include <math.h>

#define LEAKY 0.2f
#define SB 256
#define FTILE 4096

typedef _Float16 half2v __attribute__((ext_vector_type(2)));
typedef _Float16 half4 __attribute__((ext_vector_type(4)));
typedef _Float16 half8 __attribute__((ext_vector_type(8)));
typedef float f32x4 __attribute__((ext_vector_type(4)));

static inline int ceil_div(int a, int b) { return (a + b - 1) / b; }

// storage index p -> original column, for 64-col groups
__device__ __forceinline__ int PERM(int p) {
  int q = p & 63;
  return (p & ~63) | (((q & 3) << 4) | (q >> 2));
}

// ---------------- zero helper (replaces pathological rocclr fill) -----------
__global__ __launch_bounds__(256) void k_zero(int4* __restrict__ buf, int n4) {
  int i = blockIdx.x * 256 + threadIdx.x;
  if (i < n4) buf[i] = make_int4(0, 0, 0, 0);
}

// ---------------- CSR build ----------------
__global__ __launch_bounds__(256) void k_count(const int* __restrict__ ei,
                                               int* __restrict__ deg, int NE, int N) {
  int e = blockIdx.x * 256 + threadIdx.x;
  int ET = NE + N;
  if (e >= ET) return;
  int d = (e < NE) ? ei[NE + e] : (e - NE);
  atomicAdd(&deg[d], 1);
}

__global__ __launch_bounds__(256) void k_bsum(const int* __restrict__ deg,
                                              int* __restrict__ bsum, int N) {
  int b = blockIdx.x;
  int chunk = (N + SB - 1) / SB;
  int s0 = b * chunk, s1 = min(s0 + chunk, N);
  int t = threadIdx.x;
  int sum = 0;
  for (int i = s0 + t; i < s1; i += 256) sum += deg[i];
#pragma unroll
  for (int o = 32; o; o >>= 1) sum += __shfl_xor(sum, o, 64);
  __shared__ int red[4];
  if ((t & 63) == 0) red[t >> 6] = sum;
  __syncthreads();
  if (t == 0) bsum[b] = red[0] + red[1] + red[2] + red[3];
}

// scan 256 bucket sums; bpre has 257 entries; bcur is a working copy for fillA
__global__ __launch_bounds__(256) void k_bscan(const int* __restrict__ bsum,
                                               int* __restrict__ bpre,
                                               int* __restrict__ bcur,
                                               int* __restrict__ off, int N) {
  __shared__ int s[256];
  int t = threadIdx.x;
  int v = bsum[t];
  s[t] = v;
  __syncthreads();
  for (int o = 1; o < 256; o <<= 1) {
    int u = (t >= o) ? s[t - o] : 0;
    __syncthreads();
    s[t] += u;
    __syncthreads();
  }
  bpre[t] = s[t] - v;
  bcur[t] = s[t] - v;
  if (t == 255) {
    off[N] = s[255];
    bpre[256] = s[255];
  }
}

__global__ __launch_bounds__(256) void k_cscan(const int* __restrict__ deg,
                                               const int* __restrict__ bpre,
                                               int* __restrict__ off, int N) {
  int b = blockIdx.x;
  int chunk = (N + SB - 1) / SB;
  int i = b * chunk + threadIdx.x;
  int t = threadIdx.x;
  int valid = (t < chunk && i < N);
  int v = valid ? deg[i] : 0;
  __shared__ int s[256];
  s[t] = v;
  __syncthreads();
  for (int o = 1; o < 256; o <<= 1) {
    int u = (t >= o) ? s[t - o] : 0;
    __syncthreads();
    s[t] += u;
    __syncthreads();
  }
  if (valid) off[i] = s[t] - v + bpre[b];
}

// ---- fillA: radix-partition edges into bucket-contiguous (dst,src) pairs ----
__global__ __launch_bounds__(256) void k_fillA(const int* __restrict__ ei,
                                               int* __restrict__ bcur,
                                               int2* __restrict__ pairs,
                                               int NE, int N, int chunk) {
  __shared__ int hist[256], base[256], cnt2[256];
  int t = threadIdx.x;
  hist[t] = 0;
  cnt2[t] = 0;
  __syncthreads();
  int ET = NE + N;
  int e0 = blockIdx.x * FTILE;
  int sv[16], dv[16];
#pragma unroll
  for (int j = 0; j < 16; ++j) {
    int e = e0 + t + 256 * j;
    if (e < ET) {
      sv[j] = (e < NE) ? ei[e] : (e - NE);
      dv[j] = (e < NE) ? ei[NE + e] : (e - NE);
      atomicAdd(&hist[dv[j] / chunk], 1);
    } else {
      dv[j] = -1;
    }
  }
  __syncthreads();
  if (hist[t] > 0) base[t] = atomicAdd(&bcur[t], hist[t]);
  __syncthreads();
#pragma unroll
  for (int j = 0; j < 16; ++j) {
    if (dv[j] >= 0) {
      int b = dv[j] / chunk;
      int r = atomicAdd(&cnt2[b], 1);
      pairs[base[b] + r] = make_int2(dv[j], sv[j]);
    }
  }
}

// ---- fillB: one block per bucket; LDS per-dst cursors; local scatter --------
__global__ __launch_bounds__(256) void k_fillB(const int2* __restrict__ pairs,
                                               const int* __restrict__ bpre,
                                               const int* __restrict__ off,
                                               int* __restrict__ csr, int N, int chunk) {
  __shared__ int cur[256];
  int b = blockIdx.x, t = threadIdx.x;
  int node0 = b * chunk;
  for (int i = t; i < chunk; i += 256)
    if (node0 + i < N) cur[i] = off[node0 + i];
  __syncthreads();
  int i0 = bpre[b], i1 = bpre[b + 1];
  for (int i = i0 + t; i < i1; i += 256) {
    int2 pr = pairs[i];
    int pos = atomicAdd(&cur[pr.x - node0], 1);
    csr[pos] = pr.y;
  }
}

// ---------------- prep: weight fragments + folded attention vectors ---------
__global__ __launch_bounds__(256) void k_prep(const float* __restrict__ W1,
                                              const float* __restrict__ W2,
                                              const float* __restrict__ a_src1,
                                              const float* __restrict__ a_dst1,
                                              const float* __restrict__ a_src2,
                                              const float* __restrict__ a_dst2,
                                              const float* __restrict__ b1,
                                              _Float16* __restrict__ w1hf,
                                              _Float16* __restrict__ w2f,
                                              float* __restrict__ wt1s,
                                              float* __restrict__ wt1d,
                                              float* __restrict__ b1p) {
  int idx = blockIdx.x * 256 + threadIdx.x;
  if (idx < 32768) {  // w1hf[h][ks][ct][l][i]
    int i = idx & 7, l = (idx >> 3) & 63, ct = (idx >> 9) & 3, ks = (idx >> 11) & 3,
        h = idx >> 13;
    int k = 32 * ks + 8 * (l >> 4) + i;
    int col = h * 64 + 16 * ct + (l & 15);
    w1hf[idx] = (_Float16)W1[k * 256 + col];
    return;
  }
  int i2 = idx - 32768;
  if (i2 < 16384) {  // w2f[ks][ct][l][i], A-side k' is layer-1 permuted index
    int i = i2 & 7, l = (i2 >> 3) & 63, ct = (i2 >> 9) & 3, ks = i2 >> 11;
    int kp = 32 * ks + 8 * (l >> 4) + i;
    int col = 16 * ct + (l & 15);
    w2f[i2] = (_Float16)W2[PERM(kp) * 64 + col];
    return;
  }
  int i3 = i2 - 16384;
  if (i3 < 512) {  // wt1s/wt1d[k*4+h]
    int h = i3 & 3, k = i3 >> 2;
    float ss = 0.f, sd = 0.f;
    for (int d = 0; d < 64; ++d) {
      float wv = W1[k * 256 + h * 64 + d];
      ss = fmaf(wv, a_src1[h * 64 + d], ss);
      sd = fmaf(wv, a_dst1[h * 64 + d], sd);
    }
    wt1s[i3] = ss;
    wt1d[i3] = sd;
    return;
  }
  int i4 = i3 - 512;
  if (i4 < 256) b1p[i4] = b1[PERM(i4)];
}

// ---------------- logits1: as1/ad1 = x @ wt1, also emit x16 -----------------
__global__ __launch_bounds__(256) void k_logits1(const float* __restrict__ x,
                                                 const float* __restrict__ wt1s,
                                                 const float* __restrict__ wt1d,
                                                 _Float16* __restrict__ x16,
                                                 float* __restrict__ as1,
                                                 float* __restrict__ ad1, int N) {
  int w = threadIdx.x >> 6, l = threadIdx.x & 63;
  int n = blockIdx.x * 4 + w;
  if (n >= N) return;
  float2 xv = *reinterpret_cast<const float2*>(x + (size_t)n * 128 + 2 * l);
  half2v xh;
  xh[0] = (_Float16)xv.x;
  xh[1] = (_Float16)xv.y;
  *reinterpret_cast<half2v*>(x16 + (size_t)n * 128 + 2 * l) = xh;
  float4 w0s = reinterpret_cast<const float4*>(wt1s)[2 * l];
  float4 w1s = reinterpret_cast<const float4*>(wt1s)[2 * l + 1];
  float4 w0d = reinterpret_cast<const float4*>(wt1d)[2 * l];
  float4 w1d = reinterpret_cast<const float4*>(wt1d)[2 * l + 1];
  float sa[4], sd[4];
  sa[0] = xv.x * w0s.x + xv.y * w1s.x;
  sa[1] = xv.x * w0s.y + xv.y * w1s.y;
  sa[2] = xv.x * w0s.z + xv.y * w1s.z;
  sa[3] = xv.x * w0s.w + xv.y * w1s.w;
  sd[0] = xv.x * w0d.x + xv.y * w1d.x;
  sd[1] = xv.x * w0d.y + xv.y * w1d.y;
  sd[2] = xv.x * w0d.z + xv.y * w1d.z;
  sd[3] = xv.x * w0d.w + xv.y * w1d.w;
#pragma unroll
  for (int o = 1; o <= 32; o <<= 1) {
#pragma unroll
    for (int h = 0; h < 4; ++h) {
      sa[h] += __shfl_xor(sa[h], o, 64);
      sd[h] += __shfl_xor(sd[h], o, 64);
    }
  }
  if (l == 0) {
#pragma unroll
    for (int h = 0; h < 4; ++h) {
      as1[n * 4 + h] = sa[h];
      ad1[n * 4 + h] = sd[h];
    }
  }
}

// ---------------- alpha precompute, layer 1 (H=4, fp16 output) --------------
__global__ __launch_bounds__(256) void k_alpha1(const float* __restrict__ as1,
                                                const float* __restrict__ ad1,
                                                const int* __restrict__ off,
                                                const int* __restrict__ csr,
                                                _Float16* __restrict__ alpha, int N) {
  int w = threadIdx.x >> 6, lane = threadIdx.x & 63;
  int n = blockIdx.x * 4 + w;
  if (n >= N) return;
  int eidx = lane >> 2, h = lane & 3;
  float adv = ad1[n * 4 + h];
  int e0 = off[n], e1 = off[n + 1];
  float m = -INFINITY;
  for (int base = e0; base < e1; base += 16) {
    int idx = base + eidx;
    if (idx < e1) {
      int s = csr[idx];
      float t = as1[s * 4 + h] + adv;
      t = t > 0.f ? t : LEAKY * t;
      m = fmaxf(m, t);
    }
  }
#pragma unroll
  for (int o = 4; o <= 32; o <<= 1) m = fmaxf(m, __shfl_xor(m, o, 64));
  float lp = 0.f;
  for (int base = e0; base < e1; base += 16) {
    int idx = base + eidx;
    if (idx < e1) {
      int s = csr[idx];
      float t = as1[s * 4 + h] + adv;
      t = t > 0.f ? t : LEAKY * t;
      float p = __expf(t - m);
      alpha[(size_t)idx * 4 + h] = (_Float16)p;
      lp += p;
    }
  }
#pragma unroll
  for (int o = 4; o <= 32; o <<= 1) lp += __shfl_xor(lp, o, 64);
  float rinv = 1.f / lp;
  for (int base = e0; base < e1; base += 16) {
    int idx = base + eidx;
    if (idx < e1) {
      float p = (float)alpha[(size_t)idx * 4 + h];
      alpha[(size_t)idx * 4 + h] = (_Float16)(p * rinv);
    }
  }
}

// ---------------- x-space aggregation: packed-fp16 accumulate, 16 edges deep -
// lane = slot*16 + kq; slot covers edge base+4u+slot, kq covers k = 8kq..8kq+7
__global__ __launch_bounds__(256) void k_xagg(const _Float16* __restrict__ x16,
                                              const _Float16* __restrict__ alpha,
                                              const int* __restrict__ off,
                                              const int* __restrict__ csr,
                                              _Float16* __restrict__ xagg, int N) {
  int w = threadIdx.x >> 6, l = threadIdx.x & 63;
  int n = blockIdx.x * 4 + w;
  if (n >= N) return;
  int slot = l >> 4, kq = l & 15;
  int e0 = off[n], e1 = off[n + 1];
  half2v acc[4][4];
#pragma unroll
  for (int h = 0; h < 4; ++h)
#pragma unroll
    for (int j = 0; j < 4; ++j) acc[h][j] = (half2v){(_Float16)0.f, (_Float16)0.f};
  const _Float16 zero16 = (_Float16)0.f;
  for (int base = e0; base < e1; base += 16) {
#pragma unroll
    for (int u = 0; u < 4; ++u) {
      int e = base + 4 * u + slot;
      int ec = min(e, e1 - 1);
      int src = csr[ec];
      half4 al = *reinterpret_cast<const half4*>(alpha + (size_t)ec * 4);
      if (e >= e1) al = (half4){zero16, zero16, zero16, zero16};
      half8 hv = *reinterpret_cast<const half8*>(x16 + (size_t)src * 128 + 8 * kq);
      half2v xp[4];
      xp[0] = (half2v){hv[0], hv[1]};
      xp[1] = (half2v){hv[2], hv[3]};
      xp[2] = (half2v){hv[4], hv[5]};
      xp[3] = (half2v){hv[6], hv[7]};
#pragma unroll
      for (int h = 0; h < 4; ++h) {
        half2v ah = (half2v){al[h], al[h]};
#pragma unroll
        for (int j = 0; j < 4; ++j) acc[h][j] = ah * xp[j] + acc[h][j];
      }
    }
  }
  // cross-slot reduce (xor 16, 32) in packed fp16
#pragma unroll
  for (int h = 0; h < 4; ++h)
#pragma unroll
    for (int j = 0; j < 4; ++j) {
      int v0 = __shfl_xor(__builtin_bit_cast(int, acc[h][j]), 16, 64);
      acc[h][j] = acc[h][j] + __builtin_bit_cast(half2v, v0);
      int v1 = __shfl_xor(__builtin_bit_cast(int, acc[h][j]), 32, 64);
      acc[h][j] = acc[h][j] + __builtin_bit_cast(half2v, v1);
    }
  if (slot == 0) {
#pragma unroll
    for (int h = 0; h < 4; ++h) {
      half8 o;
      o[0] = acc[h][0][0];
      o[1] = acc[h][0][1];
      o[2] = acc[h][1][0];
      o[3] = acc[h][1][1];
      o[4] = acc[h][2][0];
      o[5] = acc[h][2][1];
      o[6] = acc[h][3][0];
      o[7] = acc[h][3][1];
      *reinterpret_cast<half8*>(xagg + (size_t)n * 512 + h * 128 + 8 * kq) = o;
    }
  }
}

// ---------------- layer-1 GEMM over aggregated x: hout1p = ReLU(xagg@W1+b1) --
__global__ __launch_bounds__(256) void k_gemm1f(const _Float16* __restrict__ xagg,
                                                const _Float16* __restrict__ w1hf,
                                                const float* __restrict__ b1p,
                                                _Float16* __restrict__ hout1p, int N) {
  int w = threadIdx.x >> 6, l = threadIdx.x & 63;
  int n0 = blockIdx.x * 64 + 16 * w;
  int lrow = l & 15, lgrp = l >> 4;
  int arow = min(n0 + lrow, N - 1);
  f32x4 acc[4][4];
#pragma unroll
  for (int h = 0; h < 4; ++h)
#pragma unroll
    for (int ct = 0; ct < 4; ++ct) acc[h][ct] = (f32x4){0.f, 0.f, 0.f, 0.f};
#pragma unroll
  for (int h = 0; h < 4; ++h) {
#pragma unroll
    for (int ks = 0; ks < 4; ++ks) {
      half8 af = *reinterpret_cast<const half8*>(xagg + (size_t)arow * 512 + h * 128 +
                                                 32 * ks + 8 * lgrp);
      const half8* bp =
          reinterpret_cast<const half8*>(w1hf) + (size_t)((h * 4 + ks) * 4) * 64 + l;
#pragma unroll
      for (int ct = 0; ct < 4; ++ct) {
        half8 bf = bp[ct * 64];
        acc[h][ct] = __builtin_amdgcn_mfma_f32_16x16x32_f16(af, bf, acc[h][ct], 0, 0, 0);
      }
    }
  }
  int rbase = n0 + 4 * lgrp;
#pragma unroll
  for (int h = 0; h < 4; ++h) {
    float4 bv = *reinterpret_cast<const float4*>(b1p + h * 64 + lrow * 4);
#pragma unroll
    for (int r = 0; r < 4; ++r) {
      int n = rbase + r;
      if (n < N) {
        half4 o;
        o[0] = (_Float16)fmaxf(acc[h][0][r] + bv.x, 0.f);
        o[1] = (_Float16)fmaxf(acc[h][1][r] + bv.y, 0.f);
        o[2] = (_Float16)fmaxf(acc[h][2][r] + bv.z, 0.f);
        o[3] = (_Float16)fmaxf(acc[h][3][r] + bv.w, 0.f);
        *reinterpret_cast<half4*>(hout1p + (size_t)n * 256 + h * 64 + lrow * 4) = o;
      }
    }
  }
}

// ---------------- Layer 2 GEMM (MFMA) + fused as2/ad2 epilogue ---------------
__global__ __launch_bounds__(256) void k_gemm2(const _Float16* __restrict__ hin,
                                               const _Float16* __restrict__ w2f,
                                               const float* __restrict__ a_src2,
                                               const float* __restrict__ a_dst2,
                                               _Float16* __restrict__ h2p,
                                               float* __restrict__ as2,
                                               float* __restrict__ ad2, int N) {
  int w = threadIdx.x >> 6, l = threadIdx.x & 63;
  int n0 = blockIdx.x * 64 + 16 * w;
  int lrow = l & 15, lgrp = l >> 4;
  int arow = min(n0 + lrow, N - 1);
  f32x4 acc[4];
#pragma unroll
  for (int ct = 0; ct < 4; ++ct) acc[ct] = (f32x4){0.f, 0.f, 0.f, 0.f};
#pragma unroll
  for (int ks = 0; ks < 8; ++ks) {
    half8 af =
        *reinterpret_cast<const half8*>(hin + (size_t)arow * 256 + 32 * ks + 8 * lgrp);
    const half8* bp = reinterpret_cast<const half8*>(w2f) + (size_t)(ks * 4) * 64 + l;
#pragma unroll
    for (int ct = 0; ct < 4; ++ct) {
      half8 bf = bp[ct * 64];
      acc[ct] = __builtin_amdgcn_mfma_f32_16x16x32_f16(af, bf, acc[ct], 0, 0, 0);
    }
  }
  float ascol[4], adcol[4];
#pragma unroll
  for (int ct = 0; ct < 4; ++ct) {
    ascol[ct] = a_src2[16 * ct + lrow];
    adcol[ct] = a_dst2[16 * ct + lrow];
  }
  int rbase = n0 + 4 * lgrp;
#pragma unroll
  for (int r = 0; r < 4; ++r) {
    int row = rbase + r;
    bool ok = row < N;
    float sa = 0.f, sd = 0.f;
    half4 o;
#pragma unroll
    for (int ct = 0; ct < 4; ++ct) {
      float v = acc[ct][r];
      o[ct] = (_Float16)v;
      sa = fmaf(v, ascol[ct], sa);
      sd = fmaf(v, adcol[ct], sd);
    }
    if (ok) *reinterpret_cast<half4*>(h2p + (size_t)row * 64 + lrow * 4) = o;
#pragma unroll
    for (int oo = 1; oo <= 8; oo <<= 1) {
      sa += __shfl_xor(sa, oo, 64);
      sd += __shfl_xor(sd, oo, 64);
    }
    if (ok && lrow == 0) {
      as2[row] = sa;
      ad2[row] = sd;
    }
  }
}

// ---------------- Layer 2: fused softmax + aggregation, 2-pass ---------------
// pass1: max (64 lanes). pass2: gather with UNNORMALIZED p, accumulate acc+lp,
// scale by 1/lp at the end.
__global__ __launch_bounds__(256) void k_agg2(const _Float16* __restrict__ h2p,
                                              const float* __restrict__ as2,
                                              const float* __restrict__ ad2,
                                              const float* __restrict__ b2,
                                              const int* __restrict__ off,
                                              const int* __restrict__ csr,
                                              float* __restrict__ out, int N) {
  int w = threadIdx.x >> 6, lane = threadIdx.x & 63;
  int n = blockIdx.x * 4 + w;
  if (n >= N) return;
  float adv = ad2[n];
  int e0 = off[n], e1 = off[n + 1];
  float m = -INFINITY;
  for (int idx = e0 + lane; idx < e1; idx += 64) {
    float t = as2[csr[idx]] + adv;
    t = t > 0.f ? t : LEAKY * t;
    m = fmaxf(m, t);
  }
#pragma unroll
  for (int o = 1; o <= 32; o <<= 1) m = fmaxf(m, __shfl_xor(m, o, 64));
  // pass 2: gather-accumulate with unnormalized weights
  int slot = lane >> 3, q = lane & 7;
  float acc[8];
  float lp = 0.f;
#pragma unroll
  for (int k = 0; k < 8; ++k) acc[k] = 0.f;
  for (int base = e0; base < e1; base += 16) {
#pragma unroll
    for (int u = 0; u < 2; ++u) {
      int e = base + 8 * u + slot;
      int ec = min(e, e1 - 1);
      int s = csr[ec];
      float t = as2[s] + adv;
      t = t > 0.f ? t : LEAKY * t;
      float p = (e < e1) ? __expf(t - m) : 0.f;
      lp += p;
      half8 hv = *reinterpret_cast<const half8*>(h2p + (size_t)s * 64 + 8 * q);
#pragma unroll
      for (int k = 0; k < 8; ++k) acc[k] = fmaf(p, (float)hv[k], acc[k]);
    }
  }
#pragma unroll
  for (int o = 8; o <= 32; o <<= 1) {
    lp += __shfl_xor(lp, o, 64);
#pragma unroll
    for (int k = 0; k < 8; ++k) acc[k] += __shfl_xor(acc[k], o, 64);
  }
  if (slot == 0) {
    float rinv = 1.f / lp;
    // storage p = 8q + k  ->  orig col = ((k&3)<<4) | (2q + (k>>2))
#pragma unroll
    for (int k = 0; k < 8; ++k) {
      int col = ((k & 3) << 4) + 2 * q + (k >> 2);
      out[(size_t)n * 64 + col] = acc[k] * rinv + b2[col];
    }
  }
}

extern "C" void kernel_launch(void* const* d_in, const int* in_sizes, int n_in,
                              void* d_out, int out_size, void* d_ws, size_t ws_size,
                              hipStream_t stream) {
  const float* x = (const float*)d_in[0];
  const int* ei = (const int*)d_in[1];
  const float* W1 = (const float*)d_in[2];
  const float* a_src1 = (const float*)d_in[3];
  const float* a_dst1 = (const float*)d_in[4];
  const float* b1 = (const float*)d_in[5];
  const float* W2 = (const float*)d_in[6];
  const float* a_src2 = (const float*)d_in[7];
  const float* a_dst2 = (const float*)d_in[8];
  const float* b2 = (const float*)d_in[9];
  float* out = (float*)d_out;

  const int N = in_sizes[0] / 128;
  const int NE = in_sizes[1] / 2;
  const int ET = NE + N;
  const int chunk = ceil_div(N, SB);

  char* p = (char*)d_ws;
  auto alloc = [&](size_t bytes) {
    char* r = p;
    p += (bytes + 255) & ~(size_t)255;
    return r;
  };
  int* deg = (int*)alloc((size_t)N * 4);
  int* off = (int*)alloc((size_t)(N + 1) * 4);
  int* csr = (int*)alloc((size_t)ET * 4);
  int* bsum = (int*)alloc((size_t)SB * 4);
  int* bpre = (int*)alloc((size_t)(SB + 1) * 4);
  int* bcur = (int*)alloc((size_t)SB * 4);
  int2* pairs = (int2*)alloc((size_t)ET * 8);
  _Float16* w1hf = (_Float16*)alloc((size_t)32768 * 2);
  _Float16* w2f = (_Float16*)alloc((size_t)16384 * 2);
  float* wt1s = (float*)alloc((size_t)512 * 4);
  float* wt1d = (float*)alloc((size_t)512 * 4);
  float* b1p = (float*)alloc((size_t)256 * 4);
  _Float16* x16 = (_Float16*)alloc((size_t)N * 128 * 2);
  _Float16* xagg = (_Float16*)alloc((size_t)N * 512 * 2);
  _Float16* hout1p = (_Float16*)alloc((size_t)N * 256 * 2);
  float* as1 = (float*)alloc((size_t)N * 4 * 4);
  float* ad1 = (float*)alloc((size_t)N * 4 * 4);
  _Float16* alpha1 = (_Float16*)alloc((size_t)ET * 4 * 2);
  _Float16* h2p = x16;  // reuse: x16 dead after k_xagg
  float* as2 = (float*)alloc((size_t)N * 4);
  float* ad2 = (float*)alloc((size_t)N * 4);

  int n4 = ceil_div(N, 4);
  k_zero<<<ceil_div(n4, 256), 256, 0, stream>>>((int4*)deg, n4);
  k_count<<<ceil_div(ET, 256), 256, 0, stream>>>(ei, deg, NE, N);
  k_bsum<<<SB, 256, 0, stream>>>(deg, bsum, N);
  k_bscan<<<1, 256, 0, stream>>>(bsum, bpre, bcur, off, N);
  k_cscan<<<SB, 256, 0, stream>>>(deg, bpre, off, N);
  k_fillA<<<ceil_div(ET, FTILE), 256, 0, stream>>>(ei, bcur, pairs, NE, N, chunk);
  k_fillB<<<SB, 256, 0, stream>>>(pairs, bpre, off, csr, N, chunk);
  k_prep<<<198, 256, 0, stream>>>(W1, W2, a_src1, a_dst1, a_src2, a_dst2, b1,
                                  w1hf, w2f, wt1s, wt1d, b1p);

  k_logits1<<<ceil_div(N, 4), 256, 0, stream>>>(x, wt1s, wt1d, x16, as1, ad1, N);
  k_alpha1<<<ceil_div(N, 4), 256, 0, stream>>>(as1, ad1, off, csr, alpha1, N);
  k_xagg<<<ceil_div(N, 4), 256, 0, stream>>>(x16, alpha1, off, csr, xagg, N);
  k_gemm1f<<<ceil_div(N, 64), 256, 0, stream>>>(xagg, w1hf, b1p, hout1p, N);
  k_gemm2<<<ceil_div(N, 64), 256, 0, stream>>>(hout1p, w2f, a_src2, a_dst2, h2p,
                                               as2, ad2, N);
  k_agg2<<<ceil_div(N, 4), 256, 0, stream>>>(h2p, as2, ad2, b2, off, csr, out, N);
}

// Round 13
// 226.142 us; speedup vs baseline: 1.5009x; 1.0489x over previous
//
#include <hip/hip_runtime.h>
#include <math.h>

#define LEAKY 0.2f
#define SB 256
#define FTILE 4096

typedef _Float16 half2v __attribute__((ext_vector_type(2)));
typedef _Float16 half4 __attribute__((ext_vector_type(4)));
typedef _Float16 half8 __attribute__((ext_vector_type(8)));
typedef float f32x4 __attribute__((ext_vector_type(4)));

static inline int ceil_div(int a, int b) { return (a + b - 1) / b; }

// storage index p -> original column, for 64-col groups
__device__ __forceinline__ int PERM(int p) {
  int q = p & 63;
  return (p & ~63) | (((q & 3) << 4) | (q >> 2));
}

// ---------------- zero helper ----------------
__global__ __launch_bounds__(256) void k_zero(int4* __restrict__ buf, int n4) {
  int i = blockIdx.x * 256 + threadIdx.x;
  if (i < n4) buf[i] = make_int4(0, 0, 0, 0);
}

// ---------------- CSR build ----------------
__global__ __launch_bounds__(256) void k_count(const int* __restrict__ ei,
                                               int* __restrict__ deg, int NE, int N) {
  int e = blockIdx.x * 256 + threadIdx.x;
  int ET = NE + N;
  if (e >= ET) return;
  int d = (e < NE) ? ei[NE + e] : (e - NE);
  atomicAdd(&deg[d], 1);
}

__global__ __launch_bounds__(256) void k_bsum(const int* __restrict__ deg,
                                              int* __restrict__ bsum, int N) {
  int b = blockIdx.x;
  int chunk = (N + SB - 1) / SB;
  int s0 = b * chunk, s1 = min(s0 + chunk, N);
  int t = threadIdx.x;
  int sum = 0;
  for (int i = s0 + t; i < s1; i += 256) sum += deg[i];
#pragma unroll
  for (int o = 32; o; o >>= 1) sum += __shfl_xor(sum, o, 64);
  __shared__ int red[4];
  if ((t & 63) == 0) red[t >> 6] = sum;
  __syncthreads();
  if (t == 0) bsum[b] = red[0] + red[1] + red[2] + red[3];
}

__global__ __launch_bounds__(256) void k_bscan(const int* __restrict__ bsum,
                                               int* __restrict__ bpre,
                                               int* __restrict__ bcur,
                                               int* __restrict__ off, int N) {
  __shared__ int s[256];
  int t = threadIdx.x;
  int v = bsum[t];
  s[t] = v;
  __syncthreads();
  for (int o = 1; o < 256; o <<= 1) {
    int u = (t >= o) ? s[t - o] : 0;
    __syncthreads();
    s[t] += u;
    __syncthreads();
  }
  bpre[t] = s[t] - v;
  bcur[t] = s[t] - v;
  if (t == 255) {
    off[N] = s[255];
    bpre[256] = s[255];
  }
}

__global__ __launch_bounds__(256) void k_cscan(const int* __restrict__ deg,
                                               const int* __restrict__ bpre,
                                               int* __restrict__ off, int N) {
  int b = blockIdx.x;
  int chunk = (N + SB - 1) / SB;
  int i = b * chunk + threadIdx.x;
  int t = threadIdx.x;
  int valid = (t < chunk && i < N);
  int v = valid ? deg[i] : 0;
  __shared__ int s[256];
  s[t] = v;
  __syncthreads();
  for (int o = 1; o < 256; o <<= 1) {
    int u = (t >= o) ? s[t - o] : 0;
    __syncthreads();
    s[t] += u;
    __syncthreads();
  }
  if (valid) off[i] = s[t] - v + bpre[b];
}

// ---- fillA: radix-partition edges into bucket-contiguous (dst,src) pairs ----
__global__ __launch_bounds__(256) void k_fillA(const int* __restrict__ ei,
                                               int* __restrict__ bcur,
                                               int2* __restrict__ pairs,
                                               int NE, int N, int chunk) {
  __shared__ int hist[256], base[256], cnt2[256];
  int t = threadIdx.x;
  hist[t] = 0;
  cnt2[t] = 0;
  __syncthreads();
  int ET = NE + N;
  int e0 = blockIdx.x * FTILE;
  int sv[16], dv[16];
#pragma unroll
  for (int j = 0; j < 16; ++j) {
    int e = e0 + t + 256 * j;
    if (e < ET) {
      sv[j] = (e < NE) ? ei[e] : (e - NE);
      dv[j] = (e < NE) ? ei[NE + e] : (e - NE);
      atomicAdd(&hist[dv[j] / chunk], 1);
    } else {
      dv[j] = -1;
    }
  }
  __syncthreads();
  if (hist[t] > 0) base[t] = atomicAdd(&bcur[t], hist[t]);
  __syncthreads();
#pragma unroll
  for (int j = 0; j < 16; ++j) {
    if (dv[j] >= 0) {
      int b = dv[j] / chunk;
      int r = atomicAdd(&cnt2[b], 1);
      pairs[base[b] + r] = make_int2(dv[j], sv[j]);
    }
  }
}

// ---- fillB: one block per bucket; LDS per-dst cursors; local scatter --------
__global__ __launch_bounds__(256) void k_fillB(const int2* __restrict__ pairs,
                                               const int* __restrict__ bpre,
                                               const int* __restrict__ off,
                                               int* __restrict__ csr, int N, int chunk) {
  __shared__ int cur[256];
  int b = blockIdx.x, t = threadIdx.x;
  int node0 = b * chunk;
  for (int i = t; i < chunk; i += 256)
    if (node0 + i < N) cur[i] = off[node0 + i];
  __syncthreads();
  int i0 = bpre[b], i1 = bpre[b + 1];
  for (int i = i0 + t; i < i1; i += 256) {
    int2 pr = pairs[i];
    int pos = atomicAdd(&cur[pr.x - node0], 1);
    csr[pos] = pr.y;
  }
}

// ---------------- prep: weight fragments + folded attention vectors ---------
__global__ __launch_bounds__(256) void k_prep(const float* __restrict__ W1,
                                              const float* __restrict__ W2,
                                              const float* __restrict__ a_src1,
                                              const float* __restrict__ a_dst1,
                                              const float* __restrict__ a_src2,
                                              const float* __restrict__ a_dst2,
                                              const float* __restrict__ b1,
                                              _Float16* __restrict__ w1hf,
                                              _Float16* __restrict__ w2f,
                                              float* __restrict__ wt1s,
                                              float* __restrict__ wt1d,
                                              float* __restrict__ b1p) {
  int idx = blockIdx.x * 256 + threadIdx.x;
  if (idx < 32768) {  // w1hf[h][ks][ct][l][i]
    int i = idx & 7, l = (idx >> 3) & 63, ct = (idx >> 9) & 3, ks = (idx >> 11) & 3,
        h = idx >> 13;
    int k = 32 * ks + 8 * (l >> 4) + i;
    int col = h * 64 + 16 * ct + (l & 15);
    w1hf[idx] = (_Float16)W1[k * 256 + col];
    return;
  }
  int i2 = idx - 32768;
  if (i2 < 16384) {  // w2f[ks][ct][l][i], A-side k' is layer-1 permuted index
    int i = i2 & 7, l = (i2 >> 3) & 63, ct = (i2 >> 9) & 3, ks = i2 >> 11;
    int kp = 32 * ks + 8 * (l >> 4) + i;
    int col = 16 * ct + (l & 15);
    w2f[i2] = (_Float16)W2[PERM(kp) * 64 + col];
    return;
  }
  int i3 = i2 - 16384;
  if (i3 < 512) {  // wt1s/wt1d[k*4+h]
    int h = i3 & 3, k = i3 >> 2;
    float ss = 0.f, sd = 0.f;
    for (int d = 0; d < 64; ++d) {
      float wv = W1[k * 256 + h * 64 + d];
      ss = fmaf(wv, a_src1[h * 64 + d], ss);
      sd = fmaf(wv, a_dst1[h * 64 + d], sd);
    }
    wt1s[i3] = ss;
    wt1d[i3] = sd;
    return;
  }
  int i4 = i3 - 512;
  if (i4 < 256) b1p[i4] = b1[PERM(i4)];
}

// ---------------- logits1: as1/ad1 = x @ wt1, also emit x16 -----------------
__global__ __launch_bounds__(256) void k_logits1(const float* __restrict__ x,
                                                 const float* __restrict__ wt1s,
                                                 const float* __restrict__ wt1d,
                                                 _Float16* __restrict__ x16,
                                                 float* __restrict__ as1,
                                                 float* __restrict__ ad1, int N) {
  int w = threadIdx.x >> 6, l = threadIdx.x & 63;
  int n = blockIdx.x * 4 + w;
  if (n >= N) return;
  float2 xv = *reinterpret_cast<const float2*>(x + (size_t)n * 128 + 2 * l);
  half2v xh;
  xh[0] = (_Float16)xv.x;
  xh[1] = (_Float16)xv.y;
  *reinterpret_cast<half2v*>(x16 + (size_t)n * 128 + 2 * l) = xh;
  float4 w0s = reinterpret_cast<const float4*>(wt1s)[2 * l];
  float4 w1s = reinterpret_cast<const float4*>(wt1s)[2 * l + 1];
  float4 w0d = reinterpret_cast<const float4*>(wt1d)[2 * l];
  float4 w1d = reinterpret_cast<const float4*>(wt1d)[2 * l + 1];
  float sa[4], sd[4];
  sa[0] = xv.x * w0s.x + xv.y * w1s.x;
  sa[1] = xv.x * w0s.y + xv.y * w1s.y;
  sa[2] = xv.x * w0s.z + xv.y * w1s.z;
  sa[3] = xv.x * w0s.w + xv.y * w1s.w;
  sd[0] = xv.x * w0d.x + xv.y * w1d.x;
  sd[1] = xv.x * w0d.y + xv.y * w1d.y;
  sd[2] = xv.x * w0d.z + xv.y * w1d.z;
  sd[3] = xv.x * w0d.w + xv.y * w1d.w;
#pragma unroll
  for (int o = 1; o <= 32; o <<= 1) {
#pragma unroll
    for (int h = 0; h < 4; ++h) {
      sa[h] += __shfl_xor(sa[h], o, 64);
      sd[h] += __shfl_xor(sd[h], o, 64);
    }
  }
  if (l == 0) {
#pragma unroll
    for (int h = 0; h < 4; ++h) {
      as1[n * 4 + h] = sa[h];
      ad1[n * 4 + h] = sd[h];
    }
  }
}

// ------- fused layer-1 softmax + x-space aggregation (wave per node) --------
// pass1: per-head max, lane=(eidx,h). pass2: 32-edge chunks; phase A computes
// p=exp(t-m) once per (edge,head); phase B shfl-broadcasts (src,p0..p3) to
// gather lanes (slot,kq); packed-fp16 accumulate of UNNORMALIZED p*x;
// normalized by 1/lp at store.
__global__ __launch_bounds__(256) void k_xagg(const _Float16* __restrict__ x16,
                                              const float* __restrict__ as1,
                                              const float* __restrict__ ad1,
                                              const int* __restrict__ off,
                                              const int* __restrict__ csr,
                                              _Float16* __restrict__ xagg, int N) {
  int w = threadIdx.x >> 6, l = threadIdx.x & 63;
  int n = blockIdx.x * 4 + w;
  if (n >= N) return;
  int e0 = off[n], e1 = off[n + 1];
  int eidx = l >> 2, h4 = l & 3;
  float adv = ad1[n * 4 + h4];
  // pass 1: max over own head class
  float m = -INFINITY;
  for (int base = e0; base < e1; base += 16) {
    int idx = base + eidx;
    if (idx < e1) {
      int s = csr[idx];
      float t = as1[s * 4 + h4] + adv;
      t = t > 0.f ? t : LEAKY * t;
      m = fmaxf(m, t);
    }
  }
#pragma unroll
  for (int o = 4; o <= 32; o <<= 1) m = fmaxf(m, __shfl_xor(m, o, 64));
  // pass 2
  int slot = l >> 4, kq = l & 15;
  half2v acc[4][4];
#pragma unroll
  for (int h = 0; h < 4; ++h)
#pragma unroll
    for (int j = 0; j < 4; ++j) acc[h][j] = (half2v){(_Float16)0.f, (_Float16)0.f};
  float lp = 0.f;
  for (int base = e0; base < e1; base += 32) {
    int sa0, sa1;
    float pa0, pa1;
    {
      int idx = base + eidx;
      int ec = min(idx, e1 - 1);
      sa0 = csr[ec];
      float t = as1[sa0 * 4 + h4] + adv;
      t = t > 0.f ? t : LEAKY * t;
      pa0 = (idx < e1) ? __expf(t - m) : 0.f;
    }
    {
      int idx = base + 16 + eidx;
      int ec = min(idx, e1 - 1);
      sa1 = csr[ec];
      float t = as1[sa1 * 4 + h4] + adv;
      t = t > 0.f ? t : LEAKY * t;
      pa1 = (idx < e1) ? __expf(t - m) : 0.f;
    }
    lp += pa0 + pa1;
#pragma unroll
    for (int u = 0; u < 8; ++u) {
      int er = 4 * u + slot;        // 0..31
      int sl = (er & 15) << 2;      // phase-A source lane base
      int sj;
      float p0, p1, p2, p3;
      if (u < 4) {
        sj = __shfl(sa0, sl, 64);
        p0 = __shfl(pa0, sl, 64);
        p1 = __shfl(pa0, sl + 1, 64);
        p2 = __shfl(pa0, sl + 2, 64);
        p3 = __shfl(pa0, sl + 3, 64);
      } else {
        sj = __shfl(sa1, sl, 64);
        p0 = __shfl(pa1, sl, 64);
        p1 = __shfl(pa1, sl + 1, 64);
        p2 = __shfl(pa1, sl + 2, 64);
        p3 = __shfl(pa1, sl + 3, 64);
      }
      half8 hv = *reinterpret_cast<const half8*>(x16 + (size_t)sj * 128 + 8 * kq);
      half2v xp[4];
      xp[0] = (half2v){hv[0], hv[1]};
      xp[1] = (half2v){hv[2], hv[3]};
      xp[2] = (half2v){hv[4], hv[5]};
      xp[3] = (half2v){hv[6], hv[7]};
      _Float16 q0 = (_Float16)p0, q1 = (_Float16)p1, q2 = (_Float16)p2,
               q3 = (_Float16)p3;
      half2v a0 = (half2v){q0, q0}, a1 = (half2v){q1, q1};
      half2v a2 = (half2v){q2, q2}, a3 = (half2v){q3, q3};
#pragma unroll
      for (int j = 0; j < 4; ++j) {
        acc[0][j] = a0 * xp[j] + acc[0][j];
        acc[1][j] = a1 * xp[j] + acc[1][j];
        acc[2][j] = a2 * xp[j] + acc[2][j];
        acc[3][j] = a3 * xp[j] + acc[3][j];
      }
    }
  }
#pragma unroll
  for (int o = 4; o <= 32; o <<= 1) lp += __shfl_xor(lp, o, 64);
  float rin[4];
#pragma unroll
  for (int h = 0; h < 4; ++h) rin[h] = 1.f / __shfl(lp, h, 64);
  // cross-slot reduce (xor 16, 32) packed
#pragma unroll
  for (int h = 0; h < 4; ++h)
#pragma unroll
    for (int j = 0; j < 4; ++j) {
      int v0 = __shfl_xor(__builtin_bit_cast(int, acc[h][j]), 16, 64);
      acc[h][j] = acc[h][j] + __builtin_bit_cast(half2v, v0);
      int v1 = __shfl_xor(__builtin_bit_cast(int, acc[h][j]), 32, 64);
      acc[h][j] = acc[h][j] + __builtin_bit_cast(half2v, v1);
    }
  if (slot == 0) {
#pragma unroll
    for (int h = 0; h < 4; ++h) {
      half8 o;
#pragma unroll
      for (int j = 0; j < 4; ++j) {
        o[2 * j] = (_Float16)((float)acc[h][j][0] * rin[h]);
        o[2 * j + 1] = (_Float16)((float)acc[h][j][1] * rin[h]);
      }
      *reinterpret_cast<half8*>(xagg + (size_t)n * 512 + h * 128 + 8 * kq) = o;
    }
  }
}

// -------- fused layer-1 + layer-2 GEMM: xagg -> (LDS) -> h2p, as2/ad2 --------
// 64 nodes/block, 4 waves. Phase 1: per-wave 16 rows, 4 heads x 4 ct MFMA,
// ReLU+bias -> 32KB XOR-swizzled LDS (permuted storage layout). Phase 2:
// 64-col GEMM over K=256 from LDS, fused as2/ad2 epilogue.
__global__ __launch_bounds__(256) void k_gemm12(const _Float16* __restrict__ xagg,
                                                const _Float16* __restrict__ w1hf,
                                                const _Float16* __restrict__ w2f,
                                                const float* __restrict__ b1p,
                                                const float* __restrict__ a_src2,
                                                const float* __restrict__ a_dst2,
                                                _Float16* __restrict__ h2p,
                                                float* __restrict__ as2,
                                                float* __restrict__ ad2, int N) {
  __shared__ _Float16 hs[64 * 256];  // 32 KiB
  int w = threadIdx.x >> 6, l = threadIdx.x & 63;
  int n0 = blockIdx.x * 64 + 16 * w;
  int lrow = l & 15, lgrp = l >> 4;
  int arow = min(n0 + lrow, N - 1);
  // ---- phase 1: gemm1 ----
  f32x4 acc1[4][4];
#pragma unroll
  for (int h = 0; h < 4; ++h)
#pragma unroll
    for (int ct = 0; ct < 4; ++ct) acc1[h][ct] = (f32x4){0.f, 0.f, 0.f, 0.f};
#pragma unroll
  for (int h = 0; h < 4; ++h) {
#pragma unroll
    for (int ks = 0; ks < 4; ++ks) {
      half8 af = *reinterpret_cast<const half8*>(xagg + (size_t)arow * 512 + h * 128 +
                                                 32 * ks + 8 * lgrp);
      const half8* bp =
          reinterpret_cast<const half8*>(w1hf) + (size_t)((h * 4 + ks) * 4) * 64 + l;
#pragma unroll
      for (int ct = 0; ct < 4; ++ct) {
        half8 bf = bp[ct * 64];
        acc1[h][ct] = __builtin_amdgcn_mfma_f32_16x16x32_f16(af, bf, acc1[h][ct], 0, 0, 0);
      }
    }
  }
  int lr0 = 16 * w + 4 * lgrp;  // local row base
#pragma unroll
  for (int h = 0; h < 4; ++h) {
    float4 bv = *reinterpret_cast<const float4*>(b1p + h * 64 + lrow * 4);
#pragma unroll
    for (int r = 0; r < 4; ++r) {
      int row = lr0 + r;
      half4 o;
      o[0] = (_Float16)fmaxf(acc1[h][0][r] + bv.x, 0.f);
      o[1] = (_Float16)fmaxf(acc1[h][1][r] + bv.y, 0.f);
      o[2] = (_Float16)fmaxf(acc1[h][2][r] + bv.z, 0.f);
      o[3] = (_Float16)fmaxf(acc1[h][3][r] + bv.w, 0.f);
      int ba = row * 512 + ((h * 128 + lrow * 8) ^ ((row & 7) << 4));
      *reinterpret_cast<half4*>(reinterpret_cast<char*>(hs) + ba) = o;
    }
  }
  __syncthreads();
  // ---- phase 2: gemm2 over K=256 from LDS ----
  int arow2 = 16 * w + lrow;  // local A row
  f32x4 acc2[4];
#pragma unroll
  for (int ct = 0; ct < 4; ++ct) acc2[ct] = (f32x4){0.f, 0.f, 0.f, 0.f};
#pragma unroll
  for (int ks = 0; ks < 8; ++ks) {
    int ba = arow2 * 512 + ((64 * ks + 16 * lgrp) ^ ((arow2 & 7) << 4));
    half8 af = *reinterpret_cast<const half8*>(reinterpret_cast<const char*>(hs) + ba);
    const half8* bp = reinterpret_cast<const half8*>(w2f) + (size_t)(ks * 4) * 64 + l;
#pragma unroll
    for (int ct = 0; ct < 4; ++ct) {
      half8 bf = bp[ct * 64];
      acc2[ct] = __builtin_amdgcn_mfma_f32_16x16x32_f16(af, bf, acc2[ct], 0, 0, 0);
    }
  }
  float ascol[4], adcol[4];
#pragma unroll
  for (int ct = 0; ct < 4; ++ct) {
    ascol[ct] = a_src2[16 * ct + lrow];
    adcol[ct] = a_dst2[16 * ct + lrow];
  }
  int rbase = n0 + 4 * lgrp;
#pragma unroll
  for (int r = 0; r < 4; ++r) {
    int row = rbase + r;
    bool ok = row < N;
    float sa = 0.f, sd = 0.f;
    half4 o;
#pragma unroll
    for (int ct = 0; ct < 4; ++ct) {
      float v = acc2[ct][r];
      o[ct] = (_Float16)v;
      sa = fmaf(v, ascol[ct], sa);
      sd = fmaf(v, adcol[ct], sd);
    }
    if (ok) *reinterpret_cast<half4*>(h2p + (size_t)row * 64 + lrow * 4) = o;
#pragma unroll
    for (int oo = 1; oo <= 8; oo <<= 1) {
      sa += __shfl_xor(sa, oo, 64);
      sd += __shfl_xor(sd, oo, 64);
    }
    if (ok && lrow == 0) {
      as2[row] = sa;
      ad2[row] = sd;
    }
  }
}

// ---------------- Layer 2: fused softmax + aggregation, 2-pass ---------------
__global__ __launch_bounds__(256) void k_agg2(const _Float16* __restrict__ h2p,
                                              const float* __restrict__ as2,
                                              const float* __restrict__ ad2,
                                              const float* __restrict__ b2,
                                              const int* __restrict__ off,
                                              const int* __restrict__ csr,
                                              float* __restrict__ out, int N) {
  int w = threadIdx.x >> 6, lane = threadIdx.x & 63;
  int n = blockIdx.x * 4 + w;
  if (n >= N) return;
  float adv = ad2[n];
  int e0 = off[n], e1 = off[n + 1];
  float m = -INFINITY;
  for (int idx = e0 + lane; idx < e1; idx += 64) {
    float t = as2[csr[idx]] + adv;
    t = t > 0.f ? t : LEAKY * t;
    m = fmaxf(m, t);
  }
#pragma unroll
  for (int o = 1; o <= 32; o <<= 1) m = fmaxf(m, __shfl_xor(m, o, 64));
  int slot = lane >> 3, q = lane & 7;
  float acc[8];
  float lp = 0.f;
#pragma unroll
  for (int k = 0; k < 8; ++k) acc[k] = 0.f;
  for (int base = e0; base < e1; base += 16) {
#pragma unroll
    for (int u = 0; u < 2; ++u) {
      int e = base + 8 * u + slot;
      int ec = min(e, e1 - 1);
      int s = csr[ec];
      float t = as2[s] + adv;
      t = t > 0.f ? t : LEAKY * t;
      float p = (e < e1) ? __expf(t - m) : 0.f;
      lp += p;
      half8 hv = *reinterpret_cast<const half8*>(h2p + (size_t)s * 64 + 8 * q);
#pragma unroll
      for (int k = 0; k < 8; ++k) acc[k] = fmaf(p, (float)hv[k], acc[k]);
    }
  }
#pragma unroll
  for (int o = 8; o <= 32; o <<= 1) {
    lp += __shfl_xor(lp, o, 64);
#pragma unroll
    for (int k = 0; k < 8; ++k) acc[k] += __shfl_xor(acc[k], o, 64);
  }
  if (slot == 0) {
    float rinv = 1.f / lp;
    // storage p = 8q + k  ->  orig col = ((k&3)<<4) | (2q + (k>>2))
#pragma unroll
    for (int k = 0; k < 8; ++k) {
      int col = ((k & 3) << 4) + 2 * q + (k >> 2);
      out[(size_t)n * 64 + col] = acc[k] * rinv + b2[col];
    }
  }
}

extern "C" void kernel_launch(void* const* d_in, const int* in_sizes, int n_in,
                              void* d_out, int out_size, void* d_ws, size_t ws_size,
                              hipStream_t stream) {
  const float* x = (const float*)d_in[0];
  const int* ei = (const int*)d_in[1];
  const float* W1 = (const float*)d_in[2];
  const float* a_src1 = (const float*)d_in[3];
  const float* a_dst1 = (const float*)d_in[4];
  const float* b1 = (const float*)d_in[5];
  const float* W2 = (const float*)d_in[6];
  const float* a_src2 = (const float*)d_in[7];
  const float* a_dst2 = (const float*)d_in[8];
  const float* b2 = (const float*)d_in[9];
  float* out = (float*)d_out;

  const int N = in_sizes[0] / 128;
  const int NE = in_sizes[1] / 2;
  const int ET = NE + N;
  const int chunk = ceil_div(N, SB);

  char* p = (char*)d_ws;
  auto alloc = [&](size_t bytes) {
    char* r = p;
    p += (bytes + 255) & ~(size_t)255;
    return r;
  };
  int* deg = (int*)alloc((size_t)N * 4);
  int* off = (int*)alloc((size_t)(N + 1) * 4);
  int* csr = (int*)alloc((size_t)ET * 4);
  int* bsum = (int*)alloc((size_t)SB * 4);
  int* bpre = (int*)alloc((size_t)(SB + 1) * 4);
  int* bcur = (int*)alloc((size_t)SB * 4);
  int2* pairs = (int2*)alloc((size_t)ET * 8);
  _Float16* w1hf = (_Float16*)alloc((size_t)32768 * 2);
  _Float16* w2f = (_Float16*)alloc((size_t)16384 * 2);
  float* wt1s = (float*)alloc((size_t)512 * 4);
  float* wt1d = (float*)alloc((size_t)512 * 4);
  float* b1p = (float*)alloc((size_t)256 * 4);
  _Float16* x16 = (_Float16*)alloc((size_t)N * 128 * 2);
  _Float16* xagg = (_Float16*)alloc((size_t)N * 512 * 2);
  float* as1 = (float*)alloc((size_t)N * 4 * 4);
  float* ad1 = (float*)alloc((size_t)N * 4 * 4);
  _Float16* h2p = x16;  // reuse: x16 dead after k_xagg
  float* as2 = (float*)alloc((size_t)N * 4);
  float* ad2 = (float*)alloc((size_t)N * 4);

  int n4 = ceil_div(N, 4);
  k_zero<<<ceil_div(n4, 256), 256, 0, stream>>>((int4*)deg, n4);
  k_count<<<ceil_div(ET, 256), 256, 0, stream>>>(ei, deg, NE, N);
  k_bsum<<<SB, 256, 0, stream>>>(deg, bsum, N);
  k_bscan<<<1, 256, 0, stream>>>(bsum, bpre, bcur, off, N);
  k_cscan<<<SB, 256, 0, stream>>>(deg, bpre, off, N);
  k_fillA<<<ceil_div(ET, FTILE), 256, 0, stream>>>(ei, bcur, pairs, NE, N, chunk);
  k_fillB<<<SB, 256, 0, stream>>>(pairs, bpre, off, csr, N, chunk);
  k_prep<<<198, 256, 0, stream>>>(W1, W2, a_src1, a_dst1, a_src2, a_dst2, b1,
                                  w1hf, w2f, wt1s, wt1d, b1p);

  k_logits1<<<ceil_div(N, 4), 256, 0, stream>>>(x, wt1s, wt1d, x16, as1, ad1, N);
  k_xagg<<<ceil_div(N, 4), 256, 0, stream>>>(x16, as1, ad1, off, csr, xagg, N);
  k_gemm12<<<ceil_div(N, 64), 256, 0, stream>>>(xagg, w1hf, w2f, b1p, a_src2,
                                                a_dst2, h2p, as2, ad2, N);
  k_agg2<<<ceil_div(N, 4), 256, 0, stream>>>(h2p, as2, ad2, b2, off, csr, out, N);
}

// Round 14
// 213.490 us; speedup vs baseline: 1.5898x; 1.0593x over previous
//
#include <hip/hip_runtime.h>
#include <math.h>

#define LEAKY 0.2f
#define SB 256
#define FTILE 4096

typedef _Float16 half2v __attribute__((ext_vector_type(2)));
typedef _Float16 half4 __attribute__((ext_vector_type(4)));
typedef _Float16 half8 __attribute__((ext_vector_type(8)));
typedef float f32x4 __attribute__((ext_vector_type(4)));

static inline int ceil_div(int a, int b) { return (a + b - 1) / b; }

// storage index p -> original column, for 64-col groups
__device__ __forceinline__ int PERM(int p) {
  int q = p & 63;
  return (p & ~63) | (((q & 3) << 4) | (q >> 2));
}

// ---------------- zero helper ----------------
__global__ __launch_bounds__(256) void k_zero(int4* __restrict__ buf, int n4) {
  int i = blockIdx.x * 256 + threadIdx.x;
  if (i < n4) buf[i] = make_int4(0, 0, 0, 0);
}

// ---- fillAC: per-node degree count + radix-partition into bucket regions ----
// bucket b owns pairs[b*cap .. b*cap+bcnt[b]); no prefix scan needed for pairs.
__global__ __launch_bounds__(256) void k_fillAC(const int* __restrict__ ei,
                                                int* __restrict__ deg,
                                                int* __restrict__ bcnt,
                                                int2* __restrict__ pairs,
                                                int NE, int N, int chunk, int cap) {
  __shared__ int hist[256], base[256], cnt2[256];
  int t = threadIdx.x;
  hist[t] = 0;
  cnt2[t] = 0;
  __syncthreads();
  int ET = NE + N;
  int e0 = blockIdx.x * FTILE;
  int sv[16], dv[16];
#pragma unroll
  for (int j = 0; j < 16; ++j) {
    int e = e0 + t + 256 * j;
    if (e < ET) {
      sv[j] = (e < NE) ? ei[e] : (e - NE);
      dv[j] = (e < NE) ? ei[NE + e] : (e - NE);
      atomicAdd(&hist[dv[j] / chunk], 1);
      atomicAdd(&deg[dv[j]], 1);
    } else {
      dv[j] = -1;
    }
  }
  __syncthreads();
  if (hist[t] > 0) base[t] = t * cap + atomicAdd(&bcnt[t], hist[t]);
  __syncthreads();
#pragma unroll
  for (int j = 0; j < 16; ++j) {
    if (dv[j] >= 0) {
      int b = dv[j] / chunk;
      int r = atomicAdd(&cnt2[b], 1);
      pairs[base[b] + r] = make_int2(dv[j], sv[j]);
    }
  }
}

__global__ __launch_bounds__(256) void k_bsum(const int* __restrict__ deg,
                                              int* __restrict__ bsum, int N) {
  int b = blockIdx.x;
  int chunk = (N + SB - 1) / SB;
  int s0 = b * chunk, s1 = min(s0 + chunk, N);
  int t = threadIdx.x;
  int sum = 0;
  for (int i = s0 + t; i < s1; i += 256) sum += deg[i];
#pragma unroll
  for (int o = 32; o; o >>= 1) sum += __shfl_xor(sum, o, 64);
  __shared__ int red[4];
  if ((t & 63) == 0) red[t >> 6] = sum;
  __syncthreads();
  if (t == 0) bsum[b] = red[0] + red[1] + red[2] + red[3];
}

__global__ __launch_bounds__(256) void k_bscan(const int* __restrict__ bsum,
                                               int* __restrict__ bpre,
                                               int* __restrict__ off, int N) {
  __shared__ int s[256];
  int t = threadIdx.x;
  int v = bsum[t];
  s[t] = v;
  __syncthreads();
  for (int o = 1; o < 256; o <<= 1) {
    int u = (t >= o) ? s[t - o] : 0;
    __syncthreads();
    s[t] += u;
    __syncthreads();
  }
  bpre[t] = s[t] - v;
  if (t == 255) off[N] = s[255];
}

__global__ __launch_bounds__(256) void k_cscan(const int* __restrict__ deg,
                                               const int* __restrict__ bpre,
                                               int* __restrict__ off, int N) {
  int b = blockIdx.x;
  int chunk = (N + SB - 1) / SB;
  int i = b * chunk + threadIdx.x;
  int t = threadIdx.x;
  int valid = (t < chunk && i < N);
  int v = valid ? deg[i] : 0;
  __shared__ int s[256];
  s[t] = v;
  __syncthreads();
  for (int o = 1; o < 256; o <<= 1) {
    int u = (t >= o) ? s[t - o] : 0;
    __syncthreads();
    s[t] += u;
    __syncthreads();
  }
  if (valid) off[i] = s[t] - v + bpre[b];
}

// ---- fillB: one block per bucket; LDS per-dst cursors; local scatter --------
__global__ __launch_bounds__(256) void k_fillB(const int2* __restrict__ pairs,
                                               const int* __restrict__ bcnt,
                                               const int* __restrict__ off,
                                               int* __restrict__ csr, int N,
                                               int chunk, int cap) {
  __shared__ int cur[256];
  int b = blockIdx.x, t = threadIdx.x;
  int node0 = b * chunk;
  for (int i = t; i < chunk; i += 256)
    if (node0 + i < N) cur[i] = off[node0 + i];
  __syncthreads();
  int i0 = b * cap, i1 = i0 + bcnt[b];
  for (int i = i0 + t; i < i1; i += 256) {
    int2 pr = pairs[i];
    int pos = atomicAdd(&cur[pr.x - node0], 1);
    csr[pos] = pr.y;
  }
}

// ---------------- prep: weight fragments + folded attention vectors ---------
__global__ __launch_bounds__(256) void k_prep(const float* __restrict__ W1,
                                              const float* __restrict__ W2,
                                              const float* __restrict__ a_src1,
                                              const float* __restrict__ a_dst1,
                                              const float* __restrict__ a_src2,
                                              const float* __restrict__ a_dst2,
                                              const float* __restrict__ b1,
                                              _Float16* __restrict__ w1hf,
                                              _Float16* __restrict__ w2f,
                                              float* __restrict__ wt1s,
                                              float* __restrict__ wt1d,
                                              float* __restrict__ b1p) {
  int idx = blockIdx.x * 256 + threadIdx.x;
  if (idx < 32768) {  // w1hf[h][ks][ct][l][i]
    int i = idx & 7, l = (idx >> 3) & 63, ct = (idx >> 9) & 3, ks = (idx >> 11) & 3,
        h = idx >> 13;
    int k = 32 * ks + 8 * (l >> 4) + i;
    int col = h * 64 + 16 * ct + (l & 15);
    w1hf[idx] = (_Float16)W1[k * 256 + col];
    return;
  }
  int i2 = idx - 32768;
  if (i2 < 16384) {  // w2f[ks][ct][l][i], A-side k' is layer-1 permuted index
    int i = i2 & 7, l = (i2 >> 3) & 63, ct = (i2 >> 9) & 3, ks = i2 >> 11;
    int kp = 32 * ks + 8 * (l >> 4) + i;
    int col = 16 * ct + (l & 15);
    w2f[i2] = (_Float16)W2[PERM(kp) * 64 + col];
    return;
  }
  int i3 = i2 - 16384;
  if (i3 < 512) {  // wt1s/wt1d[k*4+h]
    int h = i3 & 3, k = i3 >> 2;
    float ss = 0.f, sd = 0.f;
    for (int d = 0; d < 64; ++d) {
      float wv = W1[k * 256 + h * 64 + d];
      ss = fmaf(wv, a_src1[h * 64 + d], ss);
      sd = fmaf(wv, a_dst1[h * 64 + d], sd);
    }
    wt1s[i3] = ss;
    wt1d[i3] = sd;
    return;
  }
  int i4 = i3 - 512;
  if (i4 < 256) b1p[i4] = b1[PERM(i4)];
}

// ---------------- logits1: as1/ad1 = x @ wt1, also emit x16 -----------------
__global__ __launch_bounds__(256) void k_logits1(const float* __restrict__ x,
                                                 const float* __restrict__ wt1s,
                                                 const float* __restrict__ wt1d,
                                                 _Float16* __restrict__ x16,
                                                 float* __restrict__ as1,
                                                 float* __restrict__ ad1, int N) {
  int w = threadIdx.x >> 6, l = threadIdx.x & 63;
  int n = blockIdx.x * 4 + w;
  if (n >= N) return;
  float2 xv = *reinterpret_cast<const float2*>(x + (size_t)n * 128 + 2 * l);
  half2v xh;
  xh[0] = (_Float16)xv.x;
  xh[1] = (_Float16)xv.y;
  *reinterpret_cast<half2v*>(x16 + (size_t)n * 128 + 2 * l) = xh;
  float4 w0s = reinterpret_cast<const float4*>(wt1s)[2 * l];
  float4 w1s = reinterpret_cast<const float4*>(wt1s)[2 * l + 1];
  float4 w0d = reinterpret_cast<const float4*>(wt1d)[2 * l];
  float4 w1d = reinterpret_cast<const float4*>(wt1d)[2 * l + 1];
  float sa[4], sd[4];
  sa[0] = xv.x * w0s.x + xv.y * w1s.x;
  sa[1] = xv.x * w0s.y + xv.y * w1s.y;
  sa[2] = xv.x * w0s.z + xv.y * w1s.z;
  sa[3] = xv.x * w0s.w + xv.y * w1s.w;
  sd[0] = xv.x * w0d.x + xv.y * w1d.x;
  sd[1] = xv.x * w0d.y + xv.y * w1d.y;
  sd[2] = xv.x * w0d.z + xv.y * w1d.z;
  sd[3] = xv.x * w0d.w + xv.y * w1d.w;
#pragma unroll
  for (int o = 1; o <= 32; o <<= 1) {
#pragma unroll
    for (int h = 0; h < 4; ++h) {
      sa[h] += __shfl_xor(sa[h], o, 64);
      sd[h] += __shfl_xor(sd[h], o, 64);
    }
  }
  if (l == 0) {
#pragma unroll
    for (int h = 0; h < 4; ++h) {
      as1[n * 4 + h] = sa[h];
      ad1[n * 4 + h] = sd[h];
    }
  }
}

// ------- alpha1, 2-pass: UNNORMALIZED fp16 p + linv1 = 1/sum ---------------
__global__ __launch_bounds__(256) void k_alpha1(const float* __restrict__ as1,
                                                const float* __restrict__ ad1,
                                                const int* __restrict__ off,
                                                const int* __restrict__ csr,
                                                _Float16* __restrict__ alpha,
                                                float* __restrict__ linv1, int N) {
  int w = threadIdx.x >> 6, lane = threadIdx.x & 63;
  int n = blockIdx.x * 4 + w;
  if (n >= N) return;
  int eidx = lane >> 2, h = lane & 3;
  float adv = ad1[n * 4 + h];
  int e0 = off[n], e1 = off[n + 1];
  float m = -INFINITY;
  for (int base = e0; base < e1; base += 16) {
    int idx = base + eidx;
    if (idx < e1) {
      int s = csr[idx];
      float t = as1[s * 4 + h] + adv;
      t = t > 0.f ? t : LEAKY * t;
      m = fmaxf(m, t);
    }
  }
#pragma unroll
  for (int o = 4; o <= 32; o <<= 1) m = fmaxf(m, __shfl_xor(m, o, 64));
  float lp = 0.f;
  for (int base = e0; base < e1; base += 16) {
    int idx = base + eidx;
    if (idx < e1) {
      int s = csr[idx];
      float t = as1[s * 4 + h] + adv;
      t = t > 0.f ? t : LEAKY * t;
      float p = __expf(t - m);
      alpha[(size_t)idx * 4 + h] = (_Float16)p;
      lp += p;
    }
  }
#pragma unroll
  for (int o = 4; o <= 32; o <<= 1) lp += __shfl_xor(lp, o, 64);
  if (lane < 4) linv1[n * 4 + h] = 1.f / lp;
}

// ---------------- x-space aggregation: packed-fp16 accumulate, 16 edges deep -
// lane = slot*16 + kq; slot covers edge base+4u+slot, kq covers k = 8kq..8kq+7
// accumulates UNNORMALIZED p*x; scales by linv1 at store.
__global__ __launch_bounds__(256) void k_xagg(const _Float16* __restrict__ x16,
                                              const _Float16* __restrict__ alpha,
                                              const float* __restrict__ linv1,
                                              const int* __restrict__ off,
                                              const int* __restrict__ csr,
                                              _Float16* __restrict__ xagg, int N) {
  int w = threadIdx.x >> 6, l = threadIdx.x & 63;
  int n = blockIdx.x * 4 + w;
  if (n >= N) return;
  int slot = l >> 4, kq = l & 15;
  int e0 = off[n], e1 = off[n + 1];
  half2v acc[4][4];
#pragma unroll
  for (int h = 0; h < 4; ++h)
#pragma unroll
    for (int j = 0; j < 4; ++j) acc[h][j] = (half2v){(_Float16)0.f, (_Float16)0.f};
  const _Float16 zero16 = (_Float16)0.f;
  for (int base = e0; base < e1; base += 16) {
#pragma unroll
    for (int u = 0; u < 4; ++u) {
      int e = base + 4 * u + slot;
      int ec = min(e, e1 - 1);
      int src = csr[ec];
      half4 al = *reinterpret_cast<const half4*>(alpha + (size_t)ec * 4);
      if (e >= e1) al = (half4){zero16, zero16, zero16, zero16};
      half8 hv = *reinterpret_cast<const half8*>(x16 + (size_t)src * 128 + 8 * kq);
      half2v xp[4];
      xp[0] = (half2v){hv[0], hv[1]};
      xp[1] = (half2v){hv[2], hv[3]};
      xp[2] = (half2v){hv[4], hv[5]};
      xp[3] = (half2v){hv[6], hv[7]};
#pragma unroll
      for (int h = 0; h < 4; ++h) {
        half2v ah = (half2v){al[h], al[h]};
#pragma unroll
        for (int j = 0; j < 4; ++j) acc[h][j] = ah * xp[j] + acc[h][j];
      }
    }
  }
  // cross-slot reduce (xor 16, 32) in packed fp16
#pragma unroll
  for (int h = 0; h < 4; ++h)
#pragma unroll
    for (int j = 0; j < 4; ++j) {
      int v0 = __shfl_xor(__builtin_bit_cast(int, acc[h][j]), 16, 64);
      acc[h][j] = acc[h][j] + __builtin_bit_cast(half2v, v0);
      int v1 = __shfl_xor(__builtin_bit_cast(int, acc[h][j]), 32, 64);
      acc[h][j] = acc[h][j] + __builtin_bit_cast(half2v, v1);
    }
  if (slot == 0) {
    float4 linv = *reinterpret_cast<const float4*>(linv1 + n * 4);
    float rin[4] = {linv.x, linv.y, linv.z, linv.w};
#pragma unroll
    for (int h = 0; h < 4; ++h) {
      half8 o;
#pragma unroll
      for (int j = 0; j < 4; ++j) {
        o[2 * j] = (_Float16)((float)acc[h][j][0] * rin[h]);
        o[2 * j + 1] = (_Float16)((float)acc[h][j][1] * rin[h]);
      }
      *reinterpret_cast<half8*>(xagg + (size_t)n * 512 + h * 128 + 8 * kq) = o;
    }
  }
}

// -------- fused layer-1 + layer-2 GEMM: xagg -> (LDS) -> h2p, as2/ad2 --------
__global__ __launch_bounds__(256) void k_gemm12(const _Float16* __restrict__ xagg,
                                                const _Float16* __restrict__ w1hf,
                                                const _Float16* __restrict__ w2f,
                                                const float* __restrict__ b1p,
                                                const float* __restrict__ a_src2,
                                                const float* __restrict__ a_dst2,
                                                _Float16* __restrict__ h2p,
                                                float* __restrict__ as2,
                                                float* __restrict__ ad2, int N) {
  __shared__ _Float16 hs[64 * 256];  // 32 KiB
  int w = threadIdx.x >> 6, l = threadIdx.x & 63;
  int n0 = blockIdx.x * 64 + 16 * w;
  int lrow = l & 15, lgrp = l >> 4;
  int arow = min(n0 + lrow, N - 1);
  // ---- phase 1: gemm1 ----
  f32x4 acc1[4][4];
#pragma unroll
  for (int h = 0; h < 4; ++h)
#pragma unroll
    for (int ct = 0; ct < 4; ++ct) acc1[h][ct] = (f32x4){0.f, 0.f, 0.f, 0.f};
#pragma unroll
  for (int h = 0; h < 4; ++h) {
#pragma unroll
    for (int ks = 0; ks < 4; ++ks) {
      half8 af = *reinterpret_cast<const half8*>(xagg + (size_t)arow * 512 + h * 128 +
                                                 32 * ks + 8 * lgrp);
      const half8* bp =
          reinterpret_cast<const half8*>(w1hf) + (size_t)((h * 4 + ks) * 4) * 64 + l;
#pragma unroll
      for (int ct = 0; ct < 4; ++ct) {
        half8 bf = bp[ct * 64];
        acc1[h][ct] = __builtin_amdgcn_mfma_f32_16x16x32_f16(af, bf, acc1[h][ct], 0, 0, 0);
      }
    }
  }
  int lr0 = 16 * w + 4 * lgrp;
#pragma unroll
  for (int h = 0; h < 4; ++h) {
    float4 bv = *reinterpret_cast<const float4*>(b1p + h * 64 + lrow * 4);
#pragma unroll
    for (int r = 0; r < 4; ++r) {
      int row = lr0 + r;
      half4 o;
      o[0] = (_Float16)fmaxf(acc1[h][0][r] + bv.x, 0.f);
      o[1] = (_Float16)fmaxf(acc1[h][1][r] + bv.y, 0.f);
      o[2] = (_Float16)fmaxf(acc1[h][2][r] + bv.z, 0.f);
      o[3] = (_Float16)fmaxf(acc1[h][3][r] + bv.w, 0.f);
      int ba = row * 512 + ((h * 128 + lrow * 8) ^ ((row & 7) << 4));
      *reinterpret_cast<half4*>(reinterpret_cast<char*>(hs) + ba) = o;
    }
  }
  __syncthreads();
  // ---- phase 2: gemm2 over K=256 from LDS ----
  int arow2 = 16 * w + lrow;
  f32x4 acc2[4];
#pragma unroll
  for (int ct = 0; ct < 4; ++ct) acc2[ct] = (f32x4){0.f, 0.f, 0.f, 0.f};
#pragma unroll
  for (int ks = 0; ks < 8; ++ks) {
    int ba = arow2 * 512 + ((64 * ks + 16 * lgrp) ^ ((arow2 & 7) << 4));
    half8 af = *reinterpret_cast<const half8*>(reinterpret_cast<const char*>(hs) + ba);
    const half8* bp = reinterpret_cast<const half8*>(w2f) + (size_t)(ks * 4) * 64 + l;
#pragma unroll
    for (int ct = 0; ct < 4; ++ct) {
      half8 bf = bp[ct * 64];
      acc2[ct] = __builtin_amdgcn_mfma_f32_16x16x32_f16(af, bf, acc2[ct], 0, 0, 0);
    }
  }
  float ascol[4], adcol[4];
#pragma unroll
  for (int ct = 0; ct < 4; ++ct) {
    ascol[ct] = a_src2[16 * ct + lrow];
    adcol[ct] = a_dst2[16 * ct + lrow];
  }
  int rbase = n0 + 4 * lgrp;
#pragma unroll
  for (int r = 0; r < 4; ++r) {
    int row = rbase + r;
    bool ok = row < N;
    float sa = 0.f, sd = 0.f;
    half4 o;
#pragma unroll
    for (int ct = 0; ct < 4; ++ct) {
      float v = acc2[ct][r];
      o[ct] = (_Float16)v;
      sa = fmaf(v, ascol[ct], sa);
      sd = fmaf(v, adcol[ct], sd);
    }
    if (ok) *reinterpret_cast<half4*>(h2p + (size_t)row * 64 + lrow * 4) = o;
#pragma unroll
    for (int oo = 1; oo <= 8; oo <<= 1) {
      sa += __shfl_xor(sa, oo, 64);
      sd += __shfl_xor(sd, oo, 64);
    }
    if (ok && lrow == 0) {
      as2[row] = sa;
      ad2[row] = sd;
    }
  }
}

// ---------------- Layer 2: fused softmax + aggregation, 2-pass ---------------
__global__ __launch_bounds__(256) void k_agg2(const _Float16* __restrict__ h2p,
                                              const float* __restrict__ as2,
                                              const float* __restrict__ ad2,
                                              const float* __restrict__ b2,
                                              const int* __restrict__ off,
                                              const int* __restrict__ csr,
                                              float* __restrict__ out, int N) {
  int w = threadIdx.x >> 6, lane = threadIdx.x & 63;
  int n = blockIdx.x * 4 + w;
  if (n >= N) return;
  float adv = ad2[n];
  int e0 = off[n], e1 = off[n + 1];
  float m = -INFINITY;
  for (int idx = e0 + lane; idx < e1; idx += 64) {
    float t = as2[csr[idx]] + adv;
    t = t > 0.f ? t : LEAKY * t;
    m = fmaxf(m, t);
  }
#pragma unroll
  for (int o = 1; o <= 32; o <<= 1) m = fmaxf(m, __shfl_xor(m, o, 64));
  int slot = lane >> 3, q = lane & 7;
  float acc[8];
  float lp = 0.f;
#pragma unroll
  for (int k = 0; k < 8; ++k) acc[k] = 0.f;
  for (int base = e0; base < e1; base += 16) {
#pragma unroll
    for (int u = 0; u < 2; ++u) {
      int e = base + 8 * u + slot;
      int ec = min(e, e1 - 1);
      int s = csr[ec];
      float t = as2[s] + adv;
      t = t > 0.f ? t : LEAKY * t;
      float p = (e < e1) ? __expf(t - m) : 0.f;
      lp += p;
      half8 hv = *reinterpret_cast<const half8*>(h2p + (size_t)s * 64 + 8 * q);
#pragma unroll
      for (int k = 0; k < 8; ++k) acc[k] = fmaf(p, (float)hv[k], acc[k]);
    }
  }
#pragma unroll
  for (int o = 8; o <= 32; o <<= 1) {
    lp += __shfl_xor(lp, o, 64);
#pragma unroll
    for (int k = 0; k < 8; ++k) acc[k] += __shfl_xor(acc[k], o, 64);
  }
  if (slot == 0) {
    float rinv = 1.f / lp;
    // storage p = 8q + k  ->  orig col = ((k&3)<<4) | (2q + (k>>2))
#pragma unroll
    for (int k = 0; k < 8; ++k) {
      int col = ((k & 3) << 4) + 2 * q + (k >> 2);
      out[(size_t)n * 64 + col] = acc[k] * rinv + b2[col];
    }
  }
}

extern "C" void kernel_launch(void* const* d_in, const int* in_sizes, int n_in,
                              void* d_out, int out_size, void* d_ws, size_t ws_size,
                              hipStream_t stream) {
  const float* x = (const float*)d_in[0];
  const int* ei = (const int*)d_in[1];
  const float* W1 = (const float*)d_in[2];
  const float* a_src1 = (const float*)d_in[3];
  const float* a_dst1 = (const float*)d_in[4];
  const float* b1 = (const float*)d_in[5];
  const float* W2 = (const float*)d_in[6];
  const float* a_src2 = (const float*)d_in[7];
  const float* a_dst2 = (const float*)d_in[8];
  const float* b2 = (const float*)d_in[9];
  float* out = (float*)d_out;

  const int N = in_sizes[0] / 128;
  const int NE = in_sizes[1] / 2;
  const int ET = NE + N;
  const int chunk = ceil_div(N, SB);
  const int cap = 3 * ceil_div(ET, SB);

  char* p = (char*)d_ws;
  auto alloc = [&](size_t bytes) {
    char* r = p;
    p += (bytes + 255) & ~(size_t)255;
    return r;
  };
  int* deg = (int*)alloc((size_t)N * 4);       // must stay adjacent to bcnt
  int* bcnt = (int*)alloc((size_t)SB * 4);
  int* off = (int*)alloc((size_t)(N + 1) * 4);
  int* csr = (int*)alloc((size_t)ET * 4);
  int* bsum = (int*)alloc((size_t)SB * 4);
  int* bpre = (int*)alloc((size_t)SB * 4);
  int2* pairs = (int2*)alloc((size_t)SB * cap * 8);
  _Float16* w1hf = (_Float16*)alloc((size_t)32768 * 2);
  _Float16* w2f = (_Float16*)alloc((size_t)16384 * 2);
  float* wt1s = (float*)alloc((size_t)512 * 4);
  float* wt1d = (float*)alloc((size_t)512 * 4);
  float* b1p = (float*)alloc((size_t)256 * 4);
  _Float16* x16 = (_Float16*)alloc((size_t)N * 128 * 2);
  _Float16* xagg = (_Float16*)alloc((size_t)N * 512 * 2);
  float* as1 = (float*)alloc((size_t)N * 4 * 4);
  float* ad1 = (float*)alloc((size_t)N * 4 * 4);
  _Float16* alpha1 = (_Float16*)alloc((size_t)ET * 4 * 2);
  float* linv1 = (float*)alloc((size_t)N * 4 * 4);
  _Float16* h2p = x16;  // reuse: x16 dead after k_xagg
  float* as2 = (float*)alloc((size_t)N * 4);
  float* ad2 = (float*)alloc((size_t)N * 4);

  // zero deg + bcnt in one shot (they are adjacent, both 256B-aligned)
  size_t degBytes = ((size_t)N * 4 + 255) & ~(size_t)255;
  int zeroInt4 = (int)((degBytes + SB * 4) / 16);
  k_zero<<<ceil_div(zeroInt4, 256), 256, 0, stream>>>((int4*)deg, zeroInt4);
  k_fillAC<<<ceil_div(ET, FTILE), 256, 0, stream>>>(ei, deg, bcnt, pairs, NE, N,
                                                    chunk, cap);
  k_bsum<<<SB, 256, 0, stream>>>(deg, bsum, N);
  k_bscan<<<1, 256, 0, stream>>>(bsum, bpre, off, N);
  k_cscan<<<SB, 256, 0, stream>>>(deg, bpre, off, N);
  k_fillB<<<SB, 256, 0, stream>>>(pairs, bcnt, off, csr, N, chunk, cap);
  k_prep<<<198, 256, 0, stream>>>(W1, W2, a_src1, a_dst1, a_src2, a_dst2, b1,
                                  w1hf, w2f, wt1s, wt1d, b1p);

  k_logits1<<<ceil_div(N, 4), 256, 0, stream>>>(x, wt1s, wt1d, x16, as1, ad1, N);
  k_alpha1<<<ceil_div(N, 4), 256, 0, stream>>>(as1, ad1, off, csr, alpha1, linv1, N);
  k_xagg<<<ceil_div(N, 4), 256, 0, stream>>>(x16, alpha1, linv1, off, csr, xagg, N);
  k_gemm12<<<ceil_div(N, 64), 256, 0, stream>>>(xagg, w1hf, w2f, b1p, a_src2,
                                                a_dst2, h2p, as2, ad2, N);
  k_agg2<<<ceil_div(N, 4), 256, 0, stream>>>(h2p, as2, ad2, b2, off, csr, out, N);
}

// Round 15
// 185.140 us; speedup vs baseline: 1.8333x; 1.1531x over previous
//
#include <hip/hip_runtime.h>
#include <math.h>

#define LEAKY 0.2f
#define SB 256
#define FTILE 4096

typedef _Float16 half2v __attribute__((ext_vector_type(2)));
typedef _Float16 half4 __attribute__((ext_vector_type(4)));
typedef _Float16 half8 __attribute__((ext_vector_type(8)));
typedef float f32x4 __attribute__((ext_vector_type(4)));

static inline int ceil_div(int a, int b) { return (a + b - 1) / b; }

// storage index p -> original column, for 64-col groups
__device__ __forceinline__ int PERM(int p) {
  int q = p & 63;
  return (p & ~63) | (((q & 3) << 4) | (q >> 2));
}

// ---------------- zero helper ----------------
__global__ __launch_bounds__(256) void k_zero(int4* __restrict__ buf, int n4) {
  int i = blockIdx.x * 256 + threadIdx.x;
  if (i < n4) buf[i] = make_int4(0, 0, 0, 0);
}

// ---- fillA: radix-partition edges into bucket-contiguous (dst,src) pairs ----
// bucket b owns pairs[b*cap .. b*cap+bcnt[b]); no global deg atomics.
__global__ __launch_bounds__(256) void k_fillA(const int* __restrict__ ei,
                                               int* __restrict__ bcnt,
                                               int2* __restrict__ pairs,
                                               int NE, int N, int chunk, int cap) {
  __shared__ int hist[256], base[256], cnt2[256];
  int t = threadIdx.x;
  hist[t] = 0;
  cnt2[t] = 0;
  __syncthreads();
  int ET = NE + N;
  int e0 = blockIdx.x * FTILE;
  int sv[16], dv[16];
#pragma unroll
  for (int j = 0; j < 16; ++j) {
    int e = e0 + t + 256 * j;
    if (e < ET) {
      sv[j] = (e < NE) ? ei[e] : (e - NE);
      dv[j] = (e < NE) ? ei[NE + e] : (e - NE);
      atomicAdd(&hist[dv[j] / chunk], 1);
    } else {
      dv[j] = -1;
    }
  }
  __syncthreads();
  if (hist[t] > 0) base[t] = t * cap + atomicAdd(&bcnt[t], hist[t]);
  __syncthreads();
#pragma unroll
  for (int j = 0; j < 16; ++j) {
    if (dv[j] >= 0) {
      int b = dv[j] / chunk;
      int r = atomicAdd(&cnt2[b], 1);
      pairs[base[b] + r] = make_int2(dv[j], sv[j]);
    }
  }
}

// ---- bscan: exclusive scan of per-bucket counts -> bpre; off[N] = total -----
__global__ __launch_bounds__(256) void k_bscan(const int* __restrict__ bcnt,
                                               int* __restrict__ bpre,
                                               int* __restrict__ off, int N) {
  __shared__ int s[256];
  int t = threadIdx.x;
  int v = bcnt[t];
  s[t] = v;
  __syncthreads();
  for (int o = 1; o < 256; o <<= 1) {
    int u = (t >= o) ? s[t - o] : 0;
    __syncthreads();
    s[t] += u;
    __syncthreads();
  }
  bpre[t] = s[t] - v;
  if (t == 255) off[N] = s[255];
}

// ---- fillB2: per-bucket local degree + off + csr scatter --------------------
// pass 1: LDS histogram of bucket's pairs; LDS scan -> off (coalesced write);
// pass 2: scatter csr via LDS cursors. No global deg array at all.
__global__ __launch_bounds__(256) void k_fillB2(const int2* __restrict__ pairs,
                                                const int* __restrict__ bcnt,
                                                const int* __restrict__ bpre,
                                                int* __restrict__ off,
                                                int* __restrict__ csr, int N,
                                                int chunk, int cap) {
  __shared__ int hist[256], cur[256];
  int b = blockIdx.x, t = threadIdx.x;
  int node0 = b * chunk;
  hist[t] = 0;
  __syncthreads();
  int i0 = b * cap, i1 = i0 + bcnt[b];
  for (int i = i0 + t; i < i1; i += 256)
    atomicAdd(&hist[pairs[i].x - node0], 1);
  __syncthreads();
  // exclusive scan of hist into cur (in-place inclusive, then subtract v)
  int v = hist[t];
  for (int o = 1; o < 256; o <<= 1) {
    int u = (t >= o) ? hist[t - o] : 0;
    __syncthreads();
    hist[t] += u;
    __syncthreads();
  }
  int ex = hist[t] - v + bpre[b];
  if (t < chunk && node0 + t < N) off[node0 + t] = ex;
  cur[t] = ex;
  __syncthreads();
  for (int i = i0 + t; i < i1; i += 256) {
    int2 pr = pairs[i];
    int pos = atomicAdd(&cur[pr.x - node0], 1);
    csr[pos] = pr.y;
  }
}

// ---------------- prep: weight fragments + folded attention vectors ---------
__global__ __launch_bounds__(256) void k_prep(const float* __restrict__ W1,
                                              const float* __restrict__ W2,
                                              const float* __restrict__ a_src1,
                                              const float* __restrict__ a_dst1,
                                              const float* __restrict__ a_src2,
                                              const float* __restrict__ a_dst2,
                                              const float* __restrict__ b1,
                                              _Float16* __restrict__ w1hf,
                                              _Float16* __restrict__ w2f,
                                              float* __restrict__ wt1s,
                                              float* __restrict__ wt1d,
                                              float* __restrict__ b1p) {
  int idx = blockIdx.x * 256 + threadIdx.x;
  if (idx < 32768) {  // w1hf[h][ks][ct][l][i]
    int i = idx & 7, l = (idx >> 3) & 63, ct = (idx >> 9) & 3, ks = (idx >> 11) & 3,
        h = idx >> 13;
    int k = 32 * ks + 8 * (l >> 4) + i;
    int col = h * 64 + 16 * ct + (l & 15);
    w1hf[idx] = (_Float16)W1[k * 256 + col];
    return;
  }
  int i2 = idx - 32768;
  if (i2 < 16384) {  // w2f[ks][ct][l][i], A-side k' is layer-1 permuted index
    int i = i2 & 7, l = (i2 >> 3) & 63, ct = (i2 >> 9) & 3, ks = i2 >> 11;
    int kp = 32 * ks + 8 * (l >> 4) + i;
    int col = 16 * ct + (l & 15);
    w2f[i2] = (_Float16)W2[PERM(kp) * 64 + col];
    return;
  }
  int i3 = i2 - 16384;
  if (i3 < 512) {  // wt1s/wt1d[k*4+h]
    int h = i3 & 3, k = i3 >> 2;
    float ss = 0.f, sd = 0.f;
    for (int d = 0; d < 64; ++d) {
      float wv = W1[k * 256 + h * 64 + d];
      ss = fmaf(wv, a_src1[h * 64 + d], ss);
      sd = fmaf(wv, a_dst1[h * 64 + d], sd);
    }
    wt1s[i3] = ss;
    wt1d[i3] = sd;
    return;
  }
  int i4 = i3 - 512;
  if (i4 < 256) b1p[i4] = b1[PERM(i4)];
}

// ---------------- logits1: as1/ad1 = x @ wt1, also emit x16 -----------------
__global__ __launch_bounds__(256) void k_logits1(const float* __restrict__ x,
                                                 const float* __restrict__ wt1s,
                                                 const float* __restrict__ wt1d,
                                                 _Float16* __restrict__ x16,
                                                 float* __restrict__ as1,
                                                 float* __restrict__ ad1, int N) {
  int w = threadIdx.x >> 6, l = threadIdx.x & 63;
  int n = blockIdx.x * 4 + w;
  if (n >= N) return;
  float2 xv = *reinterpret_cast<const float2*>(x + (size_t)n * 128 + 2 * l);
  half2v xh;
  xh[0] = (_Float16)xv.x;
  xh[1] = (_Float16)xv.y;
  *reinterpret_cast<half2v*>(x16 + (size_t)n * 128 + 2 * l) = xh;
  float4 w0s = reinterpret_cast<const float4*>(wt1s)[2 * l];
  float4 w1s = reinterpret_cast<const float4*>(wt1s)[2 * l + 1];
  float4 w0d = reinterpret_cast<const float4*>(wt1d)[2 * l];
  float4 w1d = reinterpret_cast<const float4*>(wt1d)[2 * l + 1];
  float sa[4], sd[4];
  sa[0] = xv.x * w0s.x + xv.y * w1s.x;
  sa[1] = xv.x * w0s.y + xv.y * w1s.y;
  sa[2] = xv.x * w0s.z + xv.y * w1s.z;
  sa[3] = xv.x * w0s.w + xv.y * w1s.w;
  sd[0] = xv.x * w0d.x + xv.y * w1d.x;
  sd[1] = xv.x * w0d.y + xv.y * w1d.y;
  sd[2] = xv.x * w0d.z + xv.y * w1d.z;
  sd[3] = xv.x * w0d.w + xv.y * w1d.w;
#pragma unroll
  for (int o = 1; o <= 32; o <<= 1) {
#pragma unroll
    for (int h = 0; h < 4; ++h) {
      sa[h] += __shfl_xor(sa[h], o, 64);
      sd[h] += __shfl_xor(sd[h], o, 64);
    }
  }
  if (l == 0) {
#pragma unroll
    for (int h = 0; h < 4; ++h) {
      as1[n * 4 + h] = sa[h];
      ad1[n * 4 + h] = sd[h];
    }
  }
}

// ------- alpha1, 2-pass: UNNORMALIZED fp16 p + linv1 = 1/sum ---------------
__global__ __launch_bounds__(256) void k_alpha1(const float* __restrict__ as1,
                                                const float* __restrict__ ad1,
                                                const int* __restrict__ off,
                                                const int* __restrict__ csr,
                                                _Float16* __restrict__ alpha,
                                                float* __restrict__ linv1, int N) {
  int w = threadIdx.x >> 6, lane = threadIdx.x & 63;
  int n = blockIdx.x * 4 + w;
  if (n >= N) return;
  int eidx = lane >> 2, h = lane & 3;
  float adv = ad1[n * 4 + h];
  int e0 = off[n], e1 = off[n + 1];
  float m = -INFINITY;
  for (int base = e0; base < e1; base += 16) {
    int idx = base + eidx;
    if (idx < e1) {
      int s = csr[idx];
      float t = as1[s * 4 + h] + adv;
      t = t > 0.f ? t : LEAKY * t;
      m = fmaxf(m, t);
    }
  }
#pragma unroll
  for (int o = 4; o <= 32; o <<= 1) m = fmaxf(m, __shfl_xor(m, o, 64));
  float lp = 0.f;
  for (int base = e0; base < e1; base += 16) {
    int idx = base + eidx;
    if (idx < e1) {
      int s = csr[idx];
      float t = as1[s * 4 + h] + adv;
      t = t > 0.f ? t : LEAKY * t;
      float p = __expf(t - m);
      alpha[(size_t)idx * 4 + h] = (_Float16)p;
      lp += p;
    }
  }
#pragma unroll
  for (int o = 4; o <= 32; o <<= 1) lp += __shfl_xor(lp, o, 64);
  if (lane < 4) linv1[n * 4 + h] = 1.f / lp;
}

// ---------------- x-space aggregation: packed-fp16 accumulate, 16 edges deep -
__global__ __launch_bounds__(256) void k_xagg(const _Float16* __restrict__ x16,
                                              const _Float16* __restrict__ alpha,
                                              const float* __restrict__ linv1,
                                              const int* __restrict__ off,
                                              const int* __restrict__ csr,
                                              _Float16* __restrict__ xagg, int N) {
  int w = threadIdx.x >> 6, l = threadIdx.x & 63;
  int n = blockIdx.x * 4 + w;
  if (n >= N) return;
  int slot = l >> 4, kq = l & 15;
  int e0 = off[n], e1 = off[n + 1];
  half2v acc[4][4];
#pragma unroll
  for (int h = 0; h < 4; ++h)
#pragma unroll
    for (int j = 0; j < 4; ++j) acc[h][j] = (half2v){(_Float16)0.f, (_Float16)0.f};
  const _Float16 zero16 = (_Float16)0.f;
  for (int base = e0; base < e1; base += 16) {
#pragma unroll
    for (int u = 0; u < 4; ++u) {
      int e = base + 4 * u + slot;
      int ec = min(e, e1 - 1);
      int src = csr[ec];
      half4 al = *reinterpret_cast<const half4*>(alpha + (size_t)ec * 4);
      if (e >= e1) al = (half4){zero16, zero16, zero16, zero16};
      half8 hv = *reinterpret_cast<const half8*>(x16 + (size_t)src * 128 + 8 * kq);
      half2v xp[4];
      xp[0] = (half2v){hv[0], hv[1]};
      xp[1] = (half2v){hv[2], hv[3]};
      xp[2] = (half2v){hv[4], hv[5]};
      xp[3] = (half2v){hv[6], hv[7]};
#pragma unroll
      for (int h = 0; h < 4; ++h) {
        half2v ah = (half2v){al[h], al[h]};
#pragma unroll
        for (int j = 0; j < 4; ++j) acc[h][j] = ah * xp[j] + acc[h][j];
      }
    }
  }
#pragma unroll
  for (int h = 0; h < 4; ++h)
#pragma unroll
    for (int j = 0; j < 4; ++j) {
      int v0 = __shfl_xor(__builtin_bit_cast(int, acc[h][j]), 16, 64);
      acc[h][j] = acc[h][j] + __builtin_bit_cast(half2v, v0);
      int v1 = __shfl_xor(__builtin_bit_cast(int, acc[h][j]), 32, 64);
      acc[h][j] = acc[h][j] + __builtin_bit_cast(half2v, v1);
    }
  if (slot == 0) {
    float4 linv = *reinterpret_cast<const float4*>(linv1 + n * 4);
    float rin[4] = {linv.x, linv.y, linv.z, linv.w};
#pragma unroll
    for (int h = 0; h < 4; ++h) {
      half8 o;
#pragma unroll
      for (int j = 0; j < 4; ++j) {
        o[2 * j] = (_Float16)((float)acc[h][j][0] * rin[h]);
        o[2 * j + 1] = (_Float16)((float)acc[h][j][1] * rin[h]);
      }
      *reinterpret_cast<half8*>(xagg + (size_t)n * 512 + h * 128 + 8 * kq) = o;
    }
  }
}

// -------- fused layer-1 + layer-2 GEMM: xagg -> (LDS) -> h2p, as2/ad2 --------
__global__ __launch_bounds__(256) void k_gemm12(const _Float16* __restrict__ xagg,
                                                const _Float16* __restrict__ w1hf,
                                                const _Float16* __restrict__ w2f,
                                                const float* __restrict__ b1p,
                                                const float* __restrict__ a_src2,
                                                const float* __restrict__ a_dst2,
                                                _Float16* __restrict__ h2p,
                                                float* __restrict__ as2,
                                                float* __restrict__ ad2, int N) {
  __shared__ _Float16 hs[64 * 256];  // 32 KiB
  int w = threadIdx.x >> 6, l = threadIdx.x & 63;
  int n0 = blockIdx.x * 64 + 16 * w;
  int lrow = l & 15, lgrp = l >> 4;
  int arow = min(n0 + lrow, N - 1);
  // ---- phase 1: gemm1 ----
  f32x4 acc1[4][4];
#pragma unroll
  for (int h = 0; h < 4; ++h)
#pragma unroll
    for (int ct = 0; ct < 4; ++ct) acc1[h][ct] = (f32x4){0.f, 0.f, 0.f, 0.f};
#pragma unroll
  for (int h = 0; h < 4; ++h) {
#pragma unroll
    for (int ks = 0; ks < 4; ++ks) {
      half8 af = *reinterpret_cast<const half8*>(xagg + (size_t)arow * 512 + h * 128 +
                                                 32 * ks + 8 * lgrp);
      const half8* bp =
          reinterpret_cast<const half8*>(w1hf) + (size_t)((h * 4 + ks) * 4) * 64 + l;
#pragma unroll
      for (int ct = 0; ct < 4; ++ct) {
        half8 bf = bp[ct * 64];
        acc1[h][ct] = __builtin_amdgcn_mfma_f32_16x16x32_f16(af, bf, acc1[h][ct], 0, 0, 0);
      }
    }
  }
  int lr0 = 16 * w + 4 * lgrp;
#pragma unroll
  for (int h = 0; h < 4; ++h) {
    float4 bv = *reinterpret_cast<const float4*>(b1p + h * 64 + lrow * 4);
#pragma unroll
    for (int r = 0; r < 4; ++r) {
      int row = lr0 + r;
      half4 o;
      o[0] = (_Float16)fmaxf(acc1[h][0][r] + bv.x, 0.f);
      o[1] = (_Float16)fmaxf(acc1[h][1][r] + bv.y, 0.f);
      o[2] = (_Float16)fmaxf(acc1[h][2][r] + bv.z, 0.f);
      o[3] = (_Float16)fmaxf(acc1[h][3][r] + bv.w, 0.f);
      int ba = row * 512 + ((h * 128 + lrow * 8) ^ ((row & 7) << 4));
      *reinterpret_cast<half4*>(reinterpret_cast<char*>(hs) + ba) = o;
    }
  }
  __syncthreads();
  // ---- phase 2: gemm2 over K=256 from LDS ----
  int arow2 = 16 * w + lrow;
  f32x4 acc2[4];
#pragma unroll
  for (int ct = 0; ct < 4; ++ct) acc2[ct] = (f32x4){0.f, 0.f, 0.f, 0.f};
#pragma unroll
  for (int ks = 0; ks < 8; ++ks) {
    int ba = arow2 * 512 + ((64 * ks + 16 * lgrp) ^ ((arow2 & 7) << 4));
    half8 af = *reinterpret_cast<const half8*>(reinterpret_cast<const char*>(hs) + ba);
    const half8* bp = reinterpret_cast<const half8*>(w2f) + (size_t)(ks * 4) * 64 + l;
#pragma unroll
    for (int ct = 0; ct < 4; ++ct) {
      half8 bf = bp[ct * 64];
      acc2[ct] = __builtin_amdgcn_mfma_f32_16x16x32_f16(af, bf, acc2[ct], 0, 0, 0);
    }
  }
  float ascol[4], adcol[4];
#pragma unroll
  for (int ct = 0; ct < 4; ++ct) {
    ascol[ct] = a_src2[16 * ct + lrow];
    adcol[ct] = a_dst2[16 * ct + lrow];
  }
  int rbase = n0 + 4 * lgrp;
#pragma unroll
  for (int r = 0; r < 4; ++r) {
    int row = rbase + r;
    bool ok = row < N;
    float sa = 0.f, sd = 0.f;
    half4 o;
#pragma unroll
    for (int ct = 0; ct < 4; ++ct) {
      float v = acc2[ct][r];
      o[ct] = (_Float16)v;
      sa = fmaf(v, ascol[ct], sa);
      sd = fmaf(v, adcol[ct], sd);
    }
    if (ok) *reinterpret_cast<half4*>(h2p + (size_t)row * 64 + lrow * 4) = o;
#pragma unroll
    for (int oo = 1; oo <= 8; oo <<= 1) {
      sa += __shfl_xor(sa, oo, 64);
      sd += __shfl_xor(sd, oo, 64);
    }
    if (ok && lrow == 0) {
      as2[row] = sa;
      ad2[row] = sd;
    }
  }
}

// ---------------- Layer 2: fused softmax + aggregation, 2-pass ---------------
__global__ __launch_bounds__(256) void k_agg2(const _Float16* __restrict__ h2p,
                                              const float* __restrict__ as2,
                                              const float* __restrict__ ad2,
                                              const float* __restrict__ b2,
                                              const int* __restrict__ off,
                                              const int* __restrict__ csr,
                                              float* __restrict__ out, int N) {
  int w = threadIdx.x >> 6, lane = threadIdx.x & 63;
  int n = blockIdx.x * 4 + w;
  if (n >= N) return;
  float adv = ad2[n];
  int e0 = off[n], e1 = off[n + 1];
  float m = -INFINITY;
  for (int idx = e0 + lane; idx < e1; idx += 64) {
    float t = as2[csr[idx]] + adv;
    t = t > 0.f ? t : LEAKY * t;
    m = fmaxf(m, t);
  }
#pragma unroll
  for (int o = 1; o <= 32; o <<= 1) m = fmaxf(m, __shfl_xor(m, o, 64));
  int slot = lane >> 3, q = lane & 7;
  float acc[8];
  float lp = 0.f;
#pragma unroll
  for (int k = 0; k < 8; ++k) acc[k] = 0.f;
  for (int base = e0; base < e1; base += 16) {
#pragma unroll
    for (int u = 0; u < 2; ++u) {
      int e = base + 8 * u + slot;
      int ec = min(e, e1 - 1);
      int s = csr[ec];
      float t = as2[s] + adv;
      t = t > 0.f ? t : LEAKY * t;
      float p = (e < e1) ? __expf(t - m) : 0.f;
      lp += p;
      half8 hv = *reinterpret_cast<const half8*>(h2p + (size_t)s * 64 + 8 * q);
#pragma unroll
      for (int k = 0; k < 8; ++k) acc[k] = fmaf(p, (float)hv[k], acc[k]);
    }
  }
#pragma unroll
  for (int o = 8; o <= 32; o <<= 1) {
    lp += __shfl_xor(lp, o, 64);
#pragma unroll
    for (int k = 0; k < 8; ++k) acc[k] += __shfl_xor(acc[k], o, 64);
  }
  if (slot == 0) {
    float rinv = 1.f / lp;
    // storage p = 8q + k  ->  orig col = ((k&3)<<4) | (2q + (k>>2))
#pragma unroll
    for (int k = 0; k < 8; ++k) {
      int col = ((k & 3) << 4) + 2 * q + (k >> 2);
      out[(size_t)n * 64 + col] = acc[k] * rinv + b2[col];
    }
  }
}

extern "C" void kernel_launch(void* const* d_in, const int* in_sizes, int n_in,
                              void* d_out, int out_size, void* d_ws, size_t ws_size,
                              hipStream_t stream) {
  const float* x = (const float*)d_in[0];
  const int* ei = (const int*)d_in[1];
  const float* W1 = (const float*)d_in[2];
  const float* a_src1 = (const float*)d_in[3];
  const float* a_dst1 = (const float*)d_in[4];
  const float* b1 = (const float*)d_in[5];
  const float* W2 = (const float*)d_in[6];
  const float* a_src2 = (const float*)d_in[7];
  const float* a_dst2 = (const float*)d_in[8];
  const float* b2 = (const float*)d_in[9];
  float* out = (float*)d_out;

  const int N = in_sizes[0] / 128;
  const int NE = in_sizes[1] / 2;
  const int ET = NE + N;
  const int chunk = ceil_div(N, SB);
  const int cap = 3 * ceil_div(ET, SB);

  char* p = (char*)d_ws;
  auto alloc = [&](size_t bytes) {
    char* r = p;
    p += (bytes + 255) & ~(size_t)255;
    return r;
  };
  int* bcnt = (int*)alloc((size_t)SB * 4);
  int* bpre = (int*)alloc((size_t)SB * 4);
  int* off = (int*)alloc((size_t)(N + 1) * 4);
  int* csr = (int*)alloc((size_t)ET * 4);
  int2* pairs = (int2*)alloc((size_t)SB * cap * 8);
  _Float16* w1hf = (_Float16*)alloc((size_t)32768 * 2);
  _Float16* w2f = (_Float16*)alloc((size_t)16384 * 2);
  float* wt1s = (float*)alloc((size_t)512 * 4);
  float* wt1d = (float*)alloc((size_t)512 * 4);
  float* b1p = (float*)alloc((size_t)256 * 4);
  _Float16* x16 = (_Float16*)alloc((size_t)N * 128 * 2);
  _Float16* xagg = (_Float16*)alloc((size_t)N * 512 * 2);
  float* as1 = (float*)alloc((size_t)N * 4 * 4);
  float* ad1 = (float*)alloc((size_t)N * 4 * 4);
  _Float16* alpha1 = (_Float16*)alloc((size_t)ET * 4 * 2);
  float* linv1 = (float*)alloc((size_t)N * 4 * 4);
  _Float16* h2p = x16;  // reuse: x16 dead after k_xagg
  float* as2 = (float*)alloc((size_t)N * 4);
  float* ad2 = (float*)alloc((size_t)N * 4);

  k_zero<<<1, 256, 0, stream>>>((int4*)bcnt, SB / 4);
  k_fillA<<<ceil_div(ET, FTILE), 256, 0, stream>>>(ei, bcnt, pairs, NE, N, chunk, cap);
  k_bscan<<<1, 256, 0, stream>>>(bcnt, bpre, off, N);
  k_fillB2<<<SB, 256, 0, stream>>>(pairs, bcnt, bpre, off, csr, N, chunk, cap);
  k_prep<<<198, 256, 0, stream>>>(W1, W2, a_src1, a_dst1, a_src2, a_dst2, b1,
                                  w1hf, w2f, wt1s, wt1d, b1p);

  k_logits1<<<ceil_div(N, 4), 256, 0, stream>>>(x, wt1s, wt1d, x16, as1, ad1, N);
  k_alpha1<<<ceil_div(N, 4), 256, 0, stream>>>(as1, ad1, off, csr, alpha1, linv1, N);
  k_xagg<<<ceil_div(N, 4), 256, 0, stream>>>(x16, alpha1, linv1, off, csr, xagg, N);
  k_gemm12<<<ceil_div(N, 64), 256, 0, stream>>>(xagg, w1hf, w2f, b1p, a_src2,
                                                a_dst2, h2p, as2, ad2, N);
  k_agg2<<<ceil_div(N, 4), 256, 0, stream>>>(h2p, as2, ad2, b2, off, csr, out, N);
}